// Round 12
// baseline (1374.509 us; speedup 1.0000x reference)
//
#include <hip/hip_runtime.h>
#include <hip/hip_bf16.h>
#include <cstdint>
#include <cstddef>

#define INVS 0.99999500003749968f  // 1/sqrt(1+1e-5)
#define G_GRAPHS 256

using bf16 = __hip_bfloat16;
using short8 = __attribute__((ext_vector_type(8))) short;
using floatx4 = __attribute__((ext_vector_type(4))) float;

// ---------- helpers ----------
__device__ __forceinline__ unsigned short f2bf(float v) {
    union { float f; unsigned u; } x; x.f = v;
    unsigned r = x.u + 0x7fffu + ((x.u >> 16) & 1u);
    return (unsigned short)(r >> 16);
}
__device__ __forceinline__ float bflo(unsigned u) { return __uint_as_float(u << 16); }
__device__ __forceinline__ float bfhi(unsigned u) { return __uint_as_float(u & 0xffff0000u); }

// ---------- CSR build ----------
__global__ void degi_k(const int* __restrict__ dst, int* __restrict__ degi, int E) {
    int gid = blockIdx.x * 256 + threadIdx.x;
    if (gid < E) atomicAdd(&degi[dst[gid]], 1);
}

__global__ void scan_k(const int* __restrict__ degi, int* __restrict__ off, int N) {
    __shared__ int buf[1024];
    __shared__ int carry;
    int t = threadIdx.x;
    if (t == 0) carry = 0;
    __syncthreads();
    int nch = (N + 1023) / 1024;
    for (int ch = 0; ch < nch; ++ch) {
        int idx = ch * 1024 + t;
        int v = (idx < N) ? (degi[idx] + 1) : 0;
        buf[t] = v;
        __syncthreads();
        for (int ofs = 1; ofs < 1024; ofs <<= 1) {
            int add = (t >= ofs) ? buf[t - ofs] : 0;
            __syncthreads();
            buf[t] += add;
            __syncthreads();
        }
        int incl = buf[t];
        if (idx < N) off[idx] = carry + incl - v;
        __syncthreads();
        if (t == 1023) carry += incl;
        __syncthreads();
    }
    if (t == 0) off[N] = carry;
}

__global__ void fill_csr_k(const int* __restrict__ src, const int* __restrict__ dst,
                           const int* __restrict__ off, int* __restrict__ fillc,
                           int* __restrict__ csr_src, int* __restrict__ csr_dst,
                           int* __restrict__ csr_eid, int* __restrict__ slot_of,
                           int E, int N) {
    int gid = blockIdx.x * 256 + threadIdx.x;
    if (gid < E) {
        int d = dst[gid];
        int slot = off[d] + atomicAdd(&fillc[d], 1);
        csr_src[slot] = src[gid];
        csr_dst[slot] = d;
        csr_eid[slot] = gid;
        slot_of[gid] = slot;
    }
    if (gid < N) {
        int slot = off[gid + 1] - 1;   // reserved last slot = self-loop
        csr_src[slot] = gid;
        csr_dst[slot] = gid;
        csr_eid[slot] = E + gid;       // >= E marks self-loop
    }
}

// ---------- weight prep for MFMA edge MLP1 ----------
__global__ void conv_weights1_k(const float* __restrict__ w1, const float* __restrict__ w2,
                                short* __restrict__ w1s, short* __restrict__ w2s) {
    int gid = blockIdx.x * 256 + threadIdx.x;
    if (gid < 1280) {
        int f = gid >> 6, lane = gid & 63;
        int kk = f >> 2, tt = f & 3;
        int n = tt * 16 + (lane & 15);
        int k0 = kk * 32 + (lane >> 4) * 8;
        short8 v;
        for (int j = 0; j < 8; ++j) {
            int k = k0 + j;
            v[j] = (k < 144) ? (short)f2bf(w1[k * 64 + n]) : (short)0;
        }
        *(short8*)(w1s + (long long)gid * 8) = v;
    } else if (gid < 2304) {
        int g2 = gid - 1280;
        int f = g2 >> 6, lane = g2 & 63;
        int kk = f >> 3, tt = f & 7;
        int n = tt * 16 + (lane & 15);
        int k0 = kk * 32 + (lane >> 4) * 8;
        short8 v;
        for (int j = 0; j < 8; ++j) v[j] = (short)f2bf(w2[(k0 + j) * 128 + n]);
        *(short8*)(w2s + (long long)g2 * 8) = v;
    }
}

// ---------- ew prep: ew[128][256] -> frags 4 kk x 16 tt ----------
__global__ void conv_ew_k(const float* __restrict__ ew, short* __restrict__ ews) {
    int gid = blockIdx.x * 256 + threadIdx.x;
    if (gid >= 4096) return;
    int f = gid >> 6, lane = gid & 63;
    int kk = f >> 4, tt = f & 15;
    int n = tt * 16 + (lane & 15);
    int k0 = kk * 32 + (lane >> 4) * 8;
    short8 v;
    for (int j = 0; j < 8; ++j) v[j] = (short)f2bf(ew[(k0 + j) * 256 + n]);
    *(short8*)(ews + (long long)gid * 8) = v;
}

// ---------- node-linear weight prep: [wl|wr] (K x 512) -> frags ----------
template <int K>
__global__ void conv_nodew_k(const float* __restrict__ wl, const float* __restrict__ wr,
                             short* __restrict__ out) {
    int gid = blockIdx.x * 256 + threadIdx.x;
    if (gid >= (K / 32) * 32 * 64) return;
    int f = gid >> 6, lane = gid & 63;
    int kk = f >> 5, tt = f & 31;
    int n = tt * 16 + (lane & 15);
    int k0 = kk * 32 + (lane >> 4) * 8;
    short8 v;
    for (int j = 0; j < 8; ++j) {
        int k = k0 + j;
        float x = (n < 256) ? wl[k * 256 + n] : wr[k * 256 + (n - 256)];
        v[j] = (short)f2bf(x);
    }
    *(short8*)(out + (long long)gid * 8) = v;
}

// ---------- Edge MLP 1 via MFMA: eid-order compute, scatter rows to CSR slots ----------
__global__ __launch_bounds__(256) void edge_mlp1_mfma_k(
    const float* __restrict__ x, const float* __restrict__ ea,
    const int* __restrict__ src, const int* __restrict__ dst,
    const int* __restrict__ slot_of,
    const short* __restrict__ w1s, const float* __restrict__ b1,
    const short* __restrict__ w2s, const float* __restrict__ b2,
    bf16* __restrict__ out, int E) {
    __shared__ short At[32][168];
    __shared__ short Ht[32][72];
    __shared__ int sdv[32][2];
    __shared__ int slt[32];
    int t = threadIdx.x;
    long long e0 = (long long)blockIdx.x * 32;
    if (t < 64) {
        int r = t & 31;
        long long e = e0 + r;
        int v = 0;
        if (e < E) v = (t < 32) ? src[e] : dst[e];
        sdv[r][t >> 5] = v;
    } else if (t < 96) {
        int r = t - 64;
        long long e = e0 + r;
        slt[r] = (e < E) ? slot_of[e] : -1;
    }
    __syncthreads();
    for (int i = t; i < 32 * 40; i += 256) {
        int r = i / 40, c = i - r * 40;
        long long e = e0 + r;
        float4 v = {0.f, 0.f, 0.f, 0.f};
        if (e < E) {
            if (c < 16)      v = *(const float4*)(x + (long long)sdv[r][0] * 64 + c * 4);
            else if (c < 32) v = *(const float4*)(x + (long long)sdv[r][1] * 64 + (c - 16) * 4);
            else if (c < 36) v = *(const float4*)(ea + e * 16 + (c - 32) * 4);
        }
        union { ushort4 u4; unsigned short s4[4]; } pk;
        pk.s4[0] = f2bf(v.x); pk.s4[1] = f2bf(v.y); pk.s4[2] = f2bf(v.z); pk.s4[3] = f2bf(v.w);
        *(ushort4*)&At[r][c * 4] = pk.u4;
    }
    __syncthreads();

    int w = t >> 6, lane = t & 63;
    int m0 = (w & 1) * 16;
    int lr = lane & 15, lq = lane >> 4;

    int nq1 = (w >> 1) * 2;
    floatx4 acc[2];
    for (int i = 0; i < 2; ++i) acc[i] = (floatx4){0.f, 0.f, 0.f, 0.f};
    for (int kk = 0; kk < 5; ++kk) {
        short8 a = *(const short8*)&At[m0 + lr][kk * 32 + lq * 8];
        for (int tt = 0; tt < 2; ++tt) {
            short8 b = *(const short8*)(w1s + ((long long)((kk * 4 + nq1 + tt) * 64 + lane)) * 8);
            acc[tt] = __builtin_amdgcn_mfma_f32_16x16x32_bf16(a, b, acc[tt], 0, 0, 0);
        }
    }
    for (int tt = 0; tt < 2; ++tt) {
        int col = (nq1 + tt) * 16 + lr;
        float bv = b1[col];
        for (int r = 0; r < 4; ++r)
            Ht[m0 + lq * 4 + r][col] = (short)f2bf(fmaxf(acc[tt][r] + bv, 0.f));
    }
    __syncthreads();

    int nq2 = (w >> 1) * 4;
    floatx4 acc2[4];
    for (int i = 0; i < 4; ++i) acc2[i] = (floatx4){0.f, 0.f, 0.f, 0.f};
    for (int kk = 0; kk < 2; ++kk) {
        short8 a = *(const short8*)&Ht[m0 + lr][kk * 32 + lq * 8];
        for (int tt = 0; tt < 4; ++tt) {
            short8 b = *(const short8*)(w2s + ((long long)((kk * 8 + nq2 + tt) * 64 + lane)) * 8);
            acc2[tt] = __builtin_amdgcn_mfma_f32_16x16x32_bf16(a, b, acc2[tt], 0, 0, 0);
        }
    }
    for (int tt = 0; tt < 4; ++tt) {
        int col = (nq2 + tt) * 16 + lr;
        float bv = b2[col];
        for (int r = 0; r < 4; ++r)
            At[m0 + lq * 4 + r][col] = (short)f2bf(acc2[tt][r] + bv);
    }
    __syncthreads();
    // scatter rows to slot positions (coalesced 256 B per row)
    for (int i = t; i < 512; i += 256) {
        int r = i >> 4, c = i & 15;
        int s = slt[r];
        if (s >= 0)
            *(short8*)(void*)(out + (long long)s * 128 + c * 8) = *(const short8*)&At[r][c * 8];
    }
}

// ---------- node linear via MFMA: [N x K] @ [K x 512] (= [wl|wr]) + bias ----------
// NOTE: x may alias xr (x1bn overlay) — per-block reads complete before same-row writes.
template <int K, typename T>
__global__ __launch_bounds__(256) void node_linear_mfma_k(
    const T* x, const short* __restrict__ ws,
    const float* __restrict__ bl, const float* __restrict__ br,
    bf16* __restrict__ xl, bf16* xr, int N) {
    __shared__ short At[16][K + 8];
    __shared__ short Ot[16][520];
    int t = threadIdx.x;
    long long n0 = (long long)blockIdx.x * 16;
    if (sizeof(T) == 4) {
        for (int i = t; i < 16 * (K / 4); i += 256) {
            int r = i / (K / 4), c = i % (K / 4);
            long long n = n0 + r;
            float4 v = {0.f, 0.f, 0.f, 0.f};
            if (n < N) v = *(const float4*)((const float*)x + n * K + c * 4);
            union { ushort4 u4; unsigned short s4[4]; } pk;
            pk.s4[0] = f2bf(v.x); pk.s4[1] = f2bf(v.y); pk.s4[2] = f2bf(v.z); pk.s4[3] = f2bf(v.w);
            *(ushort4*)&At[r][c * 4] = pk.u4;
        }
    } else {
        for (int i = t; i < 16 * (K / 8); i += 256) {
            int r = i / (K / 8), c = i % (K / 8);
            long long n = n0 + r;
            short8 v = {0, 0, 0, 0, 0, 0, 0, 0};
            if (n < N) v = *(const short8*)(const void*)((const bf16*)x + n * K + c * 8);
            *(short8*)&At[r][c * 8] = v;
        }
    }
    __syncthreads();

    int w = t >> 6, lane = t & 63;
    int nq = w * 8;
    int lr = lane & 15, lq = lane >> 4;

    floatx4 acc[8];
    for (int i = 0; i < 8; ++i) acc[i] = (floatx4){0.f, 0.f, 0.f, 0.f};
    for (int kk = 0; kk < K / 32; ++kk) {
        short8 a = *(const short8*)&At[lr][kk * 32 + lq * 8];
        for (int tt = 0; tt < 8; ++tt) {
            short8 b = *(const short8*)(ws + ((long long)((kk * 32 + nq + tt) * 64 + lane)) * 8);
            acc[tt] = __builtin_amdgcn_mfma_f32_16x16x32_bf16(a, b, acc[tt], 0, 0, 0);
        }
    }
    for (int tt = 0; tt < 8; ++tt) {
        int col = (nq + tt) * 16 + lr;
        float bv = (col < 256) ? bl[col] : br[col - 256];
        for (int r = 0; r < 4; ++r)
            Ot[lq * 4 + r][col] = (short)f2bf(acc[tt][r] + bv);
    }
    __syncthreads();
    for (int i = t; i < 1024; i += 256) {
        int r = i >> 6, c = i & 63;
        long long n = n0 + r;
        if (n < N) {
            short8 v = *(const short8*)&Ot[r][c * 8];
            if (c < 32) *(short8*)(void*)(xl + n * 256 + c * 8) = v;
            else        *(short8*)(void*)(xr + n * 256 + (c - 32) * 8) = v;
        }
    }
}

// ---------- ee GEMM (half channels), slot order in -> slot order out ----------
template <int PASS>
__global__ __launch_bounds__(256) void gemm_ee_k(
    const bf16* __restrict__ ea_slot, const short* __restrict__ ews,
    bf16* __restrict__ eeh, int NT) {
    __shared__ short At[32][136];
    __shared__ short Et[32][136];
    int t = threadIdx.x;
    long long s0 = (long long)blockIdx.x * 32;
    for (int i = t; i < 32 * 16; i += 256) {
        int r = i >> 4, c = i & 15;
        long long s = s0 + r;
        short8 v = {0, 0, 0, 0, 0, 0, 0, 0};
        if (s < NT) v = *(const short8*)(const void*)(ea_slot + s * 128 + c * 8);
        *(short8*)&At[r][c * 8] = v;
    }
    __syncthreads();

    int w = t >> 6, lane = t & 63;
    int m0 = (w & 1) * 16, nq = (w >> 1) * 4;
    int lr = lane & 15, lq = lane >> 4;

    floatx4 acc[4];
    for (int i = 0; i < 4; ++i) acc[i] = (floatx4){0.f, 0.f, 0.f, 0.f};
    for (int kk = 0; kk < 4; ++kk) {
        short8 a = *(const short8*)&At[m0 + lr][kk * 32 + lq * 8];
        for (int tt = 0; tt < 4; ++tt) {
            short8 b = *(const short8*)(ews + ((long long)((kk * 16 + PASS * 8 + nq + tt) * 64 + lane)) * 8);
            acc[tt] = __builtin_amdgcn_mfma_f32_16x16x32_bf16(a, b, acc[tt], 0, 0, 0);
        }
    }
    for (int tt = 0; tt < 4; ++tt) {
        int col = (nq + tt) * 16 + lr;
        for (int r = 0; r < 4; ++r)
            Et[m0 + lq * 4 + r][col] = (short)f2bf(acc[tt][r]);
    }
    __syncthreads();
    {
        int r = t >> 3, c = t & 7;
        long long s = s0 + r;
        if (s < NT)
            *(short8*)(void*)(eeh + s * 128 + c * 8) = *(const short8*)&Et[r][c * 8];
    }
}

// ---------- self-loop ee = mean of incoming ee rows ----------
__global__ __launch_bounds__(256) void loop_ee_k(bf16* __restrict__ eeh,
                                                 const int* __restrict__ off, int N) {
    int t = threadIdx.x;
    int w = t >> 6, lane = t & 63;
    int n = blockIdx.x * 4 + w;
    if (n >= N) return;
    int beg = off[n], end = off[n + 1] - 1;
    float a0 = 0.f, a1 = 0.f;
    for (int i = beg; i < end; ++i) {
        unsigned pk = *(const unsigned*)(const void*)(eeh + (long long)i * 128 + lane * 2);
        a0 += bflo(pk);
        a1 += bfhi(pk);
    }
    float dv = fmaxf((float)(end - beg), 1.f);
    unsigned o = ((unsigned)f2bf(a1 / dv) << 16) | (unsigned)f2bf(a0 / dv);
    *(unsigned*)(void*)(eeh + (long long)end * 128 + lane * 2) = o;
}

// ---------- Fused GATv2 attention + aggregation + finalize ----------
// NOTE: x1bn may alias xr — xr[n] is read only by the owning wave, before its write.
template <int PASS, bool L1>
__global__ __launch_bounds__(256) void gat_fused_k(
    const bf16* __restrict__ eeh, const bf16* __restrict__ xl, const bf16* xr,
    const int* __restrict__ off, const int* __restrict__ csr_src,
    const float* __restrict__ att, const float* __restrict__ bias,
    const float* __restrict__ bng, const float* __restrict__ bnb,
    const int* __restrict__ batch,
    bf16* x1bn, float* __restrict__ pooled, int N) {
    int t = threadIdx.x;
    int w = t >> 6, lane = t & 63;
    int n = blockIdx.x * 4 + w;
    if (n >= N) return;
    int c = lane * 2;
    int gc = PASS * 128 + c;
    unsigned xrp = *(const unsigned*)(const void*)(xr + (long long)n * 256 + gc);
    float xr0 = bflo(xrp), xr1 = bfhi(xrp);
    float at0 = att[gc], at1 = att[gc + 1];
    float a0 = 0.f, a1 = 0.f, dacc = 0.f;
    int beg = off[n], end = off[n + 1];
    for (int i = beg; i < end; ++i) {
        int sid = csr_src[i];
        unsigned xlp = *(const unsigned*)(const void*)(xl + (long long)sid * 256 + gc);
        unsigned eep = *(const unsigned*)(const void*)(eeh + (long long)i * 128 + c);
        float x0 = bflo(xlp), x1v = bfhi(xlp);
        float m0 = x0 + xr0 + bflo(eep);
        float m1 = x1v + xr1 + bfhi(eep);
        m0 = m0 > 0.f ? m0 : 0.2f * m0;
        m1 = m1 > 0.f ? m1 : 0.2f * m1;
        float p = at0 * m0 + at1 * m1;
        p += __shfl_xor(p, 1, 64);
        p += __shfl_xor(p, 2, 64);
        p += __shfl_xor(p, 4, 64);
        p += __shfl_xor(p, 8, 64);
        p += __shfl_xor(p, 16, 64);
        float ex = expf(p);
        a0 += ex * x0; a1 += ex * x1v; dacc += ex;
    }
    float inv = 1.f / dacc;
    float o0 = fmaxf(a0 * inv + bias[gc],     0.f);
    float o1 = fmaxf(a1 * inv + bias[gc + 1], 0.f);
    long long pb = (long long)batch[n] * 256 + gc;
    atomicAdd(&pooled[pb],     o0);
    atomicAdd(&pooled[pb + 1], o1);
    if (L1) {
        unsigned pk = ((unsigned)f2bf(bng[gc + 1] * (o1 * INVS) + bnb[gc + 1]) << 16)
                    | (unsigned)f2bf(bng[gc] * (o0 * INVS) + bnb[gc]);
        *(unsigned*)(void*)(x1bn + (long long)n * 256 + gc) = pk;
    }
}

// ---------- global MLP layer1 ----------
__global__ void global_mlp1_k(const float* __restrict__ pooled,
                              const float* __restrict__ w1, const float* __restrict__ b1,
                              const float* __restrict__ w2, const float* __restrict__ b2,
                              const float* __restrict__ bng, const float* __restrict__ bnb,
                              float* __restrict__ u1bn) {
    __shared__ float pr[256];
    __shared__ float h[256];
    int t = threadIdx.x, g = blockIdx.x;
    pr[t] = pooled[g * 256 + t];
    __syncthreads();
    float acc = b1[t];
    for (int k = 0; k < 256; ++k) acc += pr[k] * w1[(256 + k) * 256 + t];
    h[t] = fmaxf(acc, 0.f);
    __syncthreads();
    float a2 = b2[t];
    for (int k = 0; k < 256; ++k) a2 += h[k] * w2[k * 256 + t];
    u1bn[g * 256 + t] = bng[t] * (a2 * INVS) + bnb[t];
}

// ---------- weight prep for MFMA edge MLP2 ----------
__global__ void conv_weights_k(const float* __restrict__ w1, const float* __restrict__ w2,
                               const float* __restrict__ b1,
                               const float* __restrict__ bg, const float* __restrict__ bb,
                               short* __restrict__ w1s, short* __restrict__ w2s,
                               float* __restrict__ b1f) {
    int gid = blockIdx.x * 256 + threadIdx.x;
    if (gid < 10240) {
        int f = gid >> 6, lane = gid & 63;
        int kk = f >> 3, tt = f & 7;
        int n = tt * 16 + (lane & 15);
        int k0 = kk * 32 + (lane >> 4) * 8;
        short8 v;
        for (int j = 0; j < 8; ++j) {
            int k = k0 + j;
            float x = w1[k * 128 + n];
            if (k >= 512) x *= bg[k - 512] * INVS;
            v[j] = (short)f2bf(x);
        }
        *(short8*)(w1s + (long long)gid * 8) = v;
    } else if (gid < 12288) {
        int g2 = gid - 10240;
        int f = g2 >> 6, lane = g2 & 63;
        int kk = f >> 3, tt = f & 7;
        int n = tt * 16 + (lane & 15);
        int k0 = kk * 32 + (lane >> 4) * 8;
        short8 v;
        for (int j = 0; j < 8; ++j) v[j] = (short)f2bf(w2[(k0 + j) * 128 + n]);
        *(short8*)(w2s + (long long)g2 * 8) = v;
    } else if (gid < 12416) {
        int j = gid - 12288;
        float acc = b1[j];
        for (int c = 0; c < 128; ++c) acc += bb[c] * w1[(512 + c) * 128 + j];
        b1f[j] = acc;
    }
}

// ---------- Edge MLP 2 via MFMA, slot order, 16 slots/block (2x occupancy), in-place ----------
__global__ __launch_bounds__(256) void edge_mlp2_mfma_k(
    const bf16* __restrict__ xb, bf16* __restrict__ ea_slot,
    const int* __restrict__ csr_src, const int* __restrict__ csr_dst,
    const int* __restrict__ csr_eid,
    const short* __restrict__ w1s, const float* __restrict__ b1f,
    const short* __restrict__ w2s, const float* __restrict__ b2,
    int NT, int E) {
    __shared__ short At[16][648];
    __shared__ short Ht[16][136];
    __shared__ int sdv[16][3];
    int t = threadIdx.x;
    long long s0 = (long long)blockIdx.x * 16;
    if (t < 48) {
        int r = t & 15, which = t >> 4;
        long long s = s0 + r;
        int v = (which == 2) ? E : 0;
        if (s < NT) v = (which == 0) ? csr_src[s] : (which == 1 ? csr_dst[s] : csr_eid[s]);
        sdv[r][which] = v;
    }
    __syncthreads();
    for (int i = t; i < 16 * 80; i += 256) {
        int r = i / 80, c = i - r * 80;
        long long s = s0 + r;
        bool ok = (s < NT) && (sdv[r][2] < E);
        short8 v = {0, 0, 0, 0, 0, 0, 0, 0};
        if (ok) {
            if (c < 32)      v = *(const short8*)(const void*)(xb + (long long)sdv[r][0] * 256 + c * 8);
            else if (c < 64) v = *(const short8*)(const void*)(xb + (long long)sdv[r][1] * 256 + (c - 32) * 8);
            else             v = *(const short8*)(const void*)(ea_slot + s * 128 + (c - 64) * 8);
        }
        *(short8*)&At[r][c * 8] = v;
    }
    __syncthreads();

    int w = t >> 6, lane = t & 63;
    int lr = lane & 15, lq = lane >> 4;
    int nq = w * 2;                 // 8 n-tiles, 2 per wave

    floatx4 acc[2];
    for (int i = 0; i < 2; ++i) acc[i] = (floatx4){0.f, 0.f, 0.f, 0.f};
    for (int kk = 0; kk < 20; ++kk) {
        short8 a = *(const short8*)&At[lr][kk * 32 + lq * 8];
        for (int tt = 0; tt < 2; ++tt) {
            short8 b = *(const short8*)(w1s + ((long long)((kk * 8 + nq + tt) * 64 + lane)) * 8);
            acc[tt] = __builtin_amdgcn_mfma_f32_16x16x32_bf16(a, b, acc[tt], 0, 0, 0);
        }
    }
    for (int tt = 0; tt < 2; ++tt) {
        int col = (nq + tt) * 16 + lr;
        float bv = b1f[col];
        for (int r = 0; r < 4; ++r)
            Ht[lq * 4 + r][col] = (short)f2bf(fmaxf(acc[tt][r] + bv, 0.f));
    }
    __syncthreads();

    floatx4 acc2[2];
    for (int i = 0; i < 2; ++i) acc2[i] = (floatx4){0.f, 0.f, 0.f, 0.f};
    for (int kk = 0; kk < 4; ++kk) {
        short8 a = *(const short8*)&Ht[lr][kk * 32 + lq * 8];
        for (int tt = 0; tt < 2; ++tt) {
            short8 b = *(const short8*)(w2s + ((long long)((kk * 8 + nq + tt) * 64 + lane)) * 8);
            acc2[tt] = __builtin_amdgcn_mfma_f32_16x16x32_bf16(a, b, acc2[tt], 0, 0, 0);
        }
    }
    for (int tt = 0; tt < 2; ++tt) {
        int col = (nq + tt) * 16 + lr;
        float bv = b2[col];
        for (int r = 0; r < 4; ++r)
            At[lq * 4 + r][col] = (short)f2bf(acc2[tt][r] + bv);
    }
    __syncthreads();
    {
        int r = t >> 4, c = t & 15;
        long long s = s0 + r;
        if (s < NT && sdv[r][2] < E)
            *(short8*)(void*)(ea_slot + s * 128 + c * 8) = *(const short8*)&At[r][c * 8];
    }
}

// ---------- final global MLP + head ----------
__global__ void final_mlp_k(const float* __restrict__ u1bn, const float* __restrict__ pooled,
                            const float* __restrict__ w1, const float* __restrict__ b1,
                            const float* __restrict__ w2, const float* __restrict__ b2,
                            const float* __restrict__ f1w, const float* __restrict__ f1b,
                            const float* __restrict__ f2w, const float* __restrict__ f2b,
                            float* __restrict__ out) {
    __shared__ float ub[256], pb[256], h[256], u2[256];
    int t = threadIdx.x, g = blockIdx.x;
    ub[t] = u1bn[g * 256 + t];
    pb[t] = pooled[g * 256 + t];
    __syncthreads();
    float acc = b1[t];
    for (int k = 0; k < 256; ++k)
        acc += ub[k] * w1[k * 256 + t] + pb[k] * w1[(256 + k) * 256 + t];
    h[t] = fmaxf(acc, 0.f);
    __syncthreads();
    float a2 = b2[t];
    for (int k = 0; k < 256; ++k) a2 += h[k] * w2[k * 256 + t];
    u2[t] = a2;
    __syncthreads();
    float fv = 0.f;
    if (t < 64) {
        float a3 = f1b[t];
        for (int k = 0; k < 256; ++k) a3 += u2[k] * f1w[k * 64 + t];
        fv = fmaxf(a3, 0.f) * f2w[t];
    }
    for (int off = 32; off; off >>= 1) fv += __shfl_down(fv, off, 64);
    if (t == 0) out[g] = fv + f2b[0];
}

// ---------- launch ----------
extern "C" void kernel_launch(void* const* d_in, const int* in_sizes, int n_in,
                              void* d_out, int out_size, void* d_ws, size_t ws_size,
                              hipStream_t stream) {
    const float* x         = (const float*)d_in[0];
    const float* edge_attr = (const float*)d_in[1];
    const float* e1_w1 = (const float*)d_in[2];
    const float* e1_b1 = (const float*)d_in[3];
    const float* e1_w2 = (const float*)d_in[4];
    const float* e1_b2 = (const float*)d_in[5];
    const float* g1_lw = (const float*)d_in[6];
    const float* g1_lb = (const float*)d_in[7];
    const float* g1_rw = (const float*)d_in[8];
    const float* g1_rb = (const float*)d_in[9];
    const float* g1_ew = (const float*)d_in[10];
    const float* g1_att = (const float*)d_in[11];
    const float* g1_bias = (const float*)d_in[12];
    const float* u1_w1 = (const float*)d_in[13];
    const float* u1_b1 = (const float*)d_in[14];
    const float* u1_w2 = (const float*)d_in[15];
    const float* u1_b2 = (const float*)d_in[16];
    const float* bn_n_g = (const float*)d_in[17];
    const float* bn_n_b = (const float*)d_in[18];
    const float* bn_e_g = (const float*)d_in[19];
    const float* bn_e_b = (const float*)d_in[20];
    const float* bn_u_g = (const float*)d_in[21];
    const float* bn_u_b = (const float*)d_in[22];
    const float* e2_w1 = (const float*)d_in[23];
    const float* e2_b1 = (const float*)d_in[24];
    const float* e2_w2 = (const float*)d_in[25];
    const float* e2_b2 = (const float*)d_in[26];
    const float* g2_lw = (const float*)d_in[27];
    const float* g2_lb = (const float*)d_in[28];
    const float* g2_rw = (const float*)d_in[29];
    const float* g2_rb = (const float*)d_in[30];
    const float* g2_ew = (const float*)d_in[31];
    const float* g2_att = (const float*)d_in[32];
    const float* g2_bias = (const float*)d_in[33];
    const float* u2_w1 = (const float*)d_in[34];
    const float* u2_b1 = (const float*)d_in[35];
    const float* u2_w2 = (const float*)d_in[36];
    const float* u2_b2 = (const float*)d_in[37];
    const float* fc1_w = (const float*)d_in[38];
    const float* fc1_b = (const float*)d_in[39];
    const float* fc2_w = (const float*)d_in[40];
    const float* fc2_b = (const float*)d_in[41];
    const int* edge_index = (const int*)d_in[42];
    const int* batch = (const int*)d_in[43];

    const int N = in_sizes[0] / 64;
    const int E = in_sizes[1] / 16;
    const int NT = E + N;
    const int G = G_GRAPHS;
    const int* src = edge_index;
    const int* dst = edge_index + E;
    const int NB = (NT + 31) / 32;
    const int NB16 = (NT + 15) / 16;

    // workspace carve (~237 MB; x1bn aliases xr)
    char* p = (char*)d_ws;
    auto alloc = [&](size_t bytes) { char* r = p; p += (bytes + 255) & ~(size_t)255; return r; };
    bf16* eabuf = (bf16*)alloc((size_t)NT * 128 * 2);      // ea in CSR-slot order (NT rows)
    bf16* xl    = (bf16*)alloc((size_t)N * 256 * 2);
    bf16* xr    = (bf16*)alloc((size_t)N * 256 * 2);
    bf16* x1bn  = xr;                                      // ALIAS: read-once-by-owner before write
    bf16* eeh   = (bf16*)alloc((size_t)NT * 128 * 2);
    int* degi   = (int*)alloc((size_t)N * 4);
    int* off    = (int*)alloc((size_t)(N + 1) * 4);
    int* fillc  = (int*)alloc((size_t)N * 4);
    int* csr_src = (int*)alloc((size_t)NT * 4);
    int* csr_dst = (int*)alloc((size_t)NT * 4);
    int* csr_eid = (int*)alloc((size_t)NT * 4);
    int* slot_of = (int*)alloc((size_t)E * 4);
    float* pooled = (float*)alloc((size_t)G * 256 * 4);
    float* u1bn = (float*)alloc((size_t)G * 256 * 4);
    short* w1s  = (short*)alloc((size_t)20 * 8 * 64 * 8 * 2);
    short* w2s  = (short*)alloc((size_t)4 * 8 * 64 * 8 * 2);
    float* b1f  = (float*)alloc((size_t)128 * 4);
    short* w1s1 = (short*)alloc((size_t)5 * 4 * 64 * 8 * 2);
    short* w2s1 = (short*)alloc((size_t)2 * 8 * 64 * 8 * 2);
    short* ews1 = (short*)alloc((size_t)4 * 16 * 64 * 8 * 2);
    short* ews2 = (short*)alloc((size_t)4 * 16 * 64 * 8 * 2);
    short* nw1  = (short*)alloc((size_t)2 * 32 * 64 * 8 * 2);
    short* nw2  = (short*)alloc((size_t)8 * 32 * 64 * 8 * 2);

    // ===== CSR build =====
    hipMemsetAsync(degi, 0, (size_t)N * 4, stream);
    hipMemsetAsync(fillc, 0, (size_t)N * 4, stream);
    hipMemsetAsync(pooled, 0, (size_t)G * 256 * 4, stream);
    degi_k<<<(E + 255) / 256, 256, 0, stream>>>(dst, degi, E);
    scan_k<<<1, 1024, 0, stream>>>(degi, off, N);
    fill_csr_k<<<(max(E, N) + 255) / 256, 256, 0, stream>>>(src, dst, off, fillc,
                                                            csr_src, csr_dst, csr_eid,
                                                            slot_of, E, N);

    // ===== layer 1 =====
    conv_weights1_k<<<9, 256, 0, stream>>>(e1_w1, e1_w2, w1s1, w2s1);
    conv_ew_k<<<16, 256, 0, stream>>>(g1_ew, ews1);
    conv_ew_k<<<16, 256, 0, stream>>>(g2_ew, ews2);
    conv_nodew_k<64><<<16, 256, 0, stream>>>(g1_lw, g1_rw, nw1);
    conv_nodew_k<256><<<64, 256, 0, stream>>>(g2_lw, g2_rw, nw2);
    edge_mlp1_mfma_k<<<(E + 31) / 32, 256, 0, stream>>>(x, edge_attr, src, dst, slot_of,
                                                        w1s1, e1_b1, w2s1, e1_b2, eabuf, E);
    node_linear_mfma_k<64, float><<<(N + 15) / 16, 256, 0, stream>>>(x, nw1, g1_lb, g1_rb, xl, xr, N);
    // pass 0 (heads 0,1)
    gemm_ee_k<0><<<NB, 256, 0, stream>>>(eabuf, ews1, eeh, NT);
    loop_ee_k<<<(N + 3) / 4, 256, 0, stream>>>(eeh, off, N);
    gat_fused_k<0, true><<<(N + 3) / 4, 256, 0, stream>>>(eeh, xl, xr, off, csr_src,
                                                          g1_att, g1_bias, bn_n_g, bn_n_b,
                                                          batch, x1bn, pooled, N);
    // pass 1 (heads 2,3)
    gemm_ee_k<1><<<NB, 256, 0, stream>>>(eabuf, ews1, eeh, NT);
    loop_ee_k<<<(N + 3) / 4, 256, 0, stream>>>(eeh, off, N);
    gat_fused_k<1, true><<<(N + 3) / 4, 256, 0, stream>>>(eeh, xl, xr, off, csr_src,
                                                          g1_att, g1_bias, bn_n_g, bn_n_b,
                                                          batch, x1bn, pooled, N);
    global_mlp1_k<<<G, 256, 0, stream>>>(pooled, u1_w1, u1_b1, u1_w2, u1_b2, bn_u_g, bn_u_b, u1bn);

    // ===== layer 2 =====
    conv_weights_k<<<49, 256, 0, stream>>>(e2_w1, e2_w2, e2_b1, bn_e_g, bn_e_b, w1s, w2s, b1f);
    edge_mlp2_mfma_k<<<NB16, 256, 0, stream>>>(x1bn, eabuf, csr_src, csr_dst, csr_eid,
                                               w1s, b1f, w2s, e2_b2, NT, E);
    node_linear_mfma_k<256, bf16><<<(N + 15) / 16, 256, 0, stream>>>(x1bn, nw2, g2_lb, g2_rb, xl, xr, N);
    hipMemsetAsync(pooled, 0, (size_t)G * 256 * 4, stream);
    // pass 0
    gemm_ee_k<0><<<NB, 256, 0, stream>>>(eabuf, ews2, eeh, NT);
    loop_ee_k<<<(N + 3) / 4, 256, 0, stream>>>(eeh, off, N);
    gat_fused_k<0, false><<<(N + 3) / 4, 256, 0, stream>>>(eeh, xl, xr, off, csr_src,
                                                           g2_att, g2_bias, nullptr, nullptr,
                                                           batch, nullptr, pooled, N);
    // pass 1
    gemm_ee_k<1><<<NB, 256, 0, stream>>>(eabuf, ews2, eeh, NT);
    loop_ee_k<<<(N + 3) / 4, 256, 0, stream>>>(eeh, off, N);
    gat_fused_k<1, false><<<(N + 3) / 4, 256, 0, stream>>>(eeh, xl, xr, off, csr_src,
                                                           g2_att, g2_bias, nullptr, nullptr,
                                                           batch, nullptr, pooled, N);
    final_mlp_k<<<G, 256, 0, stream>>>(u1bn, pooled, u2_w1, u2_b1, u2_w2, u2_b2,
                                       fc1_w, fc1_b, fc2_w, fc2_b, (float*)d_out);
}

// Round 13
// 1299.407 us; speedup vs baseline: 1.0578x; 1.0578x over previous
//
#include <hip/hip_runtime.h>
#include <hip/hip_bf16.h>
#include <hip/hip_fp8.h>
#include <cstdint>
#include <cstddef>

#define INVS 0.99999500003749968f  // 1/sqrt(1+1e-5)
#define G_GRAPHS 256

using bf16 = __hip_bfloat16;
using short8 = __attribute__((ext_vector_type(8))) short;
using floatx4 = __attribute__((ext_vector_type(4))) float;

// ---------- helpers ----------
__device__ __forceinline__ unsigned short f2bf(float v) {
    union { float f; unsigned u; } x; x.f = v;
    unsigned r = x.u + 0x7fffu + ((x.u >> 16) & 1u);
    return (unsigned short)(r >> 16);
}
__device__ __forceinline__ float bfu(unsigned short u) { return __uint_as_float((unsigned)u << 16); }
__device__ __forceinline__ float bflo(unsigned u) { return __uint_as_float(u << 16); }
__device__ __forceinline__ float bfhi(unsigned u) { return __uint_as_float(u & 0xffff0000u); }
__device__ __forceinline__ unsigned char f2fp8(float v) {
    __hip_fp8_e4m3 q(v); return q.__x;
}
__device__ __forceinline__ float fp82f(unsigned char b) {
    __hip_fp8_e4m3 q; q.__x = b; return (float)q;
}

// ---------- CSR build ----------
__global__ void degi_k(const int* __restrict__ dst, int* __restrict__ degi, int E) {
    int gid = blockIdx.x * 256 + threadIdx.x;
    if (gid < E) atomicAdd(&degi[dst[gid]], 1);
}

__global__ void scan_k(const int* __restrict__ degi, int* __restrict__ off, int N) {
    __shared__ int buf[1024];
    __shared__ int carry;
    int t = threadIdx.x;
    if (t == 0) carry = 0;
    __syncthreads();
    int nch = (N + 1023) / 1024;
    for (int ch = 0; ch < nch; ++ch) {
        int idx = ch * 1024 + t;
        int v = (idx < N) ? (degi[idx] + 1) : 0;
        buf[t] = v;
        __syncthreads();
        for (int ofs = 1; ofs < 1024; ofs <<= 1) {
            int add = (t >= ofs) ? buf[t - ofs] : 0;
            __syncthreads();
            buf[t] += add;
            __syncthreads();
        }
        int incl = buf[t];
        if (idx < N) off[idx] = carry + incl - v;
        __syncthreads();
        if (t == 1023) carry += incl;
        __syncthreads();
    }
    if (t == 0) off[N] = carry;
}

__global__ void fill_csr_k(const int* __restrict__ src, const int* __restrict__ dst,
                           const int* __restrict__ off, int* __restrict__ fillc,
                           int* __restrict__ csr_src, int* __restrict__ csr_dst,
                           int* __restrict__ csr_eid, int* __restrict__ slot_of,
                           int E, int N) {
    int gid = blockIdx.x * 256 + threadIdx.x;
    if (gid < E) {
        int d = dst[gid];
        int slot = off[d] + atomicAdd(&fillc[d], 1);
        csr_src[slot] = src[gid];
        csr_dst[slot] = d;
        csr_eid[slot] = gid;
        slot_of[gid] = slot;
    }
    if (gid < N) {
        int slot = off[gid + 1] - 1;   // reserved last slot = self-loop
        csr_src[slot] = gid;
        csr_dst[slot] = gid;
        csr_eid[slot] = E + gid;       // >= E marks self-loop
    }
}

// ---------- weight prep for MFMA edge MLP1 ----------
__global__ void conv_weights1_k(const float* __restrict__ w1, const float* __restrict__ w2,
                                short* __restrict__ w1s, short* __restrict__ w2s) {
    int gid = blockIdx.x * 256 + threadIdx.x;
    if (gid < 1280) {
        int f = gid >> 6, lane = gid & 63;
        int kk = f >> 2, tt = f & 3;
        int n = tt * 16 + (lane & 15);
        int k0 = kk * 32 + (lane >> 4) * 8;
        short8 v;
        for (int j = 0; j < 8; ++j) {
            int k = k0 + j;
            v[j] = (k < 144) ? (short)f2bf(w1[k * 64 + n]) : (short)0;
        }
        *(short8*)(w1s + (long long)gid * 8) = v;
    } else if (gid < 2304) {
        int g2 = gid - 1280;
        int f = g2 >> 6, lane = g2 & 63;
        int kk = f >> 3, tt = f & 7;
        int n = tt * 16 + (lane & 15);
        int k0 = kk * 32 + (lane >> 4) * 8;
        short8 v;
        for (int j = 0; j < 8; ++j) v[j] = (short)f2bf(w2[(k0 + j) * 128 + n]);
        *(short8*)(w2s + (long long)g2 * 8) = v;
    }
}

// ---------- ew prep: ew[128][256] -> frags 4 kk x 16 tt ----------
__global__ void conv_ew_k(const float* __restrict__ ew, short* __restrict__ ews) {
    int gid = blockIdx.x * 256 + threadIdx.x;
    if (gid >= 4096) return;
    int f = gid >> 6, lane = gid & 63;
    int kk = f >> 4, tt = f & 15;
    int n = tt * 16 + (lane & 15);
    int k0 = kk * 32 + (lane >> 4) * 8;
    short8 v;
    for (int j = 0; j < 8; ++j) v[j] = (short)f2bf(ew[(k0 + j) * 256 + n]);
    *(short8*)(ews + (long long)gid * 8) = v;
}

// ---------- node-linear weight prep: [wl|wr] (K x 512) -> frags ----------
template <int K>
__global__ void conv_nodew_k(const float* __restrict__ wl, const float* __restrict__ wr,
                             short* __restrict__ out) {
    int gid = blockIdx.x * 256 + threadIdx.x;
    if (gid >= (K / 32) * 32 * 64) return;
    int f = gid >> 6, lane = gid & 63;
    int kk = f >> 5, tt = f & 31;
    int n = tt * 16 + (lane & 15);
    int k0 = kk * 32 + (lane >> 4) * 8;
    short8 v;
    for (int j = 0; j < 8; ++j) {
        int k = k0 + j;
        float x = (n < 256) ? wl[k * 256 + n] : wr[k * 256 + (n - 256)];
        v[j] = (short)f2bf(x);
    }
    *(short8*)(out + (long long)gid * 8) = v;
}

// ---------- Edge MLP 1 via MFMA: eid-order compute, scatter rows to CSR slots ----------
__global__ __launch_bounds__(256) void edge_mlp1_mfma_k(
    const float* __restrict__ x, const float* __restrict__ ea,
    const int* __restrict__ src, const int* __restrict__ dst,
    const int* __restrict__ slot_of,
    const short* __restrict__ w1s, const float* __restrict__ b1,
    const short* __restrict__ w2s, const float* __restrict__ b2,
    bf16* __restrict__ out, int E) {
    __shared__ short At[32][168];
    __shared__ short Ht[32][72];
    __shared__ int sdv[32][2];
    __shared__ int slt[32];
    int t = threadIdx.x;
    long long e0 = (long long)blockIdx.x * 32;
    if (t < 64) {
        int r = t & 31;
        long long e = e0 + r;
        int v = 0;
        if (e < E) v = (t < 32) ? src[e] : dst[e];
        sdv[r][t >> 5] = v;
    } else if (t < 96) {
        int r = t - 64;
        long long e = e0 + r;
        slt[r] = (e < E) ? slot_of[e] : -1;
    }
    __syncthreads();
    for (int i = t; i < 32 * 40; i += 256) {
        int r = i / 40, c = i - r * 40;
        long long e = e0 + r;
        float4 v = {0.f, 0.f, 0.f, 0.f};
        if (e < E) {
            if (c < 16)      v = *(const float4*)(x + (long long)sdv[r][0] * 64 + c * 4);
            else if (c < 32) v = *(const float4*)(x + (long long)sdv[r][1] * 64 + (c - 16) * 4);
            else if (c < 36) v = *(const float4*)(ea + e * 16 + (c - 32) * 4);
        }
        union { ushort4 u4; unsigned short s4[4]; } pk;
        pk.s4[0] = f2bf(v.x); pk.s4[1] = f2bf(v.y); pk.s4[2] = f2bf(v.z); pk.s4[3] = f2bf(v.w);
        *(ushort4*)&At[r][c * 4] = pk.u4;
    }
    __syncthreads();

    int w = t >> 6, lane = t & 63;
    int m0 = (w & 1) * 16;
    int lr = lane & 15, lq = lane >> 4;

    int nq1 = (w >> 1) * 2;
    floatx4 acc[2];
    for (int i = 0; i < 2; ++i) acc[i] = (floatx4){0.f, 0.f, 0.f, 0.f};
    for (int kk = 0; kk < 5; ++kk) {
        short8 a = *(const short8*)&At[m0 + lr][kk * 32 + lq * 8];
        for (int tt = 0; tt < 2; ++tt) {
            short8 b = *(const short8*)(w1s + ((long long)((kk * 4 + nq1 + tt) * 64 + lane)) * 8);
            acc[tt] = __builtin_amdgcn_mfma_f32_16x16x32_bf16(a, b, acc[tt], 0, 0, 0);
        }
    }
    for (int tt = 0; tt < 2; ++tt) {
        int col = (nq1 + tt) * 16 + lr;
        float bv = b1[col];
        for (int r = 0; r < 4; ++r)
            Ht[m0 + lq * 4 + r][col] = (short)f2bf(fmaxf(acc[tt][r] + bv, 0.f));
    }
    __syncthreads();

    int nq2 = (w >> 1) * 4;
    floatx4 acc2[4];
    for (int i = 0; i < 4; ++i) acc2[i] = (floatx4){0.f, 0.f, 0.f, 0.f};
    for (int kk = 0; kk < 2; ++kk) {
        short8 a = *(const short8*)&Ht[m0 + lr][kk * 32 + lq * 8];
        for (int tt = 0; tt < 4; ++tt) {
            short8 b = *(const short8*)(w2s + ((long long)((kk * 8 + nq2 + tt) * 64 + lane)) * 8);
            acc2[tt] = __builtin_amdgcn_mfma_f32_16x16x32_bf16(a, b, acc2[tt], 0, 0, 0);
        }
    }
    for (int tt = 0; tt < 4; ++tt) {
        int col = (nq2 + tt) * 16 + lr;
        float bv = b2[col];
        for (int r = 0; r < 4; ++r)
            At[m0 + lq * 4 + r][col] = (short)f2bf(acc2[tt][r] + bv);
    }
    __syncthreads();
    for (int i = t; i < 512; i += 256) {
        int r = i >> 4, c = i & 15;
        int s = slt[r];
        if (s >= 0)
            *(short8*)(void*)(out + (long long)s * 128 + c * 8) = *(const short8*)&At[r][c * 8];
    }
}

// ---------- node linear via MFMA: [N x K] @ [K x 512] (= [wl|wr]) + bias ----------
// NOTE: x may alias xr (x1bn overlay) — per-block reads complete before same-row writes.
template <int K, typename T>
__global__ __launch_bounds__(256) void node_linear_mfma_k(
    const T* x, const short* __restrict__ ws,
    const float* __restrict__ bl, const float* __restrict__ br,
    bf16* __restrict__ xl, bf16* xr, int N) {
    __shared__ short At[16][K + 8];
    __shared__ short Ot[16][520];
    int t = threadIdx.x;
    long long n0 = (long long)blockIdx.x * 16;
    if (sizeof(T) == 4) {
        for (int i = t; i < 16 * (K / 4); i += 256) {
            int r = i / (K / 4), c = i % (K / 4);
            long long n = n0 + r;
            float4 v = {0.f, 0.f, 0.f, 0.f};
            if (n < N) v = *(const float4*)((const float*)x + n * K + c * 4);
            union { ushort4 u4; unsigned short s4[4]; } pk;
            pk.s4[0] = f2bf(v.x); pk.s4[1] = f2bf(v.y); pk.s4[2] = f2bf(v.z); pk.s4[3] = f2bf(v.w);
            *(ushort4*)&At[r][c * 4] = pk.u4;
        }
    } else {
        for (int i = t; i < 16 * (K / 8); i += 256) {
            int r = i / (K / 8), c = i % (K / 8);
            long long n = n0 + r;
            short8 v = {0, 0, 0, 0, 0, 0, 0, 0};
            if (n < N) v = *(const short8*)(const void*)((const bf16*)x + n * K + c * 8);
            *(short8*)&At[r][c * 8] = v;
        }
    }
    __syncthreads();

    int w = t >> 6, lane = t & 63;
    int nq = w * 8;
    int lr = lane & 15, lq = lane >> 4;

    floatx4 acc[8];
    for (int i = 0; i < 8; ++i) acc[i] = (floatx4){0.f, 0.f, 0.f, 0.f};
    for (int kk = 0; kk < K / 32; ++kk) {
        short8 a = *(const short8*)&At[lr][kk * 32 + lq * 8];
        for (int tt = 0; tt < 8; ++tt) {
            short8 b = *(const short8*)(ws + ((long long)((kk * 32 + nq + tt) * 64 + lane)) * 8);
            acc[tt] = __builtin_amdgcn_mfma_f32_16x16x32_bf16(a, b, acc[tt], 0, 0, 0);
        }
    }
    for (int tt = 0; tt < 8; ++tt) {
        int col = (nq + tt) * 16 + lr;
        float bv = (col < 256) ? bl[col] : br[col - 256];
        for (int r = 0; r < 4; ++r)
            Ot[lq * 4 + r][col] = (short)f2bf(acc[tt][r] + bv);
    }
    __syncthreads();
    for (int i = t; i < 1024; i += 256) {
        int r = i >> 6, c = i & 63;
        long long n = n0 + r;
        if (n < N) {
            short8 v = *(const short8*)&Ot[r][c * 8];
            if (c < 32) *(short8*)(void*)(xl + n * 256 + c * 8) = v;
            else        *(short8*)(void*)(xr + n * 256 + (c - 32) * 8) = v;
        }
    }
}

// ---------- ee GEMM, full 256 channels, fp8 out, slot order ----------
__global__ __launch_bounds__(256) void gemm_ee_k(
    const bf16* __restrict__ ea_slot, const short* __restrict__ ews,
    unsigned char* __restrict__ ee8, int NT) {
    __shared__ short At[32][136];
    __shared__ unsigned char Et[32][264];
    int t = threadIdx.x;
    long long s0 = (long long)blockIdx.x * 32;
    for (int i = t; i < 32 * 16; i += 256) {
        int r = i >> 4, c = i & 15;
        long long s = s0 + r;
        short8 v = {0, 0, 0, 0, 0, 0, 0, 0};
        if (s < NT) v = *(const short8*)(const void*)(ea_slot + s * 128 + c * 8);
        *(short8*)&At[r][c * 8] = v;
    }
    __syncthreads();

    int w = t >> 6, lane = t & 63;
    int m0 = (w & 1) * 16, nq = (w >> 1) * 8;   // 16 n-tiles, 8 per wave-pair
    int lr = lane & 15, lq = lane >> 4;

    floatx4 acc[8];
    for (int i = 0; i < 8; ++i) acc[i] = (floatx4){0.f, 0.f, 0.f, 0.f};
    for (int kk = 0; kk < 4; ++kk) {
        short8 a = *(const short8*)&At[m0 + lr][kk * 32 + lq * 8];
        for (int tt = 0; tt < 8; ++tt) {
            short8 b = *(const short8*)(ews + ((long long)((kk * 16 + nq + tt) * 64 + lane)) * 8);
            acc[tt] = __builtin_amdgcn_mfma_f32_16x16x32_bf16(a, b, acc[tt], 0, 0, 0);
        }
    }
    for (int tt = 0; tt < 8; ++tt) {
        int col = (nq + tt) * 16 + lr;
        for (int r = 0; r < 4; ++r)
            Et[m0 + lq * 4 + r][col] = f2fp8(acc[tt][r]);
    }
    __syncthreads();
    // coalesced write: 32 rows x 64 u32
    for (int i = t; i < 2048; i += 256) {
        int r = i >> 6, c = i & 63;
        long long s = s0 + r;
        if (s < NT)
            *(unsigned*)(ee8 + s * 256 + c * 4) = *(const unsigned*)&Et[r][c * 4];
    }
}

// ---------- self-loop ee = mean of incoming ee rows (fp8) ----------
__global__ __launch_bounds__(256) void loop_ee_k(unsigned char* __restrict__ ee8,
                                                 const int* __restrict__ off, int N) {
    int t = threadIdx.x;
    int w = t >> 6, lane = t & 63;
    int n = blockIdx.x * 4 + w;
    if (n >= N) return;
    int beg = off[n], end = off[n + 1] - 1;
    float a0 = 0.f, a1 = 0.f, a2 = 0.f, a3 = 0.f;
    for (int i = beg; i < end; ++i) {
        unsigned pk = *(const unsigned*)(ee8 + (long long)i * 256 + lane * 4);
        a0 += fp82f(pk & 0xff);
        a1 += fp82f((pk >> 8) & 0xff);
        a2 += fp82f((pk >> 16) & 0xff);
        a3 += fp82f(pk >> 24);
    }
    float dv = fmaxf((float)(end - beg), 1.f);
    unsigned o = (unsigned)f2fp8(a0 / dv)
               | ((unsigned)f2fp8(a1 / dv) << 8)
               | ((unsigned)f2fp8(a2 / dv) << 16)
               | ((unsigned)f2fp8(a3 / dv) << 24);
    *(unsigned*)(ee8 + (long long)end * 256 + lane * 4) = o;
}

// ---------- Fused GATv2 attention + aggregation + finalize, single pass, all 4 heads ----------
// Wave per node; lane handles 4 channels; head = lane>>4 (16 lanes x 4ch = 64ch/head).
// NOTE: x1bn may alias xr — xr[n] is read only by the owning wave, before its write.
template <bool L1>
__global__ __launch_bounds__(256) void gat_fused_k(
    const unsigned char* __restrict__ ee8, const bf16* __restrict__ xl, const bf16* xr,
    const int* __restrict__ off, const int* __restrict__ csr_src,
    const float* __restrict__ att, const float* __restrict__ bias,
    const float* __restrict__ bng, const float* __restrict__ bnb,
    const int* __restrict__ batch,
    bf16* x1bn, float* __restrict__ pooled, int N) {
    int t = threadIdx.x;
    int w = t >> 6, lane = t & 63;
    int n = blockIdx.x * 4 + w;
    if (n >= N) return;
    int c0 = lane * 4;
    union { ushort4 u4; unsigned short s4[4]; } xrp;
    xrp.u4 = *(const ushort4*)(const void*)(xr + (long long)n * 256 + c0);
    float xr0 = bfu(xrp.s4[0]), xr1 = bfu(xrp.s4[1]), xr2 = bfu(xrp.s4[2]), xr3 = bfu(xrp.s4[3]);
    float4 atv = *(const float4*)(att + c0);
    float a0 = 0.f, a1 = 0.f, a2 = 0.f, a3 = 0.f, dacc = 0.f;
    int beg = off[n], end = off[n + 1];
    for (int i = beg; i < end; ++i) {
        int sid = csr_src[i];
        union { ushort4 u4; unsigned short s4[4]; } xlp;
        xlp.u4 = *(const ushort4*)(const void*)(xl + (long long)sid * 256 + c0);
        unsigned ep = *(const unsigned*)(ee8 + (long long)i * 256 + c0);
        float x0 = bfu(xlp.s4[0]), x1 = bfu(xlp.s4[1]), x2 = bfu(xlp.s4[2]), x3 = bfu(xlp.s4[3]);
        float m0 = x0 + xr0 + fp82f(ep & 0xff);
        float m1 = x1 + xr1 + fp82f((ep >> 8) & 0xff);
        float m2 = x2 + xr2 + fp82f((ep >> 16) & 0xff);
        float m3 = x3 + xr3 + fp82f(ep >> 24);
        m0 = m0 > 0.f ? m0 : 0.2f * m0;
        m1 = m1 > 0.f ? m1 : 0.2f * m1;
        m2 = m2 > 0.f ? m2 : 0.2f * m2;
        m3 = m3 > 0.f ? m3 : 0.2f * m3;
        float p = atv.x * m0 + atv.y * m1 + atv.z * m2 + atv.w * m3;
        p += __shfl_xor(p, 1, 64);
        p += __shfl_xor(p, 2, 64);
        p += __shfl_xor(p, 4, 64);
        p += __shfl_xor(p, 8, 64);   // sum over 16 lanes = one head
        float ex = expf(p);
        a0 += ex * x0; a1 += ex * x1; a2 += ex * x2; a3 += ex * x3;
        dacc += ex;
    }
    float inv = 1.f / dacc;
    float o0 = fmaxf(a0 * inv + bias[c0],     0.f);
    float o1 = fmaxf(a1 * inv + bias[c0 + 1], 0.f);
    float o2 = fmaxf(a2 * inv + bias[c0 + 2], 0.f);
    float o3 = fmaxf(a3 * inv + bias[c0 + 3], 0.f);
    long long pb = (long long)batch[n] * 256 + c0;
    atomicAdd(&pooled[pb],     o0);
    atomicAdd(&pooled[pb + 1], o1);
    atomicAdd(&pooled[pb + 2], o2);
    atomicAdd(&pooled[pb + 3], o3);
    if (L1) {
        union { ushort4 u4; unsigned short s4[4]; } o;
        o.s4[0] = f2bf(bng[c0]     * (o0 * INVS) + bnb[c0]);
        o.s4[1] = f2bf(bng[c0 + 1] * (o1 * INVS) + bnb[c0 + 1]);
        o.s4[2] = f2bf(bng[c0 + 2] * (o2 * INVS) + bnb[c0 + 2]);
        o.s4[3] = f2bf(bng[c0 + 3] * (o3 * INVS) + bnb[c0 + 3]);
        *(ushort4*)(void*)(x1bn + (long long)n * 256 + c0) = o.u4;
    }
}

// ---------- global MLP layer1 ----------
__global__ void global_mlp1_k(const float* __restrict__ pooled,
                              const float* __restrict__ w1, const float* __restrict__ b1,
                              const float* __restrict__ w2, const float* __restrict__ b2,
                              const float* __restrict__ bng, const float* __restrict__ bnb,
                              float* __restrict__ u1bn) {
    __shared__ float pr[256];
    __shared__ float h[256];
    int t = threadIdx.x, g = blockIdx.x;
    pr[t] = pooled[g * 256 + t];
    __syncthreads();
    float acc = b1[t];
    for (int k = 0; k < 256; ++k) acc += pr[k] * w1[(256 + k) * 256 + t];
    h[t] = fmaxf(acc, 0.f);
    __syncthreads();
    float a2 = b2[t];
    for (int k = 0; k < 256; ++k) a2 += h[k] * w2[k * 256 + t];
    u1bn[g * 256 + t] = bng[t] * (a2 * INVS) + bnb[t];
}

// ---------- weight prep for MFMA edge MLP2 ----------
__global__ void conv_weights_k(const float* __restrict__ w1, const float* __restrict__ w2,
                               const float* __restrict__ b1,
                               const float* __restrict__ bg, const float* __restrict__ bb,
                               short* __restrict__ w1s, short* __restrict__ w2s,
                               float* __restrict__ b1f) {
    int gid = blockIdx.x * 256 + threadIdx.x;
    if (gid < 10240) {
        int f = gid >> 6, lane = gid & 63;
        int kk = f >> 3, tt = f & 7;
        int n = tt * 16 + (lane & 15);
        int k0 = kk * 32 + (lane >> 4) * 8;
        short8 v;
        for (int j = 0; j < 8; ++j) {
            int k = k0 + j;
            float x = w1[k * 128 + n];
            if (k >= 512) x *= bg[k - 512] * INVS;
            v[j] = (short)f2bf(x);
        }
        *(short8*)(w1s + (long long)gid * 8) = v;
    } else if (gid < 12288) {
        int g2 = gid - 10240;
        int f = g2 >> 6, lane = g2 & 63;
        int kk = f >> 3, tt = f & 7;
        int n = tt * 16 + (lane & 15);
        int k0 = kk * 32 + (lane >> 4) * 8;
        short8 v;
        for (int j = 0; j < 8; ++j) v[j] = (short)f2bf(w2[(k0 + j) * 128 + n]);
        *(short8*)(w2s + (long long)g2 * 8) = v;
    } else if (gid < 12416) {
        int j = gid - 12288;
        float acc = b1[j];
        for (int c = 0; c < 128; ++c) acc += bb[c] * w1[(512 + c) * 128 + j];
        b1f[j] = acc;
    }
}

// ---------- Edge MLP 2 via MFMA, slot order, 32 slots/block, in-place on ea_slot ----------
__global__ __launch_bounds__(256) void edge_mlp2_mfma_k(
    const bf16* __restrict__ xb, bf16* __restrict__ ea_slot,
    const int* __restrict__ csr_src, const int* __restrict__ csr_dst,
    const int* __restrict__ csr_eid,
    const short* __restrict__ w1s, const float* __restrict__ b1f,
    const short* __restrict__ w2s, const float* __restrict__ b2,
    int NT, int E) {
    __shared__ short At[32][648];
    __shared__ short Ht[32][136];
    __shared__ int sdv[32][3];
    int t = threadIdx.x;
    long long s0 = (long long)blockIdx.x * 32;
    if (t < 96) {
        int r = t & 31, which = t >> 5;
        long long s = s0 + r;
        int v = (which == 2) ? E : 0;
        if (s < NT) v = (which == 0) ? csr_src[s] : (which == 1 ? csr_dst[s] : csr_eid[s]);
        sdv[r][which] = v;
    }
    __syncthreads();
    for (int i = t; i < 32 * 80; i += 256) {
        int r = i / 80, c = i - r * 80;
        long long s = s0 + r;
        bool ok = (s < NT) && (sdv[r][2] < E);
        short8 v = {0, 0, 0, 0, 0, 0, 0, 0};
        if (ok) {
            if (c < 32)      v = *(const short8*)(const void*)(xb + (long long)sdv[r][0] * 256 + c * 8);
            else if (c < 64) v = *(const short8*)(const void*)(xb + (long long)sdv[r][1] * 256 + (c - 32) * 8);
            else             v = *(const short8*)(const void*)(ea_slot + s * 128 + (c - 64) * 8);
        }
        *(short8*)&At[r][c * 8] = v;
    }
    __syncthreads();

    int w = t >> 6, lane = t & 63;
    int m0 = (w & 1) * 16;
    int nq = (w >> 1) * 4;
    int lr = lane & 15, lq = lane >> 4;

    floatx4 acc[4];
    for (int i = 0; i < 4; ++i) acc[i] = (floatx4){0.f, 0.f, 0.f, 0.f};
    for (int kk = 0; kk < 20; ++kk) {
        short8 a = *(const short8*)&At[m0 + lr][kk * 32 + lq * 8];
        for (int tt = 0; tt < 4; ++tt) {
            short8 b = *(const short8*)(w1s + ((long long)((kk * 8 + nq + tt) * 64 + lane)) * 8);
            acc[tt] = __builtin_amdgcn_mfma_f32_16x16x32_bf16(a, b, acc[tt], 0, 0, 0);
        }
    }
    for (int tt = 0; tt < 4; ++tt) {
        int col = (nq + tt) * 16 + lr;
        float bv = b1f[col];
        for (int r = 0; r < 4; ++r)
            Ht[m0 + lq * 4 + r][col] = (short)f2bf(fmaxf(acc[tt][r] + bv, 0.f));
    }
    __syncthreads();

    floatx4 acc2[4];
    for (int i = 0; i < 4; ++i) acc2[i] = (floatx4){0.f, 0.f, 0.f, 0.f};
    for (int kk = 0; kk < 4; ++kk) {
        short8 a = *(const short8*)&Ht[m0 + lr][kk * 32 + lq * 8];
        for (int tt = 0; tt < 4; ++tt) {
            short8 b = *(const short8*)(w2s + ((long long)((kk * 8 + nq + tt) * 64 + lane)) * 8);
            acc2[tt] = __builtin_amdgcn_mfma_f32_16x16x32_bf16(a, b, acc2[tt], 0, 0, 0);
        }
    }
    for (int tt = 0; tt < 4; ++tt) {
        int col = (nq + tt) * 16 + lr;
        float bv = b2[col];
        for (int r = 0; r < 4; ++r)
            At[m0 + lq * 4 + r][col] = (short)f2bf(acc2[tt][r] + bv);
    }
    __syncthreads();
    for (int i = t; i < 512; i += 256) {
        int r = i >> 4, c = i & 15;
        long long s = s0 + r;
        if (s < NT && sdv[r][2] < E)
            *(short8*)(void*)(ea_slot + s * 128 + c * 8) = *(const short8*)&At[r][c * 8];
    }
}

// ---------- final global MLP + head ----------
__global__ void final_mlp_k(const float* __restrict__ u1bn, const float* __restrict__ pooled,
                            const float* __restrict__ w1, const float* __restrict__ b1,
                            const float* __restrict__ w2, const float* __restrict__ b2,
                            const float* __restrict__ f1w, const float* __restrict__ f1b,
                            const float* __restrict__ f2w, const float* __restrict__ f2b,
                            float* __restrict__ out) {
    __shared__ float ub[256], pb[256], h[256], u2[256];
    int t = threadIdx.x, g = blockIdx.x;
    ub[t] = u1bn[g * 256 + t];
    pb[t] = pooled[g * 256 + t];
    __syncthreads();
    float acc = b1[t];
    for (int k = 0; k < 256; ++k)
        acc += ub[k] * w1[k * 256 + t] + pb[k] * w1[(256 + k) * 256 + t];
    h[t] = fmaxf(acc, 0.f);
    __syncthreads();
    float a2 = b2[t];
    for (int k = 0; k < 256; ++k) a2 += h[k] * w2[k * 256 + t];
    u2[t] = a2;
    __syncthreads();
    float fv = 0.f;
    if (t < 64) {
        float a3 = f1b[t];
        for (int k = 0; k < 256; ++k) a3 += u2[k] * f1w[k * 64 + t];
        fv = fmaxf(a3, 0.f) * f2w[t];
    }
    for (int off = 32; off; off >>= 1) fv += __shfl_down(fv, off, 64);
    if (t == 0) out[g] = fv + f2b[0];
}

// ---------- launch ----------
extern "C" void kernel_launch(void* const* d_in, const int* in_sizes, int n_in,
                              void* d_out, int out_size, void* d_ws, size_t ws_size,
                              hipStream_t stream) {
    const float* x         = (const float*)d_in[0];
    const float* edge_attr = (const float*)d_in[1];
    const float* e1_w1 = (const float*)d_in[2];
    const float* e1_b1 = (const float*)d_in[3];
    const float* e1_w2 = (const float*)d_in[4];
    const float* e1_b2 = (const float*)d_in[5];
    const float* g1_lw = (const float*)d_in[6];
    const float* g1_lb = (const float*)d_in[7];
    const float* g1_rw = (const float*)d_in[8];
    const float* g1_rb = (const float*)d_in[9];
    const float* g1_ew = (const float*)d_in[10];
    const float* g1_att = (const float*)d_in[11];
    const float* g1_bias = (const float*)d_in[12];
    const float* u1_w1 = (const float*)d_in[13];
    const float* u1_b1 = (const float*)d_in[14];
    const float* u1_w2 = (const float*)d_in[15];
    const float* u1_b2 = (const float*)d_in[16];
    const float* bn_n_g = (const float*)d_in[17];
    const float* bn_n_b = (const float*)d_in[18];
    const float* bn_e_g = (const float*)d_in[19];
    const float* bn_e_b = (const float*)d_in[20];
    const float* bn_u_g = (const float*)d_in[21];
    const float* bn_u_b = (const float*)d_in[22];
    const float* e2_w1 = (const float*)d_in[23];
    const float* e2_b1 = (const float*)d_in[24];
    const float* e2_w2 = (const float*)d_in[25];
    const float* e2_b2 = (const float*)d_in[26];
    const float* g2_lw = (const float*)d_in[27];
    const float* g2_lb = (const float*)d_in[28];
    const float* g2_rw = (const float*)d_in[29];
    const float* g2_rb = (const float*)d_in[30];
    const float* g2_ew = (const float*)d_in[31];
    const float* g2_att = (const float*)d_in[32];
    const float* g2_bias = (const float*)d_in[33];
    const float* u2_w1 = (const float*)d_in[34];
    const float* u2_b1 = (const float*)d_in[35];
    const float* u2_w2 = (const float*)d_in[36];
    const float* u2_b2 = (const float*)d_in[37];
    const float* fc1_w = (const float*)d_in[38];
    const float* fc1_b = (const float*)d_in[39];
    const float* fc2_w = (const float*)d_in[40];
    const float* fc2_b = (const float*)d_in[41];
    const int* edge_index = (const int*)d_in[42];
    const int* batch = (const int*)d_in[43];

    const int N = in_sizes[0] / 64;
    const int E = in_sizes[1] / 16;
    const int NT = E + N;
    const int G = G_GRAPHS;
    const int* src = edge_index;
    const int* dst = edge_index + E;
    const int NB = (NT + 31) / 32;

    // workspace carve (~237 MB; x1bn aliases xr; ee8 = fp8 full-width, same 90 MB as old half-bf16)
    char* p = (char*)d_ws;
    auto alloc = [&](size_t bytes) { char* r = p; p += (bytes + 255) & ~(size_t)255; return r; };
    bf16* eabuf = (bf16*)alloc((size_t)NT * 128 * 2);      // ea in CSR-slot order (NT rows)
    bf16* xl    = (bf16*)alloc((size_t)N * 256 * 2);
    bf16* xr    = (bf16*)alloc((size_t)N * 256 * 2);
    bf16* x1bn  = xr;                                      // ALIAS: read-once-by-owner before write
    unsigned char* ee8 = (unsigned char*)alloc((size_t)NT * 256);
    int* degi   = (int*)alloc((size_t)N * 4);
    int* off    = (int*)alloc((size_t)(N + 1) * 4);
    int* fillc  = (int*)alloc((size_t)N * 4);
    int* csr_src = (int*)alloc((size_t)NT * 4);
    int* csr_dst = (int*)alloc((size_t)NT * 4);
    int* csr_eid = (int*)alloc((size_t)NT * 4);
    int* slot_of = (int*)alloc((size_t)E * 4);
    float* pooled = (float*)alloc((size_t)G * 256 * 4);
    float* u1bn = (float*)alloc((size_t)G * 256 * 4);
    short* w1s  = (short*)alloc((size_t)20 * 8 * 64 * 8 * 2);
    short* w2s  = (short*)alloc((size_t)4 * 8 * 64 * 8 * 2);
    float* b1f  = (float*)alloc((size_t)128 * 4);
    short* w1s1 = (short*)alloc((size_t)5 * 4 * 64 * 8 * 2);
    short* w2s1 = (short*)alloc((size_t)2 * 8 * 64 * 8 * 2);
    short* ews1 = (short*)alloc((size_t)4 * 16 * 64 * 8 * 2);
    short* ews2 = (short*)alloc((size_t)4 * 16 * 64 * 8 * 2);
    short* nw1  = (short*)alloc((size_t)2 * 32 * 64 * 8 * 2);
    short* nw2  = (short*)alloc((size_t)8 * 32 * 64 * 8 * 2);

    // ===== CSR build =====
    hipMemsetAsync(degi, 0, (size_t)N * 4, stream);
    hipMemsetAsync(fillc, 0, (size_t)N * 4, stream);
    hipMemsetAsync(pooled, 0, (size_t)G * 256 * 4, stream);
    degi_k<<<(E + 255) / 256, 256, 0, stream>>>(dst, degi, E);
    scan_k<<<1, 1024, 0, stream>>>(degi, off, N);
    fill_csr_k<<<(max(E, N) + 255) / 256, 256, 0, stream>>>(src, dst, off, fillc,
                                                            csr_src, csr_dst, csr_eid,
                                                            slot_of, E, N);

    // ===== layer 1 =====
    conv_weights1_k<<<9, 256, 0, stream>>>(e1_w1, e1_w2, w1s1, w2s1);
    conv_ew_k<<<16, 256, 0, stream>>>(g1_ew, ews1);
    conv_ew_k<<<16, 256, 0, stream>>>(g2_ew, ews2);
    conv_nodew_k<64><<<16, 256, 0, stream>>>(g1_lw, g1_rw, nw1);
    conv_nodew_k<256><<<64, 256, 0, stream>>>(g2_lw, g2_rw, nw2);
    edge_mlp1_mfma_k<<<(E + 31) / 32, 256, 0, stream>>>(x, edge_attr, src, dst, slot_of,
                                                        w1s1, e1_b1, w2s1, e1_b2, eabuf, E);
    node_linear_mfma_k<64, float><<<(N + 15) / 16, 256, 0, stream>>>(x, nw1, g1_lb, g1_rb, xl, xr, N);
    gemm_ee_k<<<NB, 256, 0, stream>>>(eabuf, ews1, ee8, NT);
    loop_ee_k<<<(N + 3) / 4, 256, 0, stream>>>(ee8, off, N);
    gat_fused_k<true><<<(N + 3) / 4, 256, 0, stream>>>(ee8, xl, xr, off, csr_src,
                                                       g1_att, g1_bias, bn_n_g, bn_n_b,
                                                       batch, x1bn, pooled, N);
    global_mlp1_k<<<G, 256, 0, stream>>>(pooled, u1_w1, u1_b1, u1_w2, u1_b2, bn_u_g, bn_u_b, u1bn);

    // ===== layer 2 =====
    conv_weights_k<<<49, 256, 0, stream>>>(e2_w1, e2_w2, e2_b1, bn_e_g, bn_e_b, w1s, w2s, b1f);
    edge_mlp2_mfma_k<<<NB, 256, 0, stream>>>(x1bn, eabuf, csr_src, csr_dst, csr_eid,
                                             w1s, b1f, w2s, e2_b2, NT, E);
    node_linear_mfma_k<256, bf16><<<(N + 15) / 16, 256, 0, stream>>>(x1bn, nw2, g2_lb, g2_rb, xl, xr, N);
    hipMemsetAsync(pooled, 0, (size_t)G * 256 * 4, stream);
    gemm_ee_k<<<NB, 256, 0, stream>>>(eabuf, ews2, ee8, NT);
    loop_ee_k<<<(N + 3) / 4, 256, 0, stream>>>(ee8, off, N);
    gat_fused_k<false><<<(N + 3) / 4, 256, 0, stream>>>(ee8, xl, xr, off, csr_src,
                                                        g2_att, g2_bias, nullptr, nullptr,
                                                        batch, nullptr, pooled, N);
    final_mlp_k<<<G, 256, 0, stream>>>(u1bn, pooled, u2_w1, u2_b1, u2_w2, u2_b2,
                                       fc1_w, fc1_b, fc2_w, fc2_b, (float*)d_out);
}

// Round 14
// 1197.901 us; speedup vs baseline: 1.1474x; 1.0847x over previous
//
#include <hip/hip_runtime.h>
#include <hip/hip_bf16.h>
#include <hip/hip_fp8.h>
#include <cstdint>
#include <cstddef>

#define INVS 0.99999500003749968f  // 1/sqrt(1+1e-5)
#define G_GRAPHS 256

using bf16 = __hip_bfloat16;
using short8 = __attribute__((ext_vector_type(8))) short;
using floatx4 = __attribute__((ext_vector_type(4))) float;

// ---------- helpers ----------
__device__ __forceinline__ unsigned short f2bf(float v) {
    union { float f; unsigned u; } x; x.f = v;
    unsigned r = x.u + 0x7fffu + ((x.u >> 16) & 1u);
    return (unsigned short)(r >> 16);
}
__device__ __forceinline__ float bfu(unsigned short u) { return __uint_as_float((unsigned)u << 16); }
__device__ __forceinline__ unsigned char f2fp8(float v) {
    __hip_fp8_e4m3 q(v); return q.__x;
}
__device__ __forceinline__ float fp82f(unsigned char b) {
    __hip_fp8_e4m3 q; q.__x = b; return (float)q;
}

// ---------- CSR build ----------
__global__ void degi_k(const int* __restrict__ dst, int* __restrict__ degi, int E) {
    int gid = blockIdx.x * 256 + threadIdx.x;
    if (gid < E) atomicAdd(&degi[dst[gid]], 1);
}

__global__ void scan_k(const int* __restrict__ degi, int* __restrict__ off, int N) {
    __shared__ int buf[1024];
    __shared__ int carry;
    int t = threadIdx.x;
    if (t == 0) carry = 0;
    __syncthreads();
    int nch = (N + 1023) / 1024;
    for (int ch = 0; ch < nch; ++ch) {
        int idx = ch * 1024 + t;
        int v = (idx < N) ? (degi[idx] + 1) : 0;
        buf[t] = v;
        __syncthreads();
        for (int ofs = 1; ofs < 1024; ofs <<= 1) {
            int add = (t >= ofs) ? buf[t - ofs] : 0;
            __syncthreads();
            buf[t] += add;
            __syncthreads();
        }
        int incl = buf[t];
        if (idx < N) off[idx] = carry + incl - v;
        __syncthreads();
        if (t == 1023) carry += incl;
        __syncthreads();
    }
    if (t == 0) off[N] = carry;
}

__global__ void fill_csr_k(const int* __restrict__ src, const int* __restrict__ dst,
                           const int* __restrict__ off, int* __restrict__ fillc,
                           int* __restrict__ csr_src, int* __restrict__ csr_dst,
                           int* __restrict__ csr_eid, int* __restrict__ slot_of,
                           int E, int N) {
    int gid = blockIdx.x * 256 + threadIdx.x;
    if (gid < E) {
        int d = dst[gid];
        int slot = off[d] + atomicAdd(&fillc[d], 1);
        csr_src[slot] = src[gid];
        csr_dst[slot] = d;
        csr_eid[slot] = gid;
        slot_of[gid] = slot;
    }
    if (gid < N) {
        int slot = off[gid + 1] - 1;   // reserved last slot = self-loop
        csr_src[slot] = gid;
        csr_dst[slot] = gid;
        csr_eid[slot] = E + gid;       // >= E marks self-loop
    }
}

// ---------- weight prep for MFMA edge MLP1 ----------
__global__ void conv_weights1_k(const float* __restrict__ w1, const float* __restrict__ w2,
                                short* __restrict__ w1s, short* __restrict__ w2s) {
    int gid = blockIdx.x * 256 + threadIdx.x;
    if (gid < 1280) {
        int f = gid >> 6, lane = gid & 63;
        int kk = f >> 2, tt = f & 3;
        int n = tt * 16 + (lane & 15);
        int k0 = kk * 32 + (lane >> 4) * 8;
        short8 v;
        for (int j = 0; j < 8; ++j) {
            int k = k0 + j;
            v[j] = (k < 144) ? (short)f2bf(w1[k * 64 + n]) : (short)0;
        }
        *(short8*)(w1s + (long long)gid * 8) = v;
    } else if (gid < 2304) {
        int g2 = gid - 1280;
        int f = g2 >> 6, lane = g2 & 63;
        int kk = f >> 3, tt = f & 7;
        int n = tt * 16 + (lane & 15);
        int k0 = kk * 32 + (lane >> 4) * 8;
        short8 v;
        for (int j = 0; j < 8; ++j) v[j] = (short)f2bf(w2[(k0 + j) * 128 + n]);
        *(short8*)(w2s + (long long)g2 * 8) = v;
    }
}

// ---------- ew prep: ew[128][256] -> frags 4 kk x 16 tt ----------
__global__ void conv_ew_k(const float* __restrict__ ew, short* __restrict__ ews) {
    int gid = blockIdx.x * 256 + threadIdx.x;
    if (gid >= 4096) return;
    int f = gid >> 6, lane = gid & 63;
    int kk = f >> 4, tt = f & 15;
    int n = tt * 16 + (lane & 15);
    int k0 = kk * 32 + (lane >> 4) * 8;
    short8 v;
    for (int j = 0; j < 8; ++j) v[j] = (short)f2bf(ew[(k0 + j) * 256 + n]);
    *(short8*)(ews + (long long)gid * 8) = v;
}

// ---------- node-linear weight prep: [wl|wr] (K x 512) -> frags ----------
template <int K>
__global__ void conv_nodew_k(const float* __restrict__ wl, const float* __restrict__ wr,
                             short* __restrict__ out) {
    int gid = blockIdx.x * 256 + threadIdx.x;
    if (gid >= (K / 32) * 32 * 64) return;
    int f = gid >> 6, lane = gid & 63;
    int kk = f >> 5, tt = f & 31;
    int n = tt * 16 + (lane & 15);
    int k0 = kk * 32 + (lane >> 4) * 8;
    short8 v;
    for (int j = 0; j < 8; ++j) {
        int k = k0 + j;
        float x = (n < 256) ? wl[k * 256 + n] : wr[k * 256 + (n - 256)];
        v[j] = (short)f2bf(x);
    }
    *(short8*)(out + (long long)gid * 8) = v;
}

// ---------- pre2 weight prep: M[256][256], M[k][n<128]=w1[k][n], M[k][n>=128]=w1[256+k][n-128] ----------
__global__ void conv_pre2w_k(const float* __restrict__ w1, short* __restrict__ out) {
    int gid = blockIdx.x * 256 + threadIdx.x;
    if (gid >= 8 * 16 * 64) return;
    int f = gid >> 6, lane = gid & 63;
    int kk = f >> 4, tt = f & 15;
    int n = tt * 16 + (lane & 15);
    int k0 = kk * 32 + (lane >> 4) * 8;
    short8 v;
    for (int j = 0; j < 8; ++j) {
        int k = k0 + j;
        float x = (n < 128) ? w1[k * 128 + n] : w1[(256 + k) * 128 + (n - 128)];
        v[j] = (short)f2bf(x);
    }
    *(short8*)(out + (long long)gid * 8) = v;
}

// ---------- Edge MLP 1 via MFMA: eid-order compute, scatter rows to CSR slots ----------
__global__ __launch_bounds__(256) void edge_mlp1_mfma_k(
    const float* __restrict__ x, const float* __restrict__ ea,
    const int* __restrict__ src, const int* __restrict__ dst,
    const int* __restrict__ slot_of,
    const short* __restrict__ w1s, const float* __restrict__ b1,
    const short* __restrict__ w2s, const float* __restrict__ b2,
    bf16* __restrict__ out, int E) {
    __shared__ short At[32][168];
    __shared__ short Ht[32][72];
    __shared__ int sdv[32][2];
    __shared__ int slt[32];
    int t = threadIdx.x;
    long long e0 = (long long)blockIdx.x * 32;
    if (t < 64) {
        int r = t & 31;
        long long e = e0 + r;
        int v = 0;
        if (e < E) v = (t < 32) ? src[e] : dst[e];
        sdv[r][t >> 5] = v;
    } else if (t < 96) {
        int r = t - 64;
        long long e = e0 + r;
        slt[r] = (e < E) ? slot_of[e] : -1;
    }
    __syncthreads();
    for (int i = t; i < 32 * 40; i += 256) {
        int r = i / 40, c = i - r * 40;
        long long e = e0 + r;
        float4 v = {0.f, 0.f, 0.f, 0.f};
        if (e < E) {
            if (c < 16)      v = *(const float4*)(x + (long long)sdv[r][0] * 64 + c * 4);
            else if (c < 32) v = *(const float4*)(x + (long long)sdv[r][1] * 64 + (c - 16) * 4);
            else if (c < 36) v = *(const float4*)(ea + e * 16 + (c - 32) * 4);
        }
        union { ushort4 u4; unsigned short s4[4]; } pk;
        pk.s4[0] = f2bf(v.x); pk.s4[1] = f2bf(v.y); pk.s4[2] = f2bf(v.z); pk.s4[3] = f2bf(v.w);
        *(ushort4*)&At[r][c * 4] = pk.u4;
    }
    __syncthreads();

    int w = t >> 6, lane = t & 63;
    int m0 = (w & 1) * 16;
    int lr = lane & 15, lq = lane >> 4;

    int nq1 = (w >> 1) * 2;
    floatx4 acc[2];
    for (int i = 0; i < 2; ++i) acc[i] = (floatx4){0.f, 0.f, 0.f, 0.f};
    for (int kk = 0; kk < 5; ++kk) {
        short8 a = *(const short8*)&At[m0 + lr][kk * 32 + lq * 8];
        for (int tt = 0; tt < 2; ++tt) {
            short8 b = *(const short8*)(w1s + ((long long)((kk * 4 + nq1 + tt) * 64 + lane)) * 8);
            acc[tt] = __builtin_amdgcn_mfma_f32_16x16x32_bf16(a, b, acc[tt], 0, 0, 0);
        }
    }
    for (int tt = 0; tt < 2; ++tt) {
        int col = (nq1 + tt) * 16 + lr;
        float bv = b1[col];
        for (int r = 0; r < 4; ++r)
            Ht[m0 + lq * 4 + r][col] = (short)f2bf(fmaxf(acc[tt][r] + bv, 0.f));
    }
    __syncthreads();

    int nq2 = (w >> 1) * 4;
    floatx4 acc2[4];
    for (int i = 0; i < 4; ++i) acc2[i] = (floatx4){0.f, 0.f, 0.f, 0.f};
    for (int kk = 0; kk < 2; ++kk) {
        short8 a = *(const short8*)&Ht[m0 + lr][kk * 32 + lq * 8];
        for (int tt = 0; tt < 4; ++tt) {
            short8 b = *(const short8*)(w2s + ((long long)((kk * 8 + nq2 + tt) * 64 + lane)) * 8);
            acc2[tt] = __builtin_amdgcn_mfma_f32_16x16x32_bf16(a, b, acc2[tt], 0, 0, 0);
        }
    }
    for (int tt = 0; tt < 4; ++tt) {
        int col = (nq2 + tt) * 16 + lr;
        float bv = b2[col];
        for (int r = 0; r < 4; ++r)
            At[m0 + lq * 4 + r][col] = (short)f2bf(acc2[tt][r] + bv);
    }
    __syncthreads();
    for (int i = t; i < 512; i += 256) {
        int r = i >> 4, c = i & 15;
        int s = slt[r];
        if (s >= 0)
            *(short8*)(void*)(out + (long long)s * 128 + c * 8) = *(const short8*)&At[r][c * 8];
    }
}

// ---------- node linear via MFMA: [N x K] @ [K x 512] (= [wl|wr]) + bias ----------
// NOTE: x may alias xr (x1bn overlay) — per-block reads complete before same-row writes.
template <int K, typename T>
__global__ __launch_bounds__(256) void node_linear_mfma_k(
    const T* x, const short* __restrict__ ws,
    const float* __restrict__ bl, const float* __restrict__ br,
    bf16* __restrict__ xl, bf16* xr, int N) {
    __shared__ short At[16][K + 8];
    __shared__ short Ot[16][520];
    int t = threadIdx.x;
    long long n0 = (long long)blockIdx.x * 16;
    if (sizeof(T) == 4) {
        for (int i = t; i < 16 * (K / 4); i += 256) {
            int r = i / (K / 4), c = i % (K / 4);
            long long n = n0 + r;
            float4 v = {0.f, 0.f, 0.f, 0.f};
            if (n < N) v = *(const float4*)((const float*)x + n * K + c * 4);
            union { ushort4 u4; unsigned short s4[4]; } pk;
            pk.s4[0] = f2bf(v.x); pk.s4[1] = f2bf(v.y); pk.s4[2] = f2bf(v.z); pk.s4[3] = f2bf(v.w);
            *(ushort4*)&At[r][c * 4] = pk.u4;
        }
    } else {
        for (int i = t; i < 16 * (K / 8); i += 256) {
            int r = i / (K / 8), c = i % (K / 8);
            long long n = n0 + r;
            short8 v = {0, 0, 0, 0, 0, 0, 0, 0};
            if (n < N) v = *(const short8*)(const void*)((const bf16*)x + n * K + c * 8);
            *(short8*)&At[r][c * 8] = v;
        }
    }
    __syncthreads();

    int w = t >> 6, lane = t & 63;
    int nq = w * 8;
    int lr = lane & 15, lq = lane >> 4;

    floatx4 acc[8];
    for (int i = 0; i < 8; ++i) acc[i] = (floatx4){0.f, 0.f, 0.f, 0.f};
    for (int kk = 0; kk < K / 32; ++kk) {
        short8 a = *(const short8*)&At[lr][kk * 32 + lq * 8];
        for (int tt = 0; tt < 8; ++tt) {
            short8 b = *(const short8*)(ws + ((long long)((kk * 32 + nq + tt) * 64 + lane)) * 8);
            acc[tt] = __builtin_amdgcn_mfma_f32_16x16x32_bf16(a, b, acc[tt], 0, 0, 0);
        }
    }
    for (int tt = 0; tt < 8; ++tt) {
        int col = (nq + tt) * 16 + lr;
        float bv = (col < 256) ? bl[col] : br[col - 256];
        for (int r = 0; r < 4; ++r)
            Ot[lq * 4 + r][col] = (short)f2bf(acc[tt][r] + bv);
    }
    __syncthreads();
    for (int i = t; i < 1024; i += 256) {
        int r = i >> 6, c = i & 63;
        long long n = n0 + r;
        if (n < N) {
            short8 v = *(const short8*)&Ot[r][c * 8];
            if (c < 32) *(short8*)(void*)(xl + n * 256 + c * 8) = v;
            else        *(short8*)(void*)(xr + n * 256 + (c - 32) * 8) = v;
        }
    }
}

// ---------- pre2: xp = x1bn @ M[256x256] + b1x  -> xl buffer (cols 0-127: src part; 128-255: dst part + b1) ----------
__global__ __launch_bounds__(256) void pre_mfma_k(
    const bf16* __restrict__ x, const short* __restrict__ ws,
    const float* __restrict__ bx, bf16* __restrict__ out, int N) {
    __shared__ short At[16][264];
    __shared__ short Ot[16][264];
    int t = threadIdx.x;
    long long n0 = (long long)blockIdx.x * 16;
    for (int i = t; i < 512; i += 256) {
        int r = i >> 5, c = i & 31;
        long long n = n0 + r;
        short8 v = {0, 0, 0, 0, 0, 0, 0, 0};
        if (n < N) v = *(const short8*)(const void*)(x + n * 256 + c * 8);
        *(short8*)&At[r][c * 8] = v;
    }
    __syncthreads();

    int w = t >> 6, lane = t & 63;
    int nq = w * 4;
    int lr = lane & 15, lq = lane >> 4;

    floatx4 acc[4];
    for (int i = 0; i < 4; ++i) acc[i] = (floatx4){0.f, 0.f, 0.f, 0.f};
    for (int kk = 0; kk < 8; ++kk) {
        short8 a = *(const short8*)&At[lr][kk * 32 + lq * 8];
        for (int tt = 0; tt < 4; ++tt) {
            short8 b = *(const short8*)(ws + ((long long)((kk * 16 + nq + tt) * 64 + lane)) * 8);
            acc[tt] = __builtin_amdgcn_mfma_f32_16x16x32_bf16(a, b, acc[tt], 0, 0, 0);
        }
    }
    for (int tt = 0; tt < 4; ++tt) {
        int col = (nq + tt) * 16 + lr;
        float bv = bx[col];
        for (int r = 0; r < 4; ++r)
            Ot[lq * 4 + r][col] = (short)f2bf(acc[tt][r] + bv);
    }
    __syncthreads();
    for (int i = t; i < 512; i += 256) {
        int r = i >> 5, c = i & 31;
        long long n = n0 + r;
        if (n < N)
            *(short8*)(void*)(out + n * 256 + c * 8) = *(const short8*)&Ot[r][c * 8];
    }
}

// ---------- ee GEMM, full 256 channels, fp8 out, slot order ----------
__global__ __launch_bounds__(256) void gemm_ee_k(
    const bf16* __restrict__ ea_slot, const short* __restrict__ ews,
    unsigned char* __restrict__ ee8, int NT) {
    __shared__ short At[32][136];
    __shared__ unsigned char Et[32][264];
    int t = threadIdx.x;
    long long s0 = (long long)blockIdx.x * 32;
    for (int i = t; i < 32 * 16; i += 256) {
        int r = i >> 4, c = i & 15;
        long long s = s0 + r;
        short8 v = {0, 0, 0, 0, 0, 0, 0, 0};
        if (s < NT) v = *(const short8*)(const void*)(ea_slot + s * 128 + c * 8);
        *(short8*)&At[r][c * 8] = v;
    }
    __syncthreads();

    int w = t >> 6, lane = t & 63;
    int m0 = (w & 1) * 16, nq = (w >> 1) * 8;
    int lr = lane & 15, lq = lane >> 4;

    floatx4 acc[8];
    for (int i = 0; i < 8; ++i) acc[i] = (floatx4){0.f, 0.f, 0.f, 0.f};
    for (int kk = 0; kk < 4; ++kk) {
        short8 a = *(const short8*)&At[m0 + lr][kk * 32 + lq * 8];
        for (int tt = 0; tt < 8; ++tt) {
            short8 b = *(const short8*)(ews + ((long long)((kk * 16 + nq + tt) * 64 + lane)) * 8);
            acc[tt] = __builtin_amdgcn_mfma_f32_16x16x32_bf16(a, b, acc[tt], 0, 0, 0);
        }
    }
    for (int tt = 0; tt < 8; ++tt) {
        int col = (nq + tt) * 16 + lr;
        for (int r = 0; r < 4; ++r)
            Et[m0 + lq * 4 + r][col] = f2fp8(acc[tt][r]);
    }
    __syncthreads();
    for (int i = t; i < 2048; i += 256) {
        int r = i >> 6, c = i & 63;
        long long s = s0 + r;
        if (s < NT)
            *(unsigned*)(ee8 + s * 256 + c * 4) = *(const unsigned*)&Et[r][c * 4];
    }
}

// ---------- self-loop ee = mean of incoming ee rows (fp8) ----------
__global__ __launch_bounds__(256) void loop_ee_k(unsigned char* __restrict__ ee8,
                                                 const int* __restrict__ off, int N) {
    int t = threadIdx.x;
    int w = t >> 6, lane = t & 63;
    int n = blockIdx.x * 4 + w;
    if (n >= N) return;
    int beg = off[n], end = off[n + 1] - 1;
    float a0 = 0.f, a1 = 0.f, a2 = 0.f, a3 = 0.f;
    for (int i = beg; i < end; ++i) {
        unsigned pk = *(const unsigned*)(ee8 + (long long)i * 256 + lane * 4);
        a0 += fp82f(pk & 0xff);
        a1 += fp82f((pk >> 8) & 0xff);
        a2 += fp82f((pk >> 16) & 0xff);
        a3 += fp82f(pk >> 24);
    }
    float dv = fmaxf((float)(end - beg), 1.f);
    unsigned o = (unsigned)f2fp8(a0 / dv)
               | ((unsigned)f2fp8(a1 / dv) << 8)
               | ((unsigned)f2fp8(a2 / dv) << 16)
               | ((unsigned)f2fp8(a3 / dv) << 24);
    *(unsigned*)(ee8 + (long long)end * 256 + lane * 4) = o;
}

// ---------- Fused GATv2 attention + aggregation + finalize, single pass, all 4 heads ----------
// NOTE: x1bn may alias xr — xr[n] is read only by the owning wave, before its write.
template <bool L1>
__global__ __launch_bounds__(256) void gat_fused_k(
    const unsigned char* __restrict__ ee8, const bf16* __restrict__ xl, const bf16* xr,
    const int* __restrict__ off, const int* __restrict__ csr_src,
    const float* __restrict__ att, const float* __restrict__ bias,
    const float* __restrict__ bng, const float* __restrict__ bnb,
    const int* __restrict__ batch,
    bf16* x1bn, float* __restrict__ pooled, int N) {
    int t = threadIdx.x;
    int w = t >> 6, lane = t & 63;
    int n = blockIdx.x * 4 + w;
    if (n >= N) return;
    int c0 = lane * 4;
    union { ushort4 u4; unsigned short s4[4]; } xrp;
    xrp.u4 = *(const ushort4*)(const void*)(xr + (long long)n * 256 + c0);
    float xr0 = bfu(xrp.s4[0]), xr1 = bfu(xrp.s4[1]), xr2 = bfu(xrp.s4[2]), xr3 = bfu(xrp.s4[3]);
    float4 atv = *(const float4*)(att + c0);
    float a0 = 0.f, a1 = 0.f, a2 = 0.f, a3 = 0.f, dacc = 0.f;
    int beg = off[n], end = off[n + 1];
    for (int i = beg; i < end; ++i) {
        int sid = csr_src[i];
        union { ushort4 u4; unsigned short s4[4]; } xlp;
        xlp.u4 = *(const ushort4*)(const void*)(xl + (long long)sid * 256 + c0);
        unsigned ep = *(const unsigned*)(ee8 + (long long)i * 256 + c0);
        float x0 = bfu(xlp.s4[0]), x1 = bfu(xlp.s4[1]), x2 = bfu(xlp.s4[2]), x3 = bfu(xlp.s4[3]);
        float m0 = x0 + xr0 + fp82f(ep & 0xff);
        float m1 = x1 + xr1 + fp82f((ep >> 8) & 0xff);
        float m2 = x2 + xr2 + fp82f((ep >> 16) & 0xff);
        float m3 = x3 + xr3 + fp82f(ep >> 24);
        m0 = m0 > 0.f ? m0 : 0.2f * m0;
        m1 = m1 > 0.f ? m1 : 0.2f * m1;
        m2 = m2 > 0.f ? m2 : 0.2f * m2;
        m3 = m3 > 0.f ? m3 : 0.2f * m3;
        float p = atv.x * m0 + atv.y * m1 + atv.z * m2 + atv.w * m3;
        p += __shfl_xor(p, 1, 64);
        p += __shfl_xor(p, 2, 64);
        p += __shfl_xor(p, 4, 64);
        p += __shfl_xor(p, 8, 64);
        float ex = expf(p);
        a0 += ex * x0; a1 += ex * x1; a2 += ex * x2; a3 += ex * x3;
        dacc += ex;
    }
    float inv = 1.f / dacc;
    float o0 = fmaxf(a0 * inv + bias[c0],     0.f);
    float o1 = fmaxf(a1 * inv + bias[c0 + 1], 0.f);
    float o2 = fmaxf(a2 * inv + bias[c0 + 2], 0.f);
    float o3 = fmaxf(a3 * inv + bias[c0 + 3], 0.f);
    long long pb = (long long)batch[n] * 256 + c0;
    atomicAdd(&pooled[pb],     o0);
    atomicAdd(&pooled[pb + 1], o1);
    atomicAdd(&pooled[pb + 2], o2);
    atomicAdd(&pooled[pb + 3], o3);
    if (L1) {
        union { ushort4 u4; unsigned short s4[4]; } o;
        o.s4[0] = f2bf(bng[c0]     * (o0 * INVS) + bnb[c0]);
        o.s4[1] = f2bf(bng[c0 + 1] * (o1 * INVS) + bnb[c0 + 1]);
        o.s4[2] = f2bf(bng[c0 + 2] * (o2 * INVS) + bnb[c0 + 2]);
        o.s4[3] = f2bf(bng[c0 + 3] * (o3 * INVS) + bnb[c0 + 3]);
        *(ushort4*)(void*)(x1bn + (long long)n * 256 + c0) = o.u4;
    }
}

// ---------- global MLP layer1 ----------
__global__ void global_mlp1_k(const float* __restrict__ pooled,
                              const float* __restrict__ w1, const float* __restrict__ b1,
                              const float* __restrict__ w2, const float* __restrict__ b2,
                              const float* __restrict__ bng, const float* __restrict__ bnb,
                              float* __restrict__ u1bn) {
    __shared__ float pr[256];
    __shared__ float h[256];
    int t = threadIdx.x, g = blockIdx.x;
    pr[t] = pooled[g * 256 + t];
    __syncthreads();
    float acc = b1[t];
    for (int k = 0; k < 256; ++k) acc += pr[k] * w1[(256 + k) * 256 + t];
    h[t] = fmaxf(acc, 0.f);
    __syncthreads();
    float a2 = b2[t];
    for (int k = 0; k < 256; ++k) a2 += h[k] * w2[k * 256 + t];
    u1bn[g * 256 + t] = bng[t] * (a2 * INVS) + bnb[t];
}

// ---------- weight prep for MFMA edge MLP2 (+ b1x for pre path) ----------
__global__ void conv_weights_k(const float* __restrict__ w1, const float* __restrict__ w2,
                               const float* __restrict__ b1,
                               const float* __restrict__ bg, const float* __restrict__ bb,
                               short* __restrict__ w1s, short* __restrict__ w2s,
                               float* __restrict__ b1x) {
    int gid = blockIdx.x * 256 + threadIdx.x;
    if (gid < 10240) {
        int f = gid >> 6, lane = gid & 63;
        int kk = f >> 3, tt = f & 7;
        int n = tt * 16 + (lane & 15);
        int k0 = kk * 32 + (lane >> 4) * 8;
        short8 v;
        for (int j = 0; j < 8; ++j) {
            int k = k0 + j;
            float x = w1[k * 128 + n];
            if (k >= 512) x *= bg[k - 512] * INVS;
            v[j] = (short)f2bf(x);
        }
        *(short8*)(w1s + (long long)gid * 8) = v;
    } else if (gid < 12288) {
        int g2 = gid - 10240;
        int f = g2 >> 6, lane = g2 & 63;
        int kk = f >> 3, tt = f & 7;
        int n = tt * 16 + (lane & 15);
        int k0 = kk * 32 + (lane >> 4) * 8;
        short8 v;
        for (int j = 0; j < 8; ++j) v[j] = (short)f2bf(w2[(k0 + j) * 128 + n]);
        *(short8*)(w2s + (long long)g2 * 8) = v;
    } else if (gid < 12544) {
        int j = gid - 12288;                 // b1x[0:128) = 0 (src-half bias)
        b1x[j] = 0.f;
    } else if (gid < 12672) {
        int j = gid - 12544;                 // b1x[128:256) = b1 + BN-bias fold
        float acc = b1[j];
        for (int c = 0; c < 128; ++c) acc += bb[c] * w1[(512 + c) * 128 + j];
        b1x[128 + j] = acc;
    }
}

// ---------- Edge MLP 2 via MFMA, factored: acc = pre_s[src] + pre_d[dst](+b1) ; + ea@W1c ; relu ; @W2 ----------
__global__ __launch_bounds__(256) void edge_mlp2_mfma_k(
    const bf16* __restrict__ xpre, bf16* __restrict__ ea_slot,
    const int* __restrict__ csr_src, const int* __restrict__ csr_dst,
    const int* __restrict__ csr_eid,
    const short* __restrict__ w1s,       // uses kk 16..19 (ea rows, BN-folded)
    const short* __restrict__ w2s, const float* __restrict__ b2,
    int NT, int E) {
    __shared__ float Ps[32][132];   // pre-sum fp32 (stride 132 ≡ 4 mod 32 -> 2-way only)
    __shared__ short At[32][136];   // ea tile
    __shared__ short Ht[32][136];   // hidden
    __shared__ int sdv[32][3];
    int t = threadIdx.x;
    long long s0 = (long long)blockIdx.x * 32;
    if (t < 96) {
        int r = t & 31, which = t >> 5;
        long long s = s0 + r;
        int v = (which == 2) ? E : 0;
        if (s < NT) v = (which == 0) ? csr_src[s] : (which == 1 ? csr_dst[s] : csr_eid[s]);
        sdv[r][which] = v;
    }
    __syncthreads();
    // stage Ps = xpre[src][0:128] + xpre[dst][128:256]  (32 rows x 16 chunks of 8)
    for (int i = t; i < 512; i += 256) {
        int r = i >> 4, c = i & 15;
        long long s = s0 + r;
        bool ok = (s < NT) && (sdv[r][2] < E);
        float p[8];
        if (ok) {
            short8 vs = *(const short8*)(const void*)(xpre + (long long)sdv[r][0] * 256 + c * 8);
            short8 vd = *(const short8*)(const void*)(xpre + (long long)sdv[r][1] * 256 + 128 + c * 8);
            for (int j = 0; j < 8; ++j)
                p[j] = bfu((unsigned short)vs[j]) + bfu((unsigned short)vd[j]);
        } else {
            for (int j = 0; j < 8; ++j) p[j] = 0.f;
        }
        for (int j = 0; j < 8; ++j) Ps[r][c * 8 + j] = p[j];
    }
    // stage ea (sequential slot order)
    for (int i = t; i < 512; i += 256) {
        int r = i >> 4, c = i & 15;
        long long s = s0 + r;
        short8 v = {0, 0, 0, 0, 0, 0, 0, 0};
        if (s < NT && sdv[r][2] < E)
            v = *(const short8*)(const void*)(ea_slot + s * 128 + c * 8);
        *(short8*)&At[r][c * 8] = v;
    }
    __syncthreads();

    int w = t >> 6, lane = t & 63;
    int m0 = (w & 1) * 16;
    int nq = (w >> 1) * 4;
    int lr = lane & 15, lq = lane >> 4;

    // GEMM1: C init from Ps, K=128 over ea with W1c (w1s kk 16..19)
    floatx4 acc[4];
    for (int tt = 0; tt < 4; ++tt) {
        int col = (nq + tt) * 16 + lr;
        for (int r = 0; r < 4; ++r) acc[tt][r] = Ps[m0 + lq * 4 + r][col];
    }
    for (int kk = 0; kk < 4; ++kk) {
        short8 a = *(const short8*)&At[m0 + lr][kk * 32 + lq * 8];
        for (int tt = 0; tt < 4; ++tt) {
            short8 b = *(const short8*)(w1s + ((long long)(((16 + kk) * 8 + nq + tt) * 64 + lane)) * 8);
            acc[tt] = __builtin_amdgcn_mfma_f32_16x16x32_bf16(a, b, acc[tt], 0, 0, 0);
        }
    }
    for (int tt = 0; tt < 4; ++tt) {
        int col = (nq + tt) * 16 + lr;
        for (int r = 0; r < 4; ++r)
            Ht[m0 + lq * 4 + r][col] = (short)f2bf(fmaxf(acc[tt][r], 0.f));
    }
    __syncthreads();

    floatx4 acc2[4];
    for (int i = 0; i < 4; ++i) acc2[i] = (floatx4){0.f, 0.f, 0.f, 0.f};
    for (int kk = 0; kk < 4; ++kk) {
        short8 a = *(const short8*)&Ht[m0 + lr][kk * 32 + lq * 8];
        for (int tt = 0; tt < 4; ++tt) {
            short8 b = *(const short8*)(w2s + ((long long)((kk * 8 + nq + tt) * 64 + lane)) * 8);
            acc2[tt] = __builtin_amdgcn_mfma_f32_16x16x32_bf16(a, b, acc2[tt], 0, 0, 0);
        }
    }
    for (int tt = 0; tt < 4; ++tt) {
        int col = (nq + tt) * 16 + lr;
        float bv = b2[col];
        for (int r = 0; r < 4; ++r)
            At[m0 + lq * 4 + r][col] = (short)f2bf(acc2[tt][r] + bv);
    }
    __syncthreads();
    for (int i = t; i < 512; i += 256) {
        int r = i >> 4, c = i & 15;
        long long s = s0 + r;
        if (s < NT && sdv[r][2] < E)
            *(short8*)(void*)(ea_slot + s * 128 + c * 8) = *(const short8*)&At[r][c * 8];
    }
}

// ---------- final global MLP + head ----------
__global__ void final_mlp_k(const float* __restrict__ u1bn, const float* __restrict__ pooled,
                            const float* __restrict__ w1, const float* __restrict__ b1,
                            const float* __restrict__ w2, const float* __restrict__ b2,
                            const float* __restrict__ f1w, const float* __restrict__ f1b,
                            const float* __restrict__ f2w, const float* __restrict__ f2b,
                            float* __restrict__ out) {
    __shared__ float ub[256], pb[256], h[256], u2[256];
    int t = threadIdx.x, g = blockIdx.x;
    ub[t] = u1bn[g * 256 + t];
    pb[t] = pooled[g * 256 + t];
    __syncthreads();
    float acc = b1[t];
    for (int k = 0; k < 256; ++k)
        acc += ub[k] * w1[k * 256 + t] + pb[k] * w1[(256 + k) * 256 + t];
    h[t] = fmaxf(acc, 0.f);
    __syncthreads();
    float a2 = b2[t];
    for (int k = 0; k < 256; ++k) a2 += h[k] * w2[k * 256 + t];
    u2[t] = a2;
    __syncthreads();
    float fv = 0.f;
    if (t < 64) {
        float a3 = f1b[t];
        for (int k = 0; k < 256; ++k) a3 += u2[k] * f1w[k * 64 + t];
        fv = fmaxf(a3, 0.f) * f2w[t];
    }
    for (int off = 32; off; off >>= 1) fv += __shfl_down(fv, off, 64);
    if (t == 0) out[g] = fv + f2b[0];
}

// ---------- launch ----------
extern "C" void kernel_launch(void* const* d_in, const int* in_sizes, int n_in,
                              void* d_out, int out_size, void* d_ws, size_t ws_size,
                              hipStream_t stream) {
    const float* x         = (const float*)d_in[0];
    const float* edge_attr = (const float*)d_in[1];
    const float* e1_w1 = (const float*)d_in[2];
    const float* e1_b1 = (const float*)d_in[3];
    const float* e1_w2 = (const float*)d_in[4];
    const float* e1_b2 = (const float*)d_in[5];
    const float* g1_lw = (const float*)d_in[6];
    const float* g1_lb = (const float*)d_in[7];
    const float* g1_rw = (const float*)d_in[8];
    const float* g1_rb = (const float*)d_in[9];
    const float* g1_ew = (const float*)d_in[10];
    const float* g1_att = (const float*)d_in[11];
    const float* g1_bias = (const float*)d_in[12];
    const float* u1_w1 = (const float*)d_in[13];
    const float* u1_b1 = (const float*)d_in[14];
    const float* u1_w2 = (const float*)d_in[15];
    const float* u1_b2 = (const float*)d_in[16];
    const float* bn_n_g = (const float*)d_in[17];
    const float* bn_n_b = (const float*)d_in[18];
    const float* bn_e_g = (const float*)d_in[19];
    const float* bn_e_b = (const float*)d_in[20];
    const float* bn_u_g = (const float*)d_in[21];
    const float* bn_u_b = (const float*)d_in[22];
    const float* e2_w1 = (const float*)d_in[23];
    const float* e2_b1 = (const float*)d_in[24];
    const float* e2_w2 = (const float*)d_in[25];
    const float* e2_b2 = (const float*)d_in[26];
    const float* g2_lw = (const float*)d_in[27];
    const float* g2_lb = (const float*)d_in[28];
    const float* g2_rw = (const float*)d_in[29];
    const float* g2_rb = (const float*)d_in[30];
    const float* g2_ew = (const float*)d_in[31];
    const float* g2_att = (const float*)d_in[32];
    const float* g2_bias = (const float*)d_in[33];
    const float* u2_w1 = (const float*)d_in[34];
    const float* u2_b1 = (const float*)d_in[35];
    const float* u2_w2 = (const float*)d_in[36];
    const float* u2_b2 = (const float*)d_in[37];
    const float* fc1_w = (const float*)d_in[38];
    const float* fc1_b = (const float*)d_in[39];
    const float* fc2_w = (const float*)d_in[40];
    const float* fc2_b = (const float*)d_in[41];
    const int* edge_index = (const int*)d_in[42];
    const int* batch = (const int*)d_in[43];

    const int N = in_sizes[0] / 64;
    const int E = in_sizes[1] / 16;
    const int NT = E + N;
    const int G = G_GRAPHS;
    const int* src = edge_index;
    const int* dst = edge_index + E;
    const int NB = (NT + 31) / 32;

    // workspace carve (~249 MB; x1bn aliases xr; pre2 lives in xl during edge_mlp2)
    char* p = (char*)d_ws;
    auto alloc = [&](size_t bytes) { char* r = p; p += (bytes + 255) & ~(size_t)255; return r; };
    bf16* eabuf = (bf16*)alloc((size_t)NT * 128 * 2);      // ea in CSR-slot order (NT rows)
    bf16* xl    = (bf16*)alloc((size_t)N * 256 * 2);
    bf16* xr    = (bf16*)alloc((size_t)N * 256 * 2);
    bf16* x1bn  = xr;                                      // ALIAS: read-once-by-owner before write
    unsigned char* ee8 = (unsigned char*)alloc((size_t)NT * 256);
    int* degi   = (int*)alloc((size_t)N * 4);
    int* off    = (int*)alloc((size_t)(N + 1) * 4);
    int* fillc  = (int*)alloc((size_t)N * 4);
    int* csr_src = (int*)alloc((size_t)NT * 4);
    int* csr_dst = (int*)alloc((size_t)NT * 4);
    int* csr_eid = (int*)alloc((size_t)NT * 4);
    int* slot_of = (int*)alloc((size_t)E * 4);
    float* pooled = (float*)alloc((size_t)G * 256 * 4);
    float* u1bn = (float*)alloc((size_t)G * 256 * 4);
    short* w1s  = (short*)alloc((size_t)20 * 8 * 64 * 8 * 2);
    short* w2s  = (short*)alloc((size_t)4 * 8 * 64 * 8 * 2);
    float* b1x  = (float*)alloc((size_t)256 * 4);
    short* w1s1 = (short*)alloc((size_t)5 * 4 * 64 * 8 * 2);
    short* w2s1 = (short*)alloc((size_t)2 * 8 * 64 * 8 * 2);
    short* ews1 = (short*)alloc((size_t)4 * 16 * 64 * 8 * 2);
    short* ews2 = (short*)alloc((size_t)4 * 16 * 64 * 8 * 2);
    short* nw1  = (short*)alloc((size_t)2 * 32 * 64 * 8 * 2);
    short* nw2  = (short*)alloc((size_t)8 * 32 * 64 * 8 * 2);
    short* nwp  = (short*)alloc((size_t)8 * 16 * 64 * 8 * 2);  // pre2 M[256x256] frags (128 KB)

    // ===== CSR build =====
    hipMemsetAsync(degi, 0, (size_t)N * 4, stream);
    hipMemsetAsync(fillc, 0, (size_t)N * 4, stream);
    hipMemsetAsync(pooled, 0, (size_t)G * 256 * 4, stream);
    degi_k<<<(E + 255) / 256, 256, 0, stream>>>(dst, degi, E);
    scan_k<<<1, 1024, 0, stream>>>(degi, off, N);
    fill_csr_k<<<(max(E, N) + 255) / 256, 256, 0, stream>>>(src, dst, off, fillc,
                                                            csr_src, csr_dst, csr_eid,
                                                            slot_of, E, N);

    // ===== layer 1 =====
    conv_weights1_k<<<9, 256, 0, stream>>>(e1_w1, e1_w2, w1s1, w2s1);
    conv_ew_k<<<16, 256, 0, stream>>>(g1_ew, ews1);
    conv_ew_k<<<16, 256, 0, stream>>>(g2_ew, ews2);
    conv_nodew_k<64><<<16, 256, 0, stream>>>(g1_lw, g1_rw, nw1);
    conv_nodew_k<256><<<64, 256, 0, stream>>>(g2_lw, g2_rw, nw2);
    conv_pre2w_k<<<32, 256, 0, stream>>>(e2_w1, nwp);
    edge_mlp1_mfma_k<<<(E + 31) / 32, 256, 0, stream>>>(x, edge_attr, src, dst, slot_of,
                                                        w1s1, e1_b1, w2s1, e1_b2, eabuf, E);
    node_linear_mfma_k<64, float><<<(N + 15) / 16, 256, 0, stream>>>(x, nw1, g1_lb, g1_rb, xl, xr, N);
    gemm_ee_k<<<NB, 256, 0, stream>>>(eabuf, ews1, ee8, NT);
    loop_ee_k<<<(N + 3) / 4, 256, 0, stream>>>(ee8, off, N);
    gat_fused_k<true><<<(N + 3) / 4, 256, 0, stream>>>(ee8, xl, xr, off, csr_src,
                                                       g1_att, g1_bias, bn_n_g, bn_n_b,
                                                       batch, x1bn, pooled, N);
    global_mlp1_k<<<G, 256, 0, stream>>>(pooled, u1_w1, u1_b1, u1_w2, u1_b2, bn_u_g, bn_u_b, u1bn);

    // ===== layer 2 =====
    conv_weights_k<<<50, 256, 0, stream>>>(e2_w1, e2_w2, e2_b1, bn_e_g, bn_e_b, w1s, w2s, b1x);
    // pre2 into xl (free until node_linear rewrites it)
    pre_mfma_k<<<(N + 15) / 16, 256, 0, stream>>>(x1bn, nwp, b1x, xl, N);
    edge_mlp2_mfma_k<<<NB, 256, 0, stream>>>(xl, eabuf, csr_src, csr_dst, csr_eid,
                                             w1s, w2s, e2_b2, NT, E);
    node_linear_mfma_k<256, bf16><<<(N + 15) / 16, 256, 0, stream>>>(x1bn, nw2, g2_lb, g2_rb, xl, xr, N);
    hipMemsetAsync(pooled, 0, (size_t)G * 256 * 4, stream);
    gemm_ee_k<<<NB, 256, 0, stream>>>(eabuf, ews2, ee8, NT);
    loop_ee_k<<<(N + 3) / 4, 256, 0, stream>>>(ee8, off, N);
    gat_fused_k<false><<<(N + 3) / 4, 256, 0, stream>>>(ee8, xl, xr, off, csr_src,
                                                        g2_att, g2_bias, nullptr, nullptr,
                                                        batch, nullptr, pooled, N);
    final_mlp_k<<<G, 256, 0, stream>>>(u1bn, pooled, u2_w1, u2_b1, u2_w2, u2_b2,
                                       fc1_w, fc1_b, fc2_w, fc2_b, (float*)d_out);
}

// Round 16
// 946.754 us; speedup vs baseline: 1.4518x; 1.2653x over previous
//
#include <hip/hip_runtime.h>
#include <hip/hip_bf16.h>
#include <hip/hip_fp8.h>
#include <cstdint>
#include <cstddef>

#define INVS 0.99999500003749968f  // 1/sqrt(1+1e-5)
#define G_GRAPHS 256

using bf16 = __hip_bfloat16;
using short8 = __attribute__((ext_vector_type(8))) short;
using floatx4 = __attribute__((ext_vector_type(4))) float;

// ---------- helpers ----------
__device__ __forceinline__ unsigned short f2bf(float v) {
    union { float f; unsigned u; } x; x.f = v;
    unsigned r = x.u + 0x7fffu + ((x.u >> 16) & 1u);
    return (unsigned short)(r >> 16);
}
__device__ __forceinline__ float bfu(unsigned short u) { return __uint_as_float((unsigned)u << 16); }
__device__ __forceinline__ unsigned char f2fp8(float v) {
    __hip_fp8_e4m3 q(v); return q.__x;
}
__device__ __forceinline__ float fp82f(unsigned char b) {
    __hip_fp8_e4m3 q; q.__x = b; return (float)q;
}

// ---------- CSR build ----------
__global__ void degi_k(const int* __restrict__ dst, int* __restrict__ degi, int E) {
    int gid = blockIdx.x * 256 + threadIdx.x;
    if (gid < E) atomicAdd(&degi[dst[gid]], 1);
}

__global__ void scan_k(const int* __restrict__ degi, int* __restrict__ off, int N) {
    __shared__ int buf[1024];
    __shared__ int carry;
    int t = threadIdx.x;
    if (t == 0) carry = 0;
    __syncthreads();
    int nch = (N + 1023) / 1024;
    for (int ch = 0; ch < nch; ++ch) {
        int idx = ch * 1024 + t;
        int v = (idx < N) ? (degi[idx] + 1) : 0;
        buf[t] = v;
        __syncthreads();
        for (int ofs = 1; ofs < 1024; ofs <<= 1) {
            int add = (t >= ofs) ? buf[t - ofs] : 0;
            __syncthreads();
            buf[t] += add;
            __syncthreads();
        }
        int incl = buf[t];
        if (idx < N) off[idx] = carry + incl - v;
        __syncthreads();
        if (t == 1023) carry += incl;
        __syncthreads();
    }
    if (t == 0) off[N] = carry;
}

__global__ void fill_csr_k(const int* __restrict__ src, const int* __restrict__ dst,
                           const int* __restrict__ off, int* __restrict__ fillc,
                           int* __restrict__ csr_src, int* __restrict__ csr_dst,
                           int* __restrict__ csr_eid, int* __restrict__ slot_of,
                           int E, int N) {
    int gid = blockIdx.x * 256 + threadIdx.x;
    if (gid < E) {
        int d = dst[gid];
        int slot = off[d] + atomicAdd(&fillc[d], 1);
        csr_src[slot] = src[gid];
        csr_dst[slot] = d;
        csr_eid[slot] = gid;
        slot_of[gid] = slot;
    }
    if (gid < N) {
        int slot = off[gid + 1] - 1;   // reserved last slot = self-loop
        csr_src[slot] = gid;
        csr_dst[slot] = gid;
        csr_eid[slot] = E + gid;       // >= E marks self-loop
    }
}

// ---------- weight prep for MFMA edge MLP1 ----------
__global__ void conv_weights1_k(const float* __restrict__ w1, const float* __restrict__ w2,
                                short* __restrict__ w1s, short* __restrict__ w2s) {
    int gid = blockIdx.x * 256 + threadIdx.x;
    if (gid < 1280) {
        int f = gid >> 6, lane = gid & 63;
        int kk = f >> 2, tt = f & 3;
        int n = tt * 16 + (lane & 15);
        int k0 = kk * 32 + (lane >> 4) * 8;
        short8 v;
        for (int j = 0; j < 8; ++j) {
            int k = k0 + j;
            v[j] = (k < 144) ? (short)f2bf(w1[k * 64 + n]) : (short)0;
        }
        *(short8*)(w1s + (long long)gid * 8) = v;
    } else if (gid < 2304) {
        int g2 = gid - 1280;
        int f = g2 >> 6, lane = g2 & 63;
        int kk = f >> 3, tt = f & 7;
        int n = tt * 16 + (lane & 15);
        int k0 = kk * 32 + (lane >> 4) * 8;
        short8 v;
        for (int j = 0; j < 8; ++j) v[j] = (short)f2bf(w2[(k0 + j) * 128 + n]);
        *(short8*)(w2s + (long long)g2 * 8) = v;
    }
}

// ---------- ew prep: ew[128][256] -> frags 4 kk x 16 tt ----------
__global__ void conv_ew_k(const float* __restrict__ ew, short* __restrict__ ews) {
    int gid = blockIdx.x * 256 + threadIdx.x;
    if (gid >= 4096) return;
    int f = gid >> 6, lane = gid & 63;
    int kk = f >> 4, tt = f & 15;
    int n = tt * 16 + (lane & 15);
    int k0 = kk * 32 + (lane >> 4) * 8;
    short8 v;
    for (int j = 0; j < 8; ++j) v[j] = (short)f2bf(ew[(k0 + j) * 256 + n]);
    *(short8*)(ews + (long long)gid * 8) = v;
}

// ---------- node-linear weight prep: [wl|wr] (K x 512) -> frags ----------
template <int K>
__global__ void conv_nodew_k(const float* __restrict__ wl, const float* __restrict__ wr,
                             short* __restrict__ out) {
    int gid = blockIdx.x * 256 + threadIdx.x;
    if (gid >= (K / 32) * 32 * 64) return;
    int f = gid >> 6, lane = gid & 63;
    int kk = f >> 5, tt = f & 31;
    int n = tt * 16 + (lane & 15);
    int k0 = kk * 32 + (lane >> 4) * 8;
    short8 v;
    for (int j = 0; j < 8; ++j) {
        int k = k0 + j;
        float x = (n < 256) ? wl[k * 256 + n] : wr[k * 256 + (n - 256)];
        v[j] = (short)f2bf(x);
    }
    *(short8*)(out + (long long)gid * 8) = v;
}

// ---------- pre2 weight prep: M[256][256], M[k][n<128]=w1[k][n], M[k][n>=128]=w1[256+k][n-128] ----------
__global__ void conv_pre2w_k(const float* __restrict__ w1, short* __restrict__ out) {
    int gid = blockIdx.x * 256 + threadIdx.x;
    if (gid >= 8 * 16 * 64) return;
    int f = gid >> 6, lane = gid & 63;
    int kk = f >> 4, tt = f & 15;
    int n = tt * 16 + (lane & 15);
    int k0 = kk * 32 + (lane >> 4) * 8;
    short8 v;
    for (int j = 0; j < 8; ++j) {
        int k = k0 + j;
        float x = (n < 128) ? w1[k * 128 + n] : w1[(256 + k) * 128 + (n - 128)];
        v[j] = (short)f2bf(x);
    }
    *(short8*)(out + (long long)gid * 8) = v;
}

// ---------- Edge MLP 1 via MFMA: eid-order compute, scatter rows to CSR slots ----------
__global__ __launch_bounds__(256) void edge_mlp1_mfma_k(
    const float* __restrict__ x, const float* __restrict__ ea,
    const int* __restrict__ src, const int* __restrict__ dst,
    const int* __restrict__ slot_of,
    const short* __restrict__ w1s, const float* __restrict__ b1,
    const short* __restrict__ w2s, const float* __restrict__ b2,
    bf16* __restrict__ out, int E) {
    __shared__ short At[32][168];
    __shared__ short Ht[32][72];
    __shared__ int sdv[32][2];
    __shared__ int slt[32];
    int t = threadIdx.x;
    long long e0 = (long long)blockIdx.x * 32;
    if (t < 64) {
        int r = t & 31;
        long long e = e0 + r;
        int v = 0;
        if (e < E) v = (t < 32) ? src[e] : dst[e];
        sdv[r][t >> 5] = v;
    } else if (t < 96) {
        int r = t - 64;
        long long e = e0 + r;
        slt[r] = (e < E) ? slot_of[e] : -1;
    }
    __syncthreads();
    for (int i = t; i < 32 * 40; i += 256) {
        int r = i / 40, c = i - r * 40;
        long long e = e0 + r;
        float4 v = {0.f, 0.f, 0.f, 0.f};
        if (e < E) {
            if (c < 16)      v = *(const float4*)(x + (long long)sdv[r][0] * 64 + c * 4);
            else if (c < 32) v = *(const float4*)(x + (long long)sdv[r][1] * 64 + (c - 16) * 4);
            else if (c < 36) v = *(const float4*)(ea + e * 16 + (c - 32) * 4);
        }
        ushort4 pk;
        pk.x = f2bf(v.x); pk.y = f2bf(v.y); pk.z = f2bf(v.z); pk.w = f2bf(v.w);
        *(ushort4*)&At[r][c * 4] = pk;
    }
    __syncthreads();

    int w = t >> 6, lane = t & 63;
    int m0 = (w & 1) * 16;
    int lr = lane & 15, lq = lane >> 4;

    int nq1 = (w >> 1) * 2;
    floatx4 acc[2];
    for (int i = 0; i < 2; ++i) acc[i] = (floatx4){0.f, 0.f, 0.f, 0.f};
    for (int kk = 0; kk < 5; ++kk) {
        short8 a = *(const short8*)&At[m0 + lr][kk * 32 + lq * 8];
        for (int tt = 0; tt < 2; ++tt) {
            short8 b = *(const short8*)(w1s + ((long long)((kk * 4 + nq1 + tt) * 64 + lane)) * 8);
            acc[tt] = __builtin_amdgcn_mfma_f32_16x16x32_bf16(a, b, acc[tt], 0, 0, 0);
        }
    }
    for (int tt = 0; tt < 2; ++tt) {
        int col = (nq1 + tt) * 16 + lr;
        float bv = b1[col];
        for (int r = 0; r < 4; ++r)
            Ht[m0 + lq * 4 + r][col] = (short)f2bf(fmaxf(acc[tt][r] + bv, 0.f));
    }
    __syncthreads();

    int nq2 = (w >> 1) * 4;
    floatx4 acc2[4];
    for (int i = 0; i < 4; ++i) acc2[i] = (floatx4){0.f, 0.f, 0.f, 0.f};
    for (int kk = 0; kk < 2; ++kk) {
        short8 a = *(const short8*)&Ht[m0 + lr][kk * 32 + lq * 8];
        for (int tt = 0; tt < 4; ++tt) {
            short8 b = *(const short8*)(w2s + ((long long)((kk * 8 + nq2 + tt) * 64 + lane)) * 8);
            acc2[tt] = __builtin_amdgcn_mfma_f32_16x16x32_bf16(a, b, acc2[tt], 0, 0, 0);
        }
    }
    for (int tt = 0; tt < 4; ++tt) {
        int col = (nq2 + tt) * 16 + lr;
        float bv = b2[col];
        for (int r = 0; r < 4; ++r)
            At[m0 + lq * 4 + r][col] = (short)f2bf(acc2[tt][r] + bv);
    }
    __syncthreads();
    for (int i = t; i < 512; i += 256) {
        int r = i >> 4, c = i & 15;
        int s = slt[r];
        if (s >= 0)
            *(short8*)(void*)(out + (long long)s * 128 + c * 8) = *(const short8*)&At[r][c * 8];
    }
}

// ---------- node linear via MFMA: [N x K] @ [K x 512] (= [wl|wr]) + bias ----------
// NOTE: x may alias xr (x1bn overlay) — per-block reads complete before same-row writes.
template <int K, typename T>
__global__ __launch_bounds__(256) void node_linear_mfma_k(
    const T* x, const short* __restrict__ ws,
    const float* __restrict__ bl, const float* __restrict__ br,
    bf16* __restrict__ xl, bf16* xr, int N) {
    __shared__ short At[16][K + 8];
    __shared__ short Ot[16][520];
    int t = threadIdx.x;
    long long n0 = (long long)blockIdx.x * 16;
    if (sizeof(T) == 4) {
        for (int i = t; i < 16 * (K / 4); i += 256) {
            int r = i / (K / 4), c = i % (K / 4);
            long long n = n0 + r;
            float4 v = {0.f, 0.f, 0.f, 0.f};
            if (n < N) v = *(const float4*)((const float*)x + n * K + c * 4);
            ushort4 pk;
            pk.x = f2bf(v.x); pk.y = f2bf(v.y); pk.z = f2bf(v.z); pk.w = f2bf(v.w);
            *(ushort4*)&At[r][c * 4] = pk;
        }
    } else {
        for (int i = t; i < 16 * (K / 8); i += 256) {
            int r = i / (K / 8), c = i % (K / 8);
            long long n = n0 + r;
            short8 v = {0, 0, 0, 0, 0, 0, 0, 0};
            if (n < N) v = *(const short8*)(const void*)((const bf16*)x + n * K + c * 8);
            *(short8*)&At[r][c * 8] = v;
        }
    }
    __syncthreads();

    int w = t >> 6, lane = t & 63;
    int nq = w * 8;
    int lr = lane & 15, lq = lane >> 4;

    floatx4 acc[8];
    for (int i = 0; i < 8; ++i) acc[i] = (floatx4){0.f, 0.f, 0.f, 0.f};
    for (int kk = 0; kk < K / 32; ++kk) {
        short8 a = *(const short8*)&At[lr][kk * 32 + lq * 8];
        for (int tt = 0; tt < 8; ++tt) {
            short8 b = *(const short8*)(ws + ((long long)((kk * 32 + nq + tt) * 64 + lane)) * 8);
            acc[tt] = __builtin_amdgcn_mfma_f32_16x16x32_bf16(a, b, acc[tt], 0, 0, 0);
        }
    }
    for (int tt = 0; tt < 8; ++tt) {
        int col = (nq + tt) * 16 + lr;
        float bv = (col < 256) ? bl[col] : br[col - 256];
        for (int r = 0; r < 4; ++r)
            Ot[lq * 4 + r][col] = (short)f2bf(acc[tt][r] + bv);
    }
    __syncthreads();
    for (int i = t; i < 1024; i += 256) {
        int r = i >> 6, c = i & 63;
        long long n = n0 + r;
        if (n < N) {
            short8 v = *(const short8*)&Ot[r][c * 8];
            if (c < 32) *(short8*)(void*)(xl + n * 256 + c * 8) = v;
            else        *(short8*)(void*)(xr + n * 256 + (c - 32) * 8) = v;
        }
    }
}

// ---------- pre2: xp = x1bn @ M[256x256] + b1x  -> xl buffer ----------
__global__ __launch_bounds__(256) void pre_mfma_k(
    const bf16* __restrict__ x, const short* __restrict__ ws,
    const float* __restrict__ bx, bf16* __restrict__ out, int N) {
    __shared__ short At[16][264];
    __shared__ short Ot[16][264];
    int t = threadIdx.x;
    long long n0 = (long long)blockIdx.x * 16;
    for (int i = t; i < 512; i += 256) {
        int r = i >> 5, c = i & 31;
        long long n = n0 + r;
        short8 v = {0, 0, 0, 0, 0, 0, 0, 0};
        if (n < N) v = *(const short8*)(const void*)(x + n * 256 + c * 8);
        *(short8*)&At[r][c * 8] = v;
    }
    __syncthreads();

    int w = t >> 6, lane = t & 63;
    int nq = w * 4;
    int lr = lane & 15, lq = lane >> 4;

    floatx4 acc[4];
    for (int i = 0; i < 4; ++i) acc[i] = (floatx4){0.f, 0.f, 0.f, 0.f};
    for (int kk = 0; kk < 8; ++kk) {
        short8 a = *(const short8*)&At[lr][kk * 32 + lq * 8];
        for (int tt = 0; tt < 4; ++tt) {
            short8 b = *(const short8*)(ws + ((long long)((kk * 16 + nq + tt) * 64 + lane)) * 8);
            acc[tt] = __builtin_amdgcn_mfma_f32_16x16x32_bf16(a, b, acc[tt], 0, 0, 0);
        }
    }
    for (int tt = 0; tt < 4; ++tt) {
        int col = (nq + tt) * 16 + lr;
        float bv = bx[col];
        for (int r = 0; r < 4; ++r)
            Ot[lq * 4 + r][col] = (short)f2bf(acc[tt][r] + bv);
    }
    __syncthreads();
    for (int i = t; i < 512; i += 256) {
        int r = i >> 5, c = i & 31;
        long long n = n0 + r;
        if (n < N)
            *(short8*)(void*)(out + n * 256 + c * 8) = *(const short8*)&Ot[r][c * 8];
    }
}

// ---------- ee GEMM, full 256 channels, fp8 out, slot order ----------
__global__ __launch_bounds__(256) void gemm_ee_k(
    const bf16* __restrict__ ea_slot, const short* __restrict__ ews,
    unsigned char* __restrict__ ee8, int NT) {
    __shared__ short At[32][136];
    __shared__ unsigned char Et[32][264];
    int t = threadIdx.x;
    long long s0 = (long long)blockIdx.x * 32;
    for (int i = t; i < 32 * 16; i += 256) {
        int r = i >> 4, c = i & 15;
        long long s = s0 + r;
        short8 v = {0, 0, 0, 0, 0, 0, 0, 0};
        if (s < NT) v = *(const short8*)(const void*)(ea_slot + s * 128 + c * 8);
        *(short8*)&At[r][c * 8] = v;
    }
    __syncthreads();

    int w = t >> 6, lane = t & 63;
    int m0 = (w & 1) * 16, nq = (w >> 1) * 8;
    int lr = lane & 15, lq = lane >> 4;

    floatx4 acc[8];
    for (int i = 0; i < 8; ++i) acc[i] = (floatx4){0.f, 0.f, 0.f, 0.f};
    for (int kk = 0; kk < 4; ++kk) {
        short8 a = *(const short8*)&At[m0 + lr][kk * 32 + lq * 8];
        for (int tt = 0; tt < 8; ++tt) {
            short8 b = *(const short8*)(ews + ((long long)((kk * 16 + nq + tt) * 64 + lane)) * 8);
            acc[tt] = __builtin_amdgcn_mfma_f32_16x16x32_bf16(a, b, acc[tt], 0, 0, 0);
        }
    }
    for (int tt = 0; tt < 8; ++tt) {
        int col = (nq + tt) * 16 + lr;
        for (int r = 0; r < 4; ++r)
            Et[m0 + lq * 4 + r][col] = f2fp8(acc[tt][r]);
    }
    __syncthreads();
    for (int i = t; i < 2048; i += 256) {
        int r = i >> 6, c = i & 63;
        long long s = s0 + r;
        if (s < NT)
            *(unsigned*)(ee8 + s * 256 + c * 4) = *(const unsigned*)&Et[r][c * 4];
    }
}

// ---------- self-loop ee = mean of incoming ee rows (fp8) ----------
__global__ __launch_bounds__(256) void loop_ee_k(unsigned char* __restrict__ ee8,
                                                 const int* __restrict__ off, int N) {
    int t = threadIdx.x;
    int w = t >> 6, lane = t & 63;
    int n = blockIdx.x * 4 + w;
    if (n >= N) return;
    int beg = off[n], end = off[n + 1] - 1;
    float a0 = 0.f, a1 = 0.f, a2 = 0.f, a3 = 0.f;
    for (int i = beg; i < end; ++i) {
        unsigned pk = *(const unsigned*)(ee8 + (long long)i * 256 + lane * 4);
        a0 += fp82f(pk & 0xff);
        a1 += fp82f((pk >> 8) & 0xff);
        a2 += fp82f((pk >> 16) & 0xff);
        a3 += fp82f(pk >> 24);
    }
    float dv = fmaxf((float)(end - beg), 1.f);
    unsigned o = (unsigned)f2fp8(a0 / dv)
               | ((unsigned)f2fp8(a1 / dv) << 8)
               | ((unsigned)f2fp8(a2 / dv) << 16)
               | ((unsigned)f2fp8(a3 / dv) << 24);
    *(unsigned*)(ee8 + (long long)end * 256 + lane * 4) = o;
}

// ---------- Fused GATv2 attention + aggregation + finalize ----------
// Single pass, all 4 heads; depth-1 prefetch; block-level pooled reduction (batch sorted).
// NOTE: x1bn may alias xr — xr[n] is read only by the owning wave, before its write.
template <bool L1>
__global__ __launch_bounds__(256) void gat_fused_k(
    const unsigned char* __restrict__ ee8, const bf16* __restrict__ xl, const bf16* xr,
    const int* __restrict__ off, const int* __restrict__ csr_src,
    const float* __restrict__ att, const float* __restrict__ bias,
    const float* __restrict__ bng, const float* __restrict__ bnb,
    const int* __restrict__ batch,
    bf16* x1bn, float* __restrict__ pooled, int N) {
    __shared__ float ps[4][260];
    __shared__ int bid[4];
    int t = threadIdx.x;
    int w = t >> 6, lane = t & 63;
    int n = blockIdx.x * 4 + w;
    bool valid = n < N;
    int c0 = lane * 4;
    float o0 = 0.f, o1 = 0.f, o2 = 0.f, o3 = 0.f;
    if (valid) {
        ushort4 xrp = *(const ushort4*)(const void*)(xr + (long long)n * 256 + c0);
        float xr0 = bfu(xrp.x), xr1 = bfu(xrp.y), xr2 = bfu(xrp.z), xr3 = bfu(xrp.w);
        float4 atv = *(const float4*)(att + c0);
        float a0 = 0.f, a1 = 0.f, a2 = 0.f, a3 = 0.f, dacc = 0.f;
        int beg = off[n], end = off[n + 1];
        // depth-1 prefetch of the random xl row + ee word
        ushort4 xlp;
        unsigned ep;
        {
            int sid = csr_src[beg];
            xlp = *(const ushort4*)(const void*)(xl + (long long)sid * 256 + c0);
            ep = *(const unsigned*)(ee8 + (long long)beg * 256 + c0);
        }
        for (int i = beg; i < end; ++i) {
            ushort4 cx = xlp;
            unsigned ce = ep;
            if (i + 1 < end) {
                int sid = csr_src[i + 1];
                xlp = *(const ushort4*)(const void*)(xl + (long long)sid * 256 + c0);
                ep = *(const unsigned*)(ee8 + (long long)(i + 1) * 256 + c0);
            }
            float x0 = bfu(cx.x), x1 = bfu(cx.y), x2 = bfu(cx.z), x3 = bfu(cx.w);
            float m0 = x0 + xr0 + fp82f(ce & 0xff);
            float m1 = x1 + xr1 + fp82f((ce >> 8) & 0xff);
            float m2 = x2 + xr2 + fp82f((ce >> 16) & 0xff);
            float m3 = x3 + xr3 + fp82f(ce >> 24);
            m0 = m0 > 0.f ? m0 : 0.2f * m0;
            m1 = m1 > 0.f ? m1 : 0.2f * m1;
            m2 = m2 > 0.f ? m2 : 0.2f * m2;
            m3 = m3 > 0.f ? m3 : 0.2f * m3;
            float p = atv.x * m0 + atv.y * m1 + atv.z * m2 + atv.w * m3;
            p += __shfl_xor(p, 1, 64);
            p += __shfl_xor(p, 2, 64);
            p += __shfl_xor(p, 4, 64);
            p += __shfl_xor(p, 8, 64);   // sum over 16 lanes = one head
            float ex = expf(p);
            a0 += ex * x0; a1 += ex * x1; a2 += ex * x2; a3 += ex * x3;
            dacc += ex;
        }
        float inv = 1.f / dacc;
        o0 = fmaxf(a0 * inv + bias[c0],     0.f);
        o1 = fmaxf(a1 * inv + bias[c0 + 1], 0.f);
        o2 = fmaxf(a2 * inv + bias[c0 + 2], 0.f);
        o3 = fmaxf(a3 * inv + bias[c0 + 3], 0.f);
        if (L1) {
            ushort4 o;
            o.x = f2bf(bng[c0]     * (o0 * INVS) + bnb[c0]);
            o.y = f2bf(bng[c0 + 1] * (o1 * INVS) + bnb[c0 + 1]);
            o.z = f2bf(bng[c0 + 2] * (o2 * INVS) + bnb[c0 + 2]);
            o.w = f2bf(bng[c0 + 3] * (o3 * INVS) + bnb[c0 + 3]);
            *(ushort4*)(void*)(x1bn + (long long)n * 256 + c0) = o;
        }
    }
    if (lane == 0) bid[w] = valid ? batch[n] : -1;
    ps[w][c0]     = o0;
    ps[w][c0 + 1] = o1;
    ps[w][c0 + 2] = o2;
    ps[w][c0 + 3] = o3;
    __syncthreads();
    // pooled: one atomic per channel per block when all valid nodes share a batch id
    int b0 = bid[0];
    bool same = (b0 >= 0)
             && (bid[1] < 0 || bid[1] == b0)
             && (bid[2] < 0 || bid[2] == b0)
             && (bid[3] < 0 || bid[3] == b0);
    if (same) {
        float s = ps[0][t] + ps[1][t] + ps[2][t] + ps[3][t];
        atomicAdd(&pooled[(long long)b0 * 256 + t], s);
    } else if (valid) {
        long long pb = (long long)bid[w] * 256 + c0;
        atomicAdd(&pooled[pb],     o0);
        atomicAdd(&pooled[pb + 1], o1);
        atomicAdd(&pooled[pb + 2], o2);
        atomicAdd(&pooled[pb + 3], o3);
    }
}

// ---------- global MLP layer1 ----------
__global__ void global_mlp1_k(const float* __restrict__ pooled,
                              const float* __restrict__ w1, const float* __restrict__ b1,
                              const float* __restrict__ w2, const float* __restrict__ b2,
                              const float* __restrict__ bng, const float* __restrict__ bnb,
                              float* __restrict__ u1bn) {
    __shared__ float pr[256];
    __shared__ float h[256];
    int t = threadIdx.x, g = blockIdx.x;
    pr[t] = pooled[g * 256 + t];
    __syncthreads();
    float acc = b1[t];
    for (int k = 0; k < 256; ++k) acc += pr[k] * w1[(256 + k) * 256 + t];
    h[t] = fmaxf(acc, 0.f);
    __syncthreads();
    float a2 = b2[t];
    for (int k = 0; k < 256; ++k) a2 += h[k] * w2[k * 256 + t];
    u1bn[g * 256 + t] = bng[t] * (a2 * INVS) + bnb[t];
}

// ---------- weight prep for MFMA edge MLP2 (+ b1x for pre path) ----------
__global__ void conv_weights_k(const float* __restrict__ w1, const float* __restrict__ w2,
                               const float* __restrict__ b1,
                               const float* __restrict__ bg, const float* __restrict__ bb,
                               short* __restrict__ w1s, short* __restrict__ w2s,
                               float* __restrict__ b1x) {
    int gid = blockIdx.x * 256 + threadIdx.x;
    if (gid < 10240) {
        int f = gid >> 6, lane = gid & 63;
        int kk = f >> 3, tt = f & 7;
        int n = tt * 16 + (lane & 15);
        int k0 = kk * 32 + (lane >> 4) * 8;
        short8 v;
        for (int j = 0; j < 8; ++j) {
            int k = k0 + j;
            float x = w1[k * 128 + n];
            if (k >= 512) x *= bg[k - 512] * INVS;
            v[j] = (short)f2bf(x);
        }
        *(short8*)(w1s + (long long)gid * 8) = v;
    } else if (gid < 12288) {
        int g2 = gid - 10240;
        int f = g2 >> 6, lane = g2 & 63;
        int kk = f >> 3, tt = f & 7;
        int n = tt * 16 + (lane & 15);
        int k0 = kk * 32 + (lane >> 4) * 8;
        short8 v;
        for (int j = 0; j < 8; ++j) v[j] = (short)f2bf(w2[(k0 + j) * 128 + n]);
        *(short8*)(w2s + (long long)g2 * 8) = v;
    } else if (gid < 12544) {
        int j = gid - 12288;
        b1x[j] = 0.f;
    } else if (gid < 12672) {
        int j = gid - 12544;
        float acc = b1[j];
        for (int c = 0; c < 128; ++c) acc += bb[c] * w1[(512 + c) * 128 + j];
        b1x[128 + j] = acc;
    }
}

// ---------- Edge MLP 2 via MFMA, factored: acc = pre_s[src] + pre_d[dst](+b1) ; + ea@W1c ; relu ; @W2 ----------
__global__ __launch_bounds__(256) void edge_mlp2_mfma_k(
    const bf16* __restrict__ xpre, bf16* __restrict__ ea_slot,
    const int* __restrict__ csr_src, const int* __restrict__ csr_dst,
    const int* __restrict__ csr_eid,
    const short* __restrict__ w1s,       // uses kk 16..19 (ea rows, BN-folded)
    const short* __restrict__ w2s, const float* __restrict__ b2,
    int NT, int E) {
    __shared__ float Ps[32][132];
    __shared__ short At[32][136];
    __shared__ short Ht[32][136];
    __shared__ int sdv[32][3];
    int t = threadIdx.x;
    long long s0 = (long long)blockIdx.x * 32;
    if (t < 96) {
        int r = t & 31, which = t >> 5;
        long long s = s0 + r;
        int v = (which == 2) ? E : 0;
        if (s < NT) v = (which == 0) ? csr_src[s] : (which == 1 ? csr_dst[s] : csr_eid[s]);
        sdv[r][which] = v;
    }
    __syncthreads();
    for (int i = t; i < 512; i += 256) {
        int r = i >> 4, c = i & 15;
        long long s = s0 + r;
        bool ok = (s < NT) && (sdv[r][2] < E);
        float p[8];
        if (ok) {
            short8 vs = *(const short8*)(const void*)(xpre + (long long)sdv[r][0] * 256 + c * 8);
            short8 vd = *(const short8*)(const void*)(xpre + (long long)sdv[r][1] * 256 + 128 + c * 8);
            for (int j = 0; j < 8; ++j)
                p[j] = bfu((unsigned short)vs[j]) + bfu((unsigned short)vd[j]);
        } else {
            for (int j = 0; j < 8; ++j) p[j] = 0.f;
        }
        for (int j = 0; j < 8; ++j) Ps[r][c * 8 + j] = p[j];
    }
    for (int i = t; i < 512; i += 256) {
        int r = i >> 4, c = i & 15;
        long long s = s0 + r;
        short8 v = {0, 0, 0, 0, 0, 0, 0, 0};
        if (s < NT && sdv[r][2] < E)
            v = *(const short8*)(const void*)(ea_slot + s * 128 + c * 8);
        *(short8*)&At[r][c * 8] = v;
    }
    __syncthreads();

    int w = t >> 6, lane = t & 63;
    int m0 = (w & 1) * 16;
    int nq = (w >> 1) * 4;
    int lr = lane & 15, lq = lane >> 4;

    floatx4 acc[4];
    for (int tt = 0; tt < 4; ++tt) {
        int col = (nq + tt) * 16 + lr;
        for (int r = 0; r < 4; ++r) acc[tt][r] = Ps[m0 + lq * 4 + r][col];
    }
    for (int kk = 0; kk < 4; ++kk) {
        short8 a = *(const short8*)&At[m0 + lr][kk * 32 + lq * 8];
        for (int tt = 0; tt < 4; ++tt) {
            short8 b = *(const short8*)(w1s + ((long long)(((16 + kk) * 8 + nq + tt) * 64 + lane)) * 8);
            acc[tt] = __builtin_amdgcn_mfma_f32_16x16x32_bf16(a, b, acc[tt], 0, 0, 0);
        }
    }
    for (int tt = 0; tt < 4; ++tt) {
        int col = (nq + tt) * 16 + lr;
        for (int r = 0; r < 4; ++r)
            Ht[m0 + lq * 4 + r][col] = (short)f2bf(fmaxf(acc[tt][r], 0.f));
    }
    __syncthreads();

    floatx4 acc2[4];
    for (int i = 0; i < 4; ++i) acc2[i] = (floatx4){0.f, 0.f, 0.f, 0.f};
    for (int kk = 0; kk < 4; ++kk) {
        short8 a = *(const short8*)&Ht[m0 + lr][kk * 32 + lq * 8];
        for (int tt = 0; tt < 4; ++tt) {
            short8 b = *(const short8*)(w2s + ((long long)((kk * 8 + nq + tt) * 64 + lane)) * 8);
            acc2[tt] = __builtin_amdgcn_mfma_f32_16x16x32_bf16(a, b, acc2[tt], 0, 0, 0);
        }
    }
    for (int tt = 0; tt < 4; ++tt) {
        int col = (nq + tt) * 16 + lr;
        float bv = b2[col];
        for (int r = 0; r < 4; ++r)
            At[m0 + lq * 4 + r][col] = (short)f2bf(acc2[tt][r] + bv);
    }
    __syncthreads();
    for (int i = t; i < 512; i += 256) {
        int r = i >> 4, c = i & 15;
        long long s = s0 + r;
        if (s < NT && sdv[r][2] < E)
            *(short8*)(void*)(ea_slot + s * 128 + c * 8) = *(const short8*)&At[r][c * 8];
    }
}

// ---------- final global MLP + head ----------
__global__ void final_mlp_k(const float* __restrict__ u1bn, const float* __restrict__ pooled,
                            const float* __restrict__ w1, const float* __restrict__ b1,
                            const float* __restrict__ w2, const float* __restrict__ b2,
                            const float* __restrict__ f1w, const float* __restrict__ f1b,
                            const float* __restrict__ f2w, const float* __restrict__ f2b,
                            float* __restrict__ out) {
    __shared__ float ub[256], pb[256], h[256], u2[256];
    int t = threadIdx.x, g = blockIdx.x;
    ub[t] = u1bn[g * 256 + t];
    pb[t] = pooled[g * 256 + t];
    __syncthreads();
    float acc = b1[t];
    for (int k = 0; k < 256; ++k)
        acc += ub[k] * w1[k * 256 + t] + pb[k] * w1[(256 + k) * 256 + t];
    h[t] = fmaxf(acc, 0.f);
    __syncthreads();
    float a2 = b2[t];
    for (int k = 0; k < 256; ++k) a2 += h[k] * w2[k * 256 + t];
    u2[t] = a2;
    __syncthreads();
    float fv = 0.f;
    if (t < 64) {
        float a3 = f1b[t];
        for (int k = 0; k < 256; ++k) a3 += u2[k] * f1w[k * 64 + t];
        fv = fmaxf(a3, 0.f) * f2w[t];
    }
    for (int off = 32; off; off >>= 1) fv += __shfl_down(fv, off, 64);
    if (t == 0) out[g] = fv + f2b[0];
}

// ---------- launch ----------
extern "C" void kernel_launch(void* const* d_in, const int* in_sizes, int n_in,
                              void* d_out, int out_size, void* d_ws, size_t ws_size,
                              hipStream_t stream) {
    const float* x         = (const float*)d_in[0];
    const float* edge_attr = (const float*)d_in[1];
    const float* e1_w1 = (const float*)d_in[2];
    const float* e1_b1 = (const float*)d_in[3];
    const float* e1_w2 = (const float*)d_in[4];
    const float* e1_b2 = (const float*)d_in[5];
    const float* g1_lw = (const float*)d_in[6];
    const float* g1_lb = (const float*)d_in[7];
    const float* g1_rw = (const float*)d_in[8];
    const float* g1_rb = (const float*)d_in[9];
    const float* g1_ew = (const float*)d_in[10];
    const float* g1_att = (const float*)d_in[11];
    const float* g1_bias = (const float*)d_in[12];
    const float* u1_w1 = (const float*)d_in[13];
    const float* u1_b1 = (const float*)d_in[14];
    const float* u1_w2 = (const float*)d_in[15];
    const float* u1_b2 = (const float*)d_in[16];
    const float* bn_n_g = (const float*)d_in[17];
    const float* bn_n_b = (const float*)d_in[18];
    const float* bn_e_g = (const float*)d_in[19];
    const float* bn_e_b = (const float*)d_in[20];
    const float* bn_u_g = (const float*)d_in[21];
    const float* bn_u_b = (const float*)d_in[22];
    const float* e2_w1 = (const float*)d_in[23];
    const float* e2_b1 = (const float*)d_in[24];
    const float* e2_w2 = (const float*)d_in[25];
    const float* e2_b2 = (const float*)d_in[26];
    const float* g2_lw = (const float*)d_in[27];
    const float* g2_lb = (const float*)d_in[28];
    const float* g2_rw = (const float*)d_in[29];
    const float* g2_rb = (const float*)d_in[30];
    const float* g2_ew = (const float*)d_in[31];
    const float* g2_att = (const float*)d_in[32];
    const float* g2_bias = (const float*)d_in[33];
    const float* u2_w1 = (const float*)d_in[34];
    const float* u2_b1 = (const float*)d_in[35];
    const float* u2_w2 = (const float*)d_in[36];
    const float* u2_b2 = (const float*)d_in[37];
    const float* fc1_w = (const float*)d_in[38];
    const float* fc1_b = (const float*)d_in[39];
    const float* fc2_w = (const float*)d_in[40];
    const float* fc2_b = (const float*)d_in[41];
    const int* edge_index = (const int*)d_in[42];
    const int* batch = (const int*)d_in[43];

    const int N = in_sizes[0] / 64;
    const int E = in_sizes[1] / 16;
    const int NT = E + N;
    const int G = G_GRAPHS;
    const int* src = edge_index;
    const int* dst = edge_index + E;
    const int NB = (NT + 31) / 32;

    // workspace carve (~249 MB; x1bn aliases xr; pre2 lives in xl during edge_mlp2)
    char* p = (char*)d_ws;
    auto alloc = [&](size_t bytes) { char* r = p; p += (bytes + 255) & ~(size_t)255; return r; };
    bf16* eabuf = (bf16*)alloc((size_t)NT * 128 * 2);
    bf16* xl    = (bf16*)alloc((size_t)N * 256 * 2);
    bf16* xr    = (bf16*)alloc((size_t)N * 256 * 2);
    bf16* x1bn  = xr;
    unsigned char* ee8 = (unsigned char*)alloc((size_t)NT * 256);
    int* degi   = (int*)alloc((size_t)N * 4);
    int* off    = (int*)alloc((size_t)(N + 1) * 4);
    int* fillc  = (int*)alloc((size_t)N * 4);
    int* csr_src = (int*)alloc((size_t)NT * 4);
    int* csr_dst = (int*)alloc((size_t)NT * 4);
    int* csr_eid = (int*)alloc((size_t)NT * 4);
    int* slot_of = (int*)alloc((size_t)E * 4);
    float* pooled = (float*)alloc((size_t)G * 256 * 4);
    float* u1bn = (float*)alloc((size_t)G * 256 * 4);
    short* w1s  = (short*)alloc((size_t)20 * 8 * 64 * 8 * 2);
    short* w2s  = (short*)alloc((size_t)4 * 8 * 64 * 8 * 2);
    float* b1x  = (float*)alloc((size_t)256 * 4);
    short* w1s1 = (short*)alloc((size_t)5 * 4 * 64 * 8 * 2);
    short* w2s1 = (short*)alloc((size_t)2 * 8 * 64 * 8 * 2);
    short* ews1 = (short*)alloc((size_t)4 * 16 * 64 * 8 * 2);
    short* ews2 = (short*)alloc((size_t)4 * 16 * 64 * 8 * 2);
    short* nw1  = (short*)alloc((size_t)2 * 32 * 64 * 8 * 2);
    short* nw2  = (short*)alloc((size_t)8 * 32 * 64 * 8 * 2);
    short* nwp  = (short*)alloc((size_t)8 * 16 * 64 * 8 * 2);

    // ===== CSR build =====
    hipMemsetAsync(degi, 0, (size_t)N * 4, stream);
    hipMemsetAsync(fillc, 0, (size_t)N * 4, stream);
    hipMemsetAsync(pooled, 0, (size_t)G * 256 * 4, stream);
    degi_k<<<(E + 255) / 256, 256, 0, stream>>>(dst, degi, E);
    scan_k<<<1, 1024, 0, stream>>>(degi, off, N);
    fill_csr_k<<<(max(E, N) + 255) / 256, 256, 0, stream>>>(src, dst, off, fillc,
                                                            csr_src, csr_dst, csr_eid,
                                                            slot_of, E, N);

    // ===== layer 1 =====
    conv_weights1_k<<<9, 256, 0, stream>>>(e1_w1, e1_w2, w1s1, w2s1);
    conv_ew_k<<<16, 256, 0, stream>>>(g1_ew, ews1);
    conv_ew_k<<<16, 256, 0, stream>>>(g2_ew, ews2);
    conv_nodew_k<64><<<16, 256, 0, stream>>>(g1_lw, g1_rw, nw1);
    conv_nodew_k<256><<<64, 256, 0, stream>>>(g2_lw, g2_rw, nw2);
    conv_pre2w_k<<<32, 256, 0, stream>>>(e2_w1, nwp);
    edge_mlp1_mfma_k<<<(E + 31) / 32, 256, 0, stream>>>(x, edge_attr, src, dst, slot_of,
                                                        w1s1, e1_b1, w2s1, e1_b2, eabuf, E);
    node_linear_mfma_k<64, float><<<(N + 15) / 16, 256, 0, stream>>>(x, nw1, g1_lb, g1_rb, xl, xr, N);
    gemm_ee_k<<<NB, 256, 0, stream>>>(eabuf, ews1, ee8, NT);
    loop_ee_k<<<(N + 3) / 4, 256, 0, stream>>>(ee8, off, N);
    gat_fused_k<true><<<(N + 3) / 4, 256, 0, stream>>>(ee8, xl, xr, off, csr_src,
                                                       g1_att, g1_bias, bn_n_g, bn_n_b,
                                                       batch, x1bn, pooled, N);
    global_mlp1_k<<<G, 256, 0, stream>>>(pooled, u1_w1, u1_b1, u1_w2, u1_b2, bn_u_g, bn_u_b, u1bn);

    // ===== layer 2 =====
    conv_weights_k<<<50, 256, 0, stream>>>(e2_w1, e2_w2, e2_b1, bn_e_g, bn_e_b, w1s, w2s, b1x);
    pre_mfma_k<<<(N + 15) / 16, 256, 0, stream>>>(x1bn, nwp, b1x, xl, N);
    edge_mlp2_mfma_k<<<NB, 256, 0, stream>>>(xl, eabuf, csr_src, csr_dst, csr_eid,
                                             w1s, w2s, e2_b2, NT, E);
    node_linear_mfma_k<256, bf16><<<(N + 15) / 16, 256, 0, stream>>>(x1bn, nw2, g2_lb, g2_rb, xl, xr, N);
    hipMemsetAsync(pooled, 0, (size_t)G * 256 * 4, stream);
    gemm_ee_k<<<NB, 256, 0, stream>>>(eabuf, ews2, ee8, NT);
    loop_ee_k<<<(N + 3) / 4, 256, 0, stream>>>(ee8, off, N);
    gat_fused_k<false><<<(N + 3) / 4, 256, 0, stream>>>(ee8, xl, xr, off, csr_src,
                                                        g2_att, g2_bias, nullptr, nullptr,
                                                        batch, nullptr, pooled, N);
    final_mlp_k<<<G, 256, 0, stream>>>(u1bn, pooled, u2_w1, u2_b1, u2_w2, u2_b2,
                                       fc1_w, fc1_b, fc2_w, fc2_b, (float*)d_out);
}

// Round 17
// 859.758 us; speedup vs baseline: 1.5987x; 1.1012x over previous
//
#include <hip/hip_runtime.h>
#include <hip/hip_bf16.h>
#include <hip/hip_fp8.h>
#include <cstdint>
#include <cstddef>

#define INVS 0.99999500003749968f  // 1/sqrt(1+1e-5)
#define G_GRAPHS 256

using bf16 = __hip_bfloat16;
using short8 = __attribute__((ext_vector_type(8))) short;
using floatx4 = __attribute__((ext_vector_type(4))) float;

// ---------- helpers ----------
__device__ __forceinline__ unsigned short f2bf(float v) {
    union { float f; unsigned u; } x; x.f = v;
    unsigned r = x.u + 0x7fffu + ((x.u >> 16) & 1u);
    return (unsigned short)(r >> 16);
}
__device__ __forceinline__ float bfu(unsigned short u) { return __uint_as_float((unsigned)u << 16); }
__device__ __forceinline__ unsigned char f2fp8(float v) {
    __hip_fp8_e4m3 q(v); return q.__x;
}
__device__ __forceinline__ float fp82f(unsigned char b) {
    __hip_fp8_e4m3 q; q.__x = b; return (float)q;
}

// ---------- CSR build ----------
__global__ void degi_k(const int* __restrict__ dst, int* __restrict__ degi, int E) {
    int gid = blockIdx.x * 256 + threadIdx.x;
    if (gid < E) atomicAdd(&degi[dst[gid]], 1);
}

// Hierarchical exclusive scan of (degi[i]+1), i in [0,N). Phase 1: 2048/block.
__global__ __launch_bounds__(1024) void scan_blk_k(const int* __restrict__ degi,
                                                   int* __restrict__ off,
                                                   int* __restrict__ bsum, int N) {
    __shared__ int buf[1024];
    int t = threadIdx.x;
    int base = blockIdx.x * 2048;
    int i0 = base + 2 * t, i1 = base + 2 * t + 1;
    int v0 = (i0 < N) ? (degi[i0] + 1) : 0;
    int v1 = (i1 < N) ? (degi[i1] + 1) : 0;
    int s = v0 + v1;
    buf[t] = s;
    __syncthreads();
    for (int ofs = 1; ofs < 1024; ofs <<= 1) {
        int add = (t >= ofs) ? buf[t - ofs] : 0;
        __syncthreads();
        buf[t] += add;
        __syncthreads();
    }
    int excl = buf[t] - s;           // exclusive sum of pairs before this thread
    if (i0 < N) off[i0] = excl;
    if (i1 < N) off[i1] = excl + v0;
    if (t == 1023) bsum[blockIdx.x] = buf[1023];
}

// Phase 2: serial scan of block sums (NBLK ~ 25), writes off[N] = grand total.
__global__ void scan_top_k(const int* __restrict__ bsum, int* __restrict__ boff,
                           int* __restrict__ off, int NBLK, int N) {
    if (threadIdx.x == 0 && blockIdx.x == 0) {
        int run = 0;
        for (int i = 0; i < NBLK; ++i) { boff[i] = run; run += bsum[i]; }
        off[N] = run;
    }
}

// Phase 3: add block offsets.
__global__ void scan_add_k(int* __restrict__ off, const int* __restrict__ boff, int N) {
    int gid = blockIdx.x * 256 + threadIdx.x;
    if (gid < N) off[gid] += boff[gid >> 11];
}

__global__ void fill_csr_k(const int* __restrict__ src, const int* __restrict__ dst,
                           const int* __restrict__ off, int* __restrict__ fillc,
                           int* __restrict__ csr_src, int* __restrict__ csr_dst,
                           int* __restrict__ csr_eid, int* __restrict__ slot_of,
                           int E, int N) {
    int gid = blockIdx.x * 256 + threadIdx.x;
    if (gid < E) {
        int d = dst[gid];
        int slot = off[d] + atomicAdd(&fillc[d], 1);
        csr_src[slot] = src[gid];
        csr_dst[slot] = d;
        csr_eid[slot] = gid;
        slot_of[gid] = slot;
    }
    if (gid < N) {
        int slot = off[gid + 1] - 1;   // reserved last slot = self-loop
        csr_src[slot] = gid;
        csr_dst[slot] = gid;
        csr_eid[slot] = E + gid;       // >= E marks self-loop
    }
}

// ---------- weight prep for MFMA edge MLP1 ----------
__global__ void conv_weights1_k(const float* __restrict__ w1, const float* __restrict__ w2,
                                short* __restrict__ w1s, short* __restrict__ w2s) {
    int gid = blockIdx.x * 256 + threadIdx.x;
    if (gid < 1280) {
        int f = gid >> 6, lane = gid & 63;
        int kk = f >> 2, tt = f & 3;
        int n = tt * 16 + (lane & 15);
        int k0 = kk * 32 + (lane >> 4) * 8;
        short8 v;
        for (int j = 0; j < 8; ++j) {
            int k = k0 + j;
            v[j] = (k < 144) ? (short)f2bf(w1[k * 64 + n]) : (short)0;
        }
        *(short8*)(w1s + (long long)gid * 8) = v;
    } else if (gid < 2304) {
        int g2 = gid - 1280;
        int f = g2 >> 6, lane = g2 & 63;
        int kk = f >> 3, tt = f & 7;
        int n = tt * 16 + (lane & 15);
        int k0 = kk * 32 + (lane >> 4) * 8;
        short8 v;
        for (int j = 0; j < 8; ++j) v[j] = (short)f2bf(w2[(k0 + j) * 128 + n]);
        *(short8*)(w2s + (long long)g2 * 8) = v;
    }
}

// ---------- ew prep: ew[128][256] -> frags 4 kk x 16 tt ----------
__global__ void conv_ew_k(const float* __restrict__ ew, short* __restrict__ ews) {
    int gid = blockIdx.x * 256 + threadIdx.x;
    if (gid >= 4096) return;
    int f = gid >> 6, lane = gid & 63;
    int kk = f >> 4, tt = f & 15;
    int n = tt * 16 + (lane & 15);
    int k0 = kk * 32 + (lane >> 4) * 8;
    short8 v;
    for (int j = 0; j < 8; ++j) v[j] = (short)f2bf(ew[(k0 + j) * 256 + n]);
    *(short8*)(ews + (long long)gid * 8) = v;
}

// ---------- node-linear weight prep: [wl|wr] (K x 512) -> frags ----------
template <int K>
__global__ void conv_nodew_k(const float* __restrict__ wl, const float* __restrict__ wr,
                             short* __restrict__ out) {
    int gid = blockIdx.x * 256 + threadIdx.x;
    if (gid >= (K / 32) * 32 * 64) return;
    int f = gid >> 6, lane = gid & 63;
    int kk = f >> 5, tt = f & 31;
    int n = tt * 16 + (lane & 15);
    int k0 = kk * 32 + (lane >> 4) * 8;
    short8 v;
    for (int j = 0; j < 8; ++j) {
        int k = k0 + j;
        float x = (n < 256) ? wl[k * 256 + n] : wr[k * 256 + (n - 256)];
        v[j] = (short)f2bf(x);
    }
    *(short8*)(out + (long long)gid * 8) = v;
}

// ---------- pre2 weight prep: M[256][256], M[k][n<128]=w1[k][n], M[k][n>=128]=w1[256+k][n-128] ----------
__global__ void conv_pre2w_k(const float* __restrict__ w1, short* __restrict__ out) {
    int gid = blockIdx.x * 256 + threadIdx.x;
    if (gid >= 8 * 16 * 64) return;
    int f = gid >> 6, lane = gid & 63;
    int kk = f >> 4, tt = f & 15;
    int n = tt * 16 + (lane & 15);
    int k0 = kk * 32 + (lane >> 4) * 8;
    short8 v;
    for (int j = 0; j < 8; ++j) {
        int k = k0 + j;
        float x = (n < 128) ? w1[k * 128 + n] : w1[(256 + k) * 128 + (n - 128)];
        v[j] = (short)f2bf(x);
    }
    *(short8*)(out + (long long)gid * 8) = v;
}

// ---------- Edge MLP 1 via MFMA: eid-order compute, scatter rows to CSR slots ----------
__global__ __launch_bounds__(256) void edge_mlp1_mfma_k(
    const float* __restrict__ x, const float* __restrict__ ea,
    const int* __restrict__ src, const int* __restrict__ dst,
    const int* __restrict__ slot_of,
    const short* __restrict__ w1s, const float* __restrict__ b1,
    const short* __restrict__ w2s, const float* __restrict__ b2,
    bf16* __restrict__ out, int E) {
    __shared__ short At[32][168];
    __shared__ short Ht[32][72];
    __shared__ int sdv[32][2];
    __shared__ int slt[32];
    int t = threadIdx.x;
    long long e0 = (long long)blockIdx.x * 32;
    if (t < 64) {
        int r = t & 31;
        long long e = e0 + r;
        int v = 0;
        if (e < E) v = (t < 32) ? src[e] : dst[e];
        sdv[r][t >> 5] = v;
    } else if (t < 96) {
        int r = t - 64;
        long long e = e0 + r;
        slt[r] = (e < E) ? slot_of[e] : -1;
    }
    __syncthreads();
    for (int i = t; i < 32 * 40; i += 256) {
        int r = i / 40, c = i - r * 40;
        long long e = e0 + r;
        float4 v = {0.f, 0.f, 0.f, 0.f};
        if (e < E) {
            if (c < 16)      v = *(const float4*)(x + (long long)sdv[r][0] * 64 + c * 4);
            else if (c < 32) v = *(const float4*)(x + (long long)sdv[r][1] * 64 + (c - 16) * 4);
            else if (c < 36) v = *(const float4*)(ea + e * 16 + (c - 32) * 4);
        }
        ushort4 pk;
        pk.x = f2bf(v.x); pk.y = f2bf(v.y); pk.z = f2bf(v.z); pk.w = f2bf(v.w);
        *(ushort4*)&At[r][c * 4] = pk;
    }
    __syncthreads();

    int w = t >> 6, lane = t & 63;
    int m0 = (w & 1) * 16;
    int lr = lane & 15, lq = lane >> 4;

    int nq1 = (w >> 1) * 2;
    floatx4 acc[2];
    for (int i = 0; i < 2; ++i) acc[i] = (floatx4){0.f, 0.f, 0.f, 0.f};
    for (int kk = 0; kk < 5; ++kk) {
        short8 a = *(const short8*)&At[m0 + lr][kk * 32 + lq * 8];
        for (int tt = 0; tt < 2; ++tt) {
            short8 b = *(const short8*)(w1s + ((long long)((kk * 4 + nq1 + tt) * 64 + lane)) * 8);
            acc[tt] = __builtin_amdgcn_mfma_f32_16x16x32_bf16(a, b, acc[tt], 0, 0, 0);
        }
    }
    for (int tt = 0; tt < 2; ++tt) {
        int col = (nq1 + tt) * 16 + lr;
        float bv = b1[col];
        for (int r = 0; r < 4; ++r)
            Ht[m0 + lq * 4 + r][col] = (short)f2bf(fmaxf(acc[tt][r] + bv, 0.f));
    }
    __syncthreads();

    int nq2 = (w >> 1) * 4;
    floatx4 acc2[4];
    for (int i = 0; i < 4; ++i) acc2[i] = (floatx4){0.f, 0.f, 0.f, 0.f};
    for (int kk = 0; kk < 2; ++kk) {
        short8 a = *(const short8*)&Ht[m0 + lr][kk * 32 + lq * 8];
        for (int tt = 0; tt < 4; ++tt) {
            short8 b = *(const short8*)(w2s + ((long long)((kk * 8 + nq2 + tt) * 64 + lane)) * 8);
            acc2[tt] = __builtin_amdgcn_mfma_f32_16x16x32_bf16(a, b, acc2[tt], 0, 0, 0);
        }
    }
    for (int tt = 0; tt < 4; ++tt) {
        int col = (nq2 + tt) * 16 + lr;
        float bv = b2[col];
        for (int r = 0; r < 4; ++r)
            At[m0 + lq * 4 + r][col] = (short)f2bf(acc2[tt][r] + bv);
    }
    __syncthreads();
    for (int i = t; i < 512; i += 256) {
        int r = i >> 4, c = i & 15;
        int s = slt[r];
        if (s >= 0)
            *(short8*)(void*)(out + (long long)s * 128 + c * 8) = *(const short8*)&At[r][c * 8];
    }
}

// ---------- node linear via MFMA: [N x K] @ [K x 512] (= [wl|wr]) + bias ----------
// NOTE: x may alias xr (x1bn overlay) — per-block reads complete before same-row writes.
template <int K, typename T>
__global__ __launch_bounds__(256) void node_linear_mfma_k(
    const T* x, const short* __restrict__ ws,
    const float* __restrict__ bl, const float* __restrict__ br,
    bf16* __restrict__ xl, bf16* xr, int N) {
    __shared__ short At[16][K + 8];
    __shared__ short Ot[16][520];
    int t = threadIdx.x;
    long long n0 = (long long)blockIdx.x * 16;
    if (sizeof(T) == 4) {
        for (int i = t; i < 16 * (K / 4); i += 256) {
            int r = i / (K / 4), c = i % (K / 4);
            long long n = n0 + r;
            float4 v = {0.f, 0.f, 0.f, 0.f};
            if (n < N) v = *(const float4*)((const float*)x + n * K + c * 4);
            ushort4 pk;
            pk.x = f2bf(v.x); pk.y = f2bf(v.y); pk.z = f2bf(v.z); pk.w = f2bf(v.w);
            *(ushort4*)&At[r][c * 4] = pk;
        }
    } else {
        for (int i = t; i < 16 * (K / 8); i += 256) {
            int r = i / (K / 8), c = i % (K / 8);
            long long n = n0 + r;
            short8 v = {0, 0, 0, 0, 0, 0, 0, 0};
            if (n < N) v = *(const short8*)(const void*)((const bf16*)x + n * K + c * 8);
            *(short8*)&At[r][c * 8] = v;
        }
    }
    __syncthreads();

    int w = t >> 6, lane = t & 63;
    int nq = w * 8;
    int lr = lane & 15, lq = lane >> 4;

    floatx4 acc[8];
    for (int i = 0; i < 8; ++i) acc[i] = (floatx4){0.f, 0.f, 0.f, 0.f};
    for (int kk = 0; kk < K / 32; ++kk) {
        short8 a = *(const short8*)&At[lr][kk * 32 + lq * 8];
        for (int tt = 0; tt < 8; ++tt) {
            short8 b = *(const short8*)(ws + ((long long)((kk * 32 + nq + tt) * 64 + lane)) * 8);
            acc[tt] = __builtin_amdgcn_mfma_f32_16x16x32_bf16(a, b, acc[tt], 0, 0, 0);
        }
    }
    for (int tt = 0; tt < 8; ++tt) {
        int col = (nq + tt) * 16 + lr;
        float bv = (col < 256) ? bl[col] : br[col - 256];
        for (int r = 0; r < 4; ++r)
            Ot[lq * 4 + r][col] = (short)f2bf(acc[tt][r] + bv);
    }
    __syncthreads();
    for (int i = t; i < 1024; i += 256) {
        int r = i >> 6, c = i & 63;
        long long n = n0 + r;
        if (n < N) {
            short8 v = *(const short8*)&Ot[r][c * 8];
            if (c < 32) *(short8*)(void*)(xl + n * 256 + c * 8) = v;
            else        *(short8*)(void*)(xr + n * 256 + (c - 32) * 8) = v;
        }
    }
}

// ---------- pre2: xp = x1bn @ M[256x256] + b1x  -> xl buffer ----------
__global__ __launch_bounds__(256) void pre_mfma_k(
    const bf16* __restrict__ x, const short* __restrict__ ws,
    const float* __restrict__ bx, bf16* __restrict__ out, int N) {
    __shared__ short At[16][264];
    __shared__ short Ot[16][264];
    int t = threadIdx.x;
    long long n0 = (long long)blockIdx.x * 16;
    for (int i = t; i < 512; i += 256) {
        int r = i >> 5, c = i & 31;
        long long n = n0 + r;
        short8 v = {0, 0, 0, 0, 0, 0, 0, 0};
        if (n < N) v = *(const short8*)(const void*)(x + n * 256 + c * 8);
        *(short8*)&At[r][c * 8] = v;
    }
    __syncthreads();

    int w = t >> 6, lane = t & 63;
    int nq = w * 4;
    int lr = lane & 15, lq = lane >> 4;

    floatx4 acc[4];
    for (int i = 0; i < 4; ++i) acc[i] = (floatx4){0.f, 0.f, 0.f, 0.f};
    for (int kk = 0; kk < 8; ++kk) {
        short8 a = *(const short8*)&At[lr][kk * 32 + lq * 8];
        for (int tt = 0; tt < 4; ++tt) {
            short8 b = *(const short8*)(ws + ((long long)((kk * 16 + nq + tt) * 64 + lane)) * 8);
            acc[tt] = __builtin_amdgcn_mfma_f32_16x16x32_bf16(a, b, acc[tt], 0, 0, 0);
        }
    }
    for (int tt = 0; tt < 4; ++tt) {
        int col = (nq + tt) * 16 + lr;
        float bv = bx[col];
        for (int r = 0; r < 4; ++r)
            Ot[lq * 4 + r][col] = (short)f2bf(acc[tt][r] + bv);
    }
    __syncthreads();
    for (int i = t; i < 512; i += 256) {
        int r = i >> 5, c = i & 31;
        long long n = n0 + r;
        if (n < N)
            *(short8*)(void*)(out + n * 256 + c * 8) = *(const short8*)&Ot[r][c * 8];
    }
}

// ---------- ee GEMM, full 256 channels, fp8 out, slot order ----------
__global__ __launch_bounds__(256) void gemm_ee_k(
    const bf16* __restrict__ ea_slot, const short* __restrict__ ews,
    unsigned char* __restrict__ ee8, int NT) {
    __shared__ short At[32][136];
    __shared__ unsigned char Et[32][264];
    int t = threadIdx.x;
    long long s0 = (long long)blockIdx.x * 32;
    for (int i = t; i < 32 * 16; i += 256) {
        int r = i >> 4, c = i & 15;
        long long s = s0 + r;
        short8 v = {0, 0, 0, 0, 0, 0, 0, 0};
        if (s < NT) v = *(const short8*)(const void*)(ea_slot + s * 128 + c * 8);
        *(short8*)&At[r][c * 8] = v;
    }
    __syncthreads();

    int w = t >> 6, lane = t & 63;
    int m0 = (w & 1) * 16, nq = (w >> 1) * 8;
    int lr = lane & 15, lq = lane >> 4;

    floatx4 acc[8];
    for (int i = 0; i < 8; ++i) acc[i] = (floatx4){0.f, 0.f, 0.f, 0.f};
    for (int kk = 0; kk < 4; ++kk) {
        short8 a = *(const short8*)&At[m0 + lr][kk * 32 + lq * 8];
        for (int tt = 0; tt < 8; ++tt) {
            short8 b = *(const short8*)(ews + ((long long)((kk * 16 + nq + tt) * 64 + lane)) * 8);
            acc[tt] = __builtin_amdgcn_mfma_f32_16x16x32_bf16(a, b, acc[tt], 0, 0, 0);
        }
    }
    for (int tt = 0; tt < 8; ++tt) {
        int col = (nq + tt) * 16 + lr;
        for (int r = 0; r < 4; ++r)
            Et[m0 + lq * 4 + r][col] = f2fp8(acc[tt][r]);
    }
    __syncthreads();
    for (int i = t; i < 2048; i += 256) {
        int r = i >> 6, c = i & 63;
        long long s = s0 + r;
        if (s < NT)
            *(unsigned*)(ee8 + s * 256 + c * 4) = *(const unsigned*)&Et[r][c * 4];
    }
}

// ---------- self-loop ee = mean of incoming ee rows (fp8) ----------
__global__ __launch_bounds__(256) void loop_ee_k(unsigned char* __restrict__ ee8,
                                                 const int* __restrict__ off, int N) {
    int t = threadIdx.x;
    int w = t >> 6, lane = t & 63;
    int n = blockIdx.x * 4 + w;
    if (n >= N) return;
    int beg = off[n], end = off[n + 1] - 1;
    float a0 = 0.f, a1 = 0.f, a2 = 0.f, a3 = 0.f;
    for (int i = beg; i < end; ++i) {
        unsigned pk = *(const unsigned*)(ee8 + (long long)i * 256 + lane * 4);
        a0 += fp82f(pk & 0xff);
        a1 += fp82f((pk >> 8) & 0xff);
        a2 += fp82f((pk >> 16) & 0xff);
        a3 += fp82f(pk >> 24);
    }
    float dv = fmaxf((float)(end - beg), 1.f);
    unsigned o = (unsigned)f2fp8(a0 / dv)
               | ((unsigned)f2fp8(a1 / dv) << 8)
               | ((unsigned)f2fp8(a2 / dv) << 16)
               | ((unsigned)f2fp8(a3 / dv) << 24);
    *(unsigned*)(ee8 + (long long)end * 256 + lane * 4) = o;
}

// ---------- Fused GATv2 attention + aggregation + finalize ----------
// Single pass, all 4 heads; depth-1 prefetch; block-level pooled reduction (batch sorted).
// NOTE: x1bn may alias xr — xr[n] is read only by the owning wave, before its write.
template <bool L1>
__global__ __launch_bounds__(256) void gat_fused_k(
    const unsigned char* __restrict__ ee8, const bf16* __restrict__ xl, const bf16* xr,
    const int* __restrict__ off, const int* __restrict__ csr_src,
    const float* __restrict__ att, const float* __restrict__ bias,
    const float* __restrict__ bng, const float* __restrict__ bnb,
    const int* __restrict__ batch,
    bf16* x1bn, float* __restrict__ pooled, int N) {
    __shared__ float ps[4][260];
    __shared__ int bid[4];
    int t = threadIdx.x;
    int w = t >> 6, lane = t & 63;
    int n = blockIdx.x * 4 + w;
    bool valid = n < N;
    int c0 = lane * 4;
    float o0 = 0.f, o1 = 0.f, o2 = 0.f, o3 = 0.f;
    if (valid) {
        ushort4 xrp = *(const ushort4*)(const void*)(xr + (long long)n * 256 + c0);
        float xr0 = bfu(xrp.x), xr1 = bfu(xrp.y), xr2 = bfu(xrp.z), xr3 = bfu(xrp.w);
        float4 atv = *(const float4*)(att + c0);
        float a0 = 0.f, a1 = 0.f, a2 = 0.f, a3 = 0.f, dacc = 0.f;
        int beg = off[n], end = off[n + 1];
        ushort4 xlp;
        unsigned ep;
        {
            int sid = csr_src[beg];
            xlp = *(const ushort4*)(const void*)(xl + (long long)sid * 256 + c0);
            ep = *(const unsigned*)(ee8 + (long long)beg * 256 + c0);
        }
        for (int i = beg; i < end; ++i) {
            ushort4 cx = xlp;
            unsigned ce = ep;
            if (i + 1 < end) {
                int sid = csr_src[i + 1];
                xlp = *(const ushort4*)(const void*)(xl + (long long)sid * 256 + c0);
                ep = *(const unsigned*)(ee8 + (long long)(i + 1) * 256 + c0);
            }
            float x0 = bfu(cx.x), x1 = bfu(cx.y), x2 = bfu(cx.z), x3 = bfu(cx.w);
            float m0 = x0 + xr0 + fp82f(ce & 0xff);
            float m1 = x1 + xr1 + fp82f((ce >> 8) & 0xff);
            float m2 = x2 + xr2 + fp82f((ce >> 16) & 0xff);
            float m3 = x3 + xr3 + fp82f(ce >> 24);
            m0 = m0 > 0.f ? m0 : 0.2f * m0;
            m1 = m1 > 0.f ? m1 : 0.2f * m1;
            m2 = m2 > 0.f ? m2 : 0.2f * m2;
            m3 = m3 > 0.f ? m3 : 0.2f * m3;
            float p = atv.x * m0 + atv.y * m1 + atv.z * m2 + atv.w * m3;
            p += __shfl_xor(p, 1, 64);
            p += __shfl_xor(p, 2, 64);
            p += __shfl_xor(p, 4, 64);
            p += __shfl_xor(p, 8, 64);
            float ex = expf(p);
            a0 += ex * x0; a1 += ex * x1; a2 += ex * x2; a3 += ex * x3;
            dacc += ex;
        }
        float inv = 1.f / dacc;
        o0 = fmaxf(a0 * inv + bias[c0],     0.f);
        o1 = fmaxf(a1 * inv + bias[c0 + 1], 0.f);
        o2 = fmaxf(a2 * inv + bias[c0 + 2], 0.f);
        o3 = fmaxf(a3 * inv + bias[c0 + 3], 0.f);
        if (L1) {
            ushort4 o;
            o.x = f2bf(bng[c0]     * (o0 * INVS) + bnb[c0]);
            o.y = f2bf(bng[c0 + 1] * (o1 * INVS) + bnb[c0 + 1]);
            o.z = f2bf(bng[c0 + 2] * (o2 * INVS) + bnb[c0 + 2]);
            o.w = f2bf(bng[c0 + 3] * (o3 * INVS) + bnb[c0 + 3]);
            *(ushort4*)(void*)(x1bn + (long long)n * 256 + c0) = o;
        }
    }
    if (lane == 0) bid[w] = valid ? batch[n] : -1;
    ps[w][c0]     = o0;
    ps[w][c0 + 1] = o1;
    ps[w][c0 + 2] = o2;
    ps[w][c0 + 3] = o3;
    __syncthreads();
    int b0 = bid[0];
    bool same = (b0 >= 0)
             && (bid[1] < 0 || bid[1] == b0)
             && (bid[2] < 0 || bid[2] == b0)
             && (bid[3] < 0 || bid[3] == b0);
    if (same) {
        float s = ps[0][t] + ps[1][t] + ps[2][t] + ps[3][t];
        atomicAdd(&pooled[(long long)b0 * 256 + t], s);
    } else if (valid) {
        long long pb = (long long)bid[w] * 256 + c0;
        atomicAdd(&pooled[pb],     o0);
        atomicAdd(&pooled[pb + 1], o1);
        atomicAdd(&pooled[pb + 2], o2);
        atomicAdd(&pooled[pb + 3], o3);
    }
}

// ---------- global MLP layer1 ----------
__global__ void global_mlp1_k(const float* __restrict__ pooled,
                              const float* __restrict__ w1, const float* __restrict__ b1,
                              const float* __restrict__ w2, const float* __restrict__ b2,
                              const float* __restrict__ bng, const float* __restrict__ bnb,
                              float* __restrict__ u1bn) {
    __shared__ float pr[256];
    __shared__ float h[256];
    int t = threadIdx.x, g = blockIdx.x;
    pr[t] = pooled[g * 256 + t];
    __syncthreads();
    float acc = b1[t];
    for (int k = 0; k < 256; ++k) acc += pr[k] * w1[(256 + k) * 256 + t];
    h[t] = fmaxf(acc, 0.f);
    __syncthreads();
    float a2 = b2[t];
    for (int k = 0; k < 256; ++k) a2 += h[k] * w2[k * 256 + t];
    u1bn[g * 256 + t] = bng[t] * (a2 * INVS) + bnb[t];
}

// ---------- weight prep for MFMA edge MLP2 (+ b1x for pre path) ----------
__global__ void conv_weights_k(const float* __restrict__ w1, const float* __restrict__ w2,
                               const float* __restrict__ b1,
                               const float* __restrict__ bg, const float* __restrict__ bb,
                               short* __restrict__ w1s, short* __restrict__ w2s,
                               float* __restrict__ b1x) {
    int gid = blockIdx.x * 256 + threadIdx.x;
    if (gid < 10240) {
        int f = gid >> 6, lane = gid & 63;
        int kk = f >> 3, tt = f & 7;
        int n = tt * 16 + (lane & 15);
        int k0 = kk * 32 + (lane >> 4) * 8;
        short8 v;
        for (int j = 0; j < 8; ++j) {
            int k = k0 + j;
            float x = w1[k * 128 + n];
            if (k >= 512) x *= bg[k - 512] * INVS;
            v[j] = (short)f2bf(x);
        }
        *(short8*)(w1s + (long long)gid * 8) = v;
    } else if (gid < 12288) {
        int g2 = gid - 10240;
        int f = g2 >> 6, lane = g2 & 63;
        int kk = f >> 3, tt = f & 7;
        int n = tt * 16 + (lane & 15);
        int k0 = kk * 32 + (lane >> 4) * 8;
        short8 v;
        for (int j = 0; j < 8; ++j) v[j] = (short)f2bf(w2[(k0 + j) * 128 + n]);
        *(short8*)(w2s + (long long)g2 * 8) = v;
    } else if (gid < 12544) {
        int j = gid - 12288;
        b1x[j] = 0.f;
    } else if (gid < 12672) {
        int j = gid - 12544;
        float acc = b1[j];
        for (int c = 0; c < 128; ++c) acc += bb[c] * w1[(512 + c) * 128 + j];
        b1x[128 + j] = acc;
    }
}

// ---------- Edge MLP 2 via MFMA, factored: acc = pre_s[src] + pre_d[dst](+b1) ; + ea@W1c ; relu ; @W2 ----------
__global__ __launch_bounds__(256) void edge_mlp2_mfma_k(
    const bf16* __restrict__ xpre, bf16* __restrict__ ea_slot,
    const int* __restrict__ csr_src, const int* __restrict__ csr_dst,
    const int* __restrict__ csr_eid,
    const short* __restrict__ w1s,       // uses kk 16..19 (ea rows, BN-folded)
    const short* __restrict__ w2s, const float* __restrict__ b2,
    int NT, int E) {
    __shared__ float Ps[32][132];
    __shared__ short At[32][136];
    __shared__ short Ht[32][136];
    __shared__ int sdv[32][3];
    int t = threadIdx.x;
    long long s0 = (long long)blockIdx.x * 32;
    if (t < 96) {
        int r = t & 31, which = t >> 5;
        long long s = s0 + r;
        int v = (which == 2) ? E : 0;
        if (s < NT) v = (which == 0) ? csr_src[s] : (which == 1 ? csr_dst[s] : csr_eid[s]);
        sdv[r][which] = v;
    }
    __syncthreads();
    for (int i = t; i < 512; i += 256) {
        int r = i >> 4, c = i & 15;
        long long s = s0 + r;
        bool ok = (s < NT) && (sdv[r][2] < E);
        float p[8];
        if (ok) {
            short8 vs = *(const short8*)(const void*)(xpre + (long long)sdv[r][0] * 256 + c * 8);
            short8 vd = *(const short8*)(const void*)(xpre + (long long)sdv[r][1] * 256 + 128 + c * 8);
            for (int j = 0; j < 8; ++j)
                p[j] = bfu((unsigned short)vs[j]) + bfu((unsigned short)vd[j]);
        } else {
            for (int j = 0; j < 8; ++j) p[j] = 0.f;
        }
        for (int j = 0; j < 8; ++j) Ps[r][c * 8 + j] = p[j];
    }
    for (int i = t; i < 512; i += 256) {
        int r = i >> 4, c = i & 15;
        long long s = s0 + r;
        short8 v = {0, 0, 0, 0, 0, 0, 0, 0};
        if (s < NT && sdv[r][2] < E)
            v = *(const short8*)(const void*)(ea_slot + s * 128 + c * 8);
        *(short8*)&At[r][c * 8] = v;
    }
    __syncthreads();

    int w = t >> 6, lane = t & 63;
    int m0 = (w & 1) * 16;
    int nq = (w >> 1) * 4;
    int lr = lane & 15, lq = lane >> 4;

    floatx4 acc[4];
    for (int tt = 0; tt < 4; ++tt) {
        int col = (nq + tt) * 16 + lr;
        for (int r = 0; r < 4; ++r) acc[tt][r] = Ps[m0 + lq * 4 + r][col];
    }
    for (int kk = 0; kk < 4; ++kk) {
        short8 a = *(const short8*)&At[m0 + lr][kk * 32 + lq * 8];
        for (int tt = 0; tt < 4; ++tt) {
            short8 b = *(const short8*)(w1s + ((long long)(((16 + kk) * 8 + nq + tt) * 64 + lane)) * 8);
            acc[tt] = __builtin_amdgcn_mfma_f32_16x16x32_bf16(a, b, acc[tt], 0, 0, 0);
        }
    }
    for (int tt = 0; tt < 4; ++tt) {
        int col = (nq + tt) * 16 + lr;
        for (int r = 0; r < 4; ++r)
            Ht[m0 + lq * 4 + r][col] = (short)f2bf(fmaxf(acc[tt][r], 0.f));
    }
    __syncthreads();

    floatx4 acc2[4];
    for (int i = 0; i < 4; ++i) acc2[i] = (floatx4){0.f, 0.f, 0.f, 0.f};
    for (int kk = 0; kk < 4; ++kk) {
        short8 a = *(const short8*)&Ht[m0 + lr][kk * 32 + lq * 8];
        for (int tt = 0; tt < 4; ++tt) {
            short8 b = *(const short8*)(w2s + ((long long)((kk * 8 + nq + tt) * 64 + lane)) * 8);
            acc2[tt] = __builtin_amdgcn_mfma_f32_16x16x32_bf16(a, b, acc2[tt], 0, 0, 0);
        }
    }
    for (int tt = 0; tt < 4; ++tt) {
        int col = (nq + tt) * 16 + lr;
        float bv = b2[col];
        for (int r = 0; r < 4; ++r)
            At[m0 + lq * 4 + r][col] = (short)f2bf(acc2[tt][r] + bv);
    }
    __syncthreads();
    for (int i = t; i < 512; i += 256) {
        int r = i >> 4, c = i & 15;
        long long s = s0 + r;
        if (s < NT && sdv[r][2] < E)
            *(short8*)(void*)(ea_slot + s * 128 + c * 8) = *(const short8*)&At[r][c * 8];
    }
}

// ---------- final global MLP + head ----------
__global__ void final_mlp_k(const float* __restrict__ u1bn, const float* __restrict__ pooled,
                            const float* __restrict__ w1, const float* __restrict__ b1,
                            const float* __restrict__ w2, const float* __restrict__ b2,
                            const float* __restrict__ f1w, const float* __restrict__ f1b,
                            const float* __restrict__ f2w, const float* __restrict__ f2b,
                            float* __restrict__ out) {
    __shared__ float ub[256], pb[256], h[256], u2[256];
    int t = threadIdx.x, g = blockIdx.x;
    ub[t] = u1bn[g * 256 + t];
    pb[t] = pooled[g * 256 + t];
    __syncthreads();
    float acc = b1[t];
    for (int k = 0; k < 256; ++k)
        acc += ub[k] * w1[k * 256 + t] + pb[k] * w1[(256 + k) * 256 + t];
    h[t] = fmaxf(acc, 0.f);
    __syncthreads();
    float a2 = b2[t];
    for (int k = 0; k < 256; ++k) a2 += h[k] * w2[k * 256 + t];
    u2[t] = a2;
    __syncthreads();
    float fv = 0.f;
    if (t < 64) {
        float a3 = f1b[t];
        for (int k = 0; k < 256; ++k) a3 += u2[k] * f1w[k * 64 + t];
        fv = fmaxf(a3, 0.f) * f2w[t];
    }
    for (int off = 32; off; off >>= 1) fv += __shfl_down(fv, off, 64);
    if (t == 0) out[g] = fv + f2b[0];
}

// ---------- launch ----------
extern "C" void kernel_launch(void* const* d_in, const int* in_sizes, int n_in,
                              void* d_out, int out_size, void* d_ws, size_t ws_size,
                              hipStream_t stream) {
    const float* x         = (const float*)d_in[0];
    const float* edge_attr = (const float*)d_in[1];
    const float* e1_w1 = (const float*)d_in[2];
    const float* e1_b1 = (const float*)d_in[3];
    const float* e1_w2 = (const float*)d_in[4];
    const float* e1_b2 = (const float*)d_in[5];
    const float* g1_lw = (const float*)d_in[6];
    const float* g1_lb = (const float*)d_in[7];
    const float* g1_rw = (const float*)d_in[8];
    const float* g1_rb = (const float*)d_in[9];
    const float* g1_ew = (const float*)d_in[10];
    const float* g1_att = (const float*)d_in[11];
    const float* g1_bias = (const float*)d_in[12];
    const float* u1_w1 = (const float*)d_in[13];
    const float* u1_b1 = (const float*)d_in[14];
    const float* u1_w2 = (const float*)d_in[15];
    const float* u1_b2 = (const float*)d_in[16];
    const float* bn_n_g = (const float*)d_in[17];
    const float* bn_n_b = (const float*)d_in[18];
    const float* bn_e_g = (const float*)d_in[19];
    const float* bn_e_b = (const float*)d_in[20];
    const float* bn_u_g = (const float*)d_in[21];
    const float* bn_u_b = (const float*)d_in[22];
    const float* e2_w1 = (const float*)d_in[23];
    const float* e2_b1 = (const float*)d_in[24];
    const float* e2_w2 = (const float*)d_in[25];
    const float* e2_b2 = (const float*)d_in[26];
    const float* g2_lw = (const float*)d_in[27];
    const float* g2_lb = (const float*)d_in[28];
    const float* g2_rw = (const float*)d_in[29];
    const float* g2_rb = (const float*)d_in[30];
    const float* g2_ew = (const float*)d_in[31];
    const float* g2_att = (const float*)d_in[32];
    const float* g2_bias = (const float*)d_in[33];
    const float* u2_w1 = (const float*)d_in[34];
    const float* u2_b1 = (const float*)d_in[35];
    const float* u2_w2 = (const float*)d_in[36];
    const float* u2_b2 = (const float*)d_in[37];
    const float* fc1_w = (const float*)d_in[38];
    const float* fc1_b = (const float*)d_in[39];
    const float* fc2_w = (const float*)d_in[40];
    const float* fc2_b = (const float*)d_in[41];
    const int* edge_index = (const int*)d_in[42];
    const int* batch = (const int*)d_in[43];

    const int N = in_sizes[0] / 64;
    const int E = in_sizes[1] / 16;
    const int NT = E + N;
    const int G = G_GRAPHS;
    const int* src = edge_index;
    const int* dst = edge_index + E;
    const int NB = (NT + 31) / 32;
    const int NSB = (N + 2047) / 2048;   // scan blocks

    // workspace carve (~249 MB; x1bn aliases xr; pre2 lives in xl during edge_mlp2)
    char* p = (char*)d_ws;
    auto alloc = [&](size_t bytes) { char* r = p; p += (bytes + 255) & ~(size_t)255; return r; };
    bf16* eabuf = (bf16*)alloc((size_t)NT * 128 * 2);
    bf16* xl    = (bf16*)alloc((size_t)N * 256 * 2);
    bf16* xr    = (bf16*)alloc((size_t)N * 256 * 2);
    bf16* x1bn  = xr;
    unsigned char* ee8 = (unsigned char*)alloc((size_t)NT * 256);
    int* degi   = (int*)alloc((size_t)N * 4);
    int* off    = (int*)alloc((size_t)(N + 1) * 4);
    int* fillc  = (int*)alloc((size_t)N * 4);
    int* csr_src = (int*)alloc((size_t)NT * 4);
    int* csr_dst = (int*)alloc((size_t)NT * 4);
    int* csr_eid = (int*)alloc((size_t)NT * 4);
    int* slot_of = (int*)alloc((size_t)E * 4);
    int* bsum   = (int*)alloc((size_t)(NSB + 1) * 4);
    int* boff   = (int*)alloc((size_t)(NSB + 1) * 4);
    float* pooled = (float*)alloc((size_t)G * 256 * 4);
    float* u1bn = (float*)alloc((size_t)G * 256 * 4);
    short* w1s  = (short*)alloc((size_t)20 * 8 * 64 * 8 * 2);
    short* w2s  = (short*)alloc((size_t)4 * 8 * 64 * 8 * 2);
    float* b1x  = (float*)alloc((size_t)256 * 4);
    short* w1s1 = (short*)alloc((size_t)5 * 4 * 64 * 8 * 2);
    short* w2s1 = (short*)alloc((size_t)2 * 8 * 64 * 8 * 2);
    short* ews1 = (short*)alloc((size_t)4 * 16 * 64 * 8 * 2);
    short* ews2 = (short*)alloc((size_t)4 * 16 * 64 * 8 * 2);
    short* nw1  = (short*)alloc((size_t)2 * 32 * 64 * 8 * 2);
    short* nw2  = (short*)alloc((size_t)8 * 32 * 64 * 8 * 2);
    short* nwp  = (short*)alloc((size_t)8 * 16 * 64 * 8 * 2);

    // ===== CSR build =====
    hipMemsetAsync(degi, 0, (size_t)N * 4, stream);
    hipMemsetAsync(fillc, 0, (size_t)N * 4, stream);
    hipMemsetAsync(pooled, 0, (size_t)G * 256 * 4, stream);
    degi_k<<<(E + 255) / 256, 256, 0, stream>>>(dst, degi, E);
    scan_blk_k<<<NSB, 1024, 0, stream>>>(degi, off, bsum, N);
    scan_top_k<<<1, 64, 0, stream>>>(bsum, boff, off, NSB, N);
    scan_add_k<<<(N + 255) / 256, 256, 0, stream>>>(off, boff, N);
    fill_csr_k<<<(max(E, N) + 255) / 256, 256, 0, stream>>>(src, dst, off, fillc,
                                                            csr_src, csr_dst, csr_eid,
                                                            slot_of, E, N);

    // ===== layer 1 =====
    conv_weights1_k<<<9, 256, 0, stream>>>(e1_w1, e1_w2, w1s1, w2s1);
    conv_ew_k<<<16, 256, 0, stream>>>(g1_ew, ews1);
    conv_ew_k<<<16, 256, 0, stream>>>(g2_ew, ews2);
    conv_nodew_k<64><<<16, 256, 0, stream>>>(g1_lw, g1_rw, nw1);
    conv_nodew_k<256><<<64, 256, 0, stream>>>(g2_lw, g2_rw, nw2);
    conv_pre2w_k<<<32, 256, 0, stream>>>(e2_w1, nwp);
    edge_mlp1_mfma_k<<<(E + 31) / 32, 256, 0, stream>>>(x, edge_attr, src, dst, slot_of,
                                                        w1s1, e1_b1, w2s1, e1_b2, eabuf, E);
    node_linear_mfma_k<64, float><<<(N + 15) / 16, 256, 0, stream>>>(x, nw1, g1_lb, g1_rb, xl, xr, N);
    gemm_ee_k<<<NB, 256, 0, stream>>>(eabuf, ews1, ee8, NT);
    loop_ee_k<<<(N + 3) / 4, 256, 0, stream>>>(ee8, off, N);
    gat_fused_k<true><<<(N + 3) / 4, 256, 0, stream>>>(ee8, xl, xr, off, csr_src,
                                                       g1_att, g1_bias, bn_n_g, bn_n_b,
                                                       batch, x1bn, pooled, N);
    global_mlp1_k<<<G, 256, 0, stream>>>(pooled, u1_w1, u1_b1, u1_w2, u1_b2, bn_u_g, bn_u_b, u1bn);

    // ===== layer 2 =====
    conv_weights_k<<<50, 256, 0, stream>>>(e2_w1, e2_w2, e2_b1, bn_e_g, bn_e_b, w1s, w2s, b1x);
    pre_mfma_k<<<(N + 15) / 16, 256, 0, stream>>>(x1bn, nwp, b1x, xl, N);
    edge_mlp2_mfma_k<<<NB, 256, 0, stream>>>(xl, eabuf, csr_src, csr_dst, csr_eid,
                                             w1s, w2s, e2_b2, NT, E);
    node_linear_mfma_k<256, bf16><<<(N + 15) / 16, 256, 0, stream>>>(x1bn, nw2, g2_lb, g2_rb, xl, xr, N);
    hipMemsetAsync(pooled, 0, (size_t)G * 256 * 4, stream);
    gemm_ee_k<<<NB, 256, 0, stream>>>(eabuf, ews2, ee8, NT);
    loop_ee_k<<<(N + 3) / 4, 256, 0, stream>>>(ee8, off, N);
    gat_fused_k<false><<<(N + 3) / 4, 256, 0, stream>>>(ee8, xl, xr, off, csr_src,
                                                        g2_att, g2_bias, nullptr, nullptr,
                                                        batch, nullptr, pooled, N);
    final_mlp_k<<<G, 256, 0, stream>>>(u1bn, pooled, u2_w1, u2_b1, u2_w2, u2_b2,
                                       fc1_w, fc1_b, fc2_w, fc2_b, (float*)d_out);
}